// Round 5
// baseline (296.517 us; speedup 1.0000x reference)
//
#include <hip/hip_runtime.h>
#include <math.h>

#define T 2048
#define NH 12
#define HD 64
#define C3 2304   // 3*768
#define CE 768
#define NB 2

typedef __attribute__((ext_vector_type(8))) short bf16x8;
typedef __attribute__((ext_vector_type(4))) float f32x4;

// ---------------- fp32 -> (hi,lo) bf16 split, RNE both halves ----------------
__device__ inline void bf16split(float a, unsigned short& h, unsigned short& l) {
    unsigned int u = __float_as_uint(a);
    unsigned int r = (u + 0x7FFFu + ((u >> 16) & 1u)) >> 16;
    h = (unsigned short)r;
    float hf = __uint_as_float(r << 16);
    float lo = a - hf;                      // exact (Sterbenz)
    unsigned int v = __float_as_uint(lo);
    l = (unsigned short)((v + 0x7FFFu + ((v >> 16) & 1u)) >> 16);
}

// A-side converter: fp32 [R][C] -> bf16 planes H,L (same layout). total/8 threads.
__global__ __launch_bounds__(256) void cvt_split_kernel(const float* __restrict__ A,
        unsigned short* __restrict__ H, unsigned short* __restrict__ L) {
    int i = blockIdx.x * 256 + threadIdx.x;         // 8-element group
    float4 a0 = *(reinterpret_cast<const float4*>(A) + (size_t)i * 2);
    float4 a1 = *(reinterpret_cast<const float4*>(A) + (size_t)i * 2 + 1);
    float f[8] = {a0.x, a0.y, a0.z, a0.w, a1.x, a1.y, a1.z, a1.w};
    unsigned short h[8], l[8];
    #pragma unroll
    for (int j = 0; j < 8; ++j) bf16split(f[j], h[j], l[j]);
    uint4 hv, lv;
    hv.x = (unsigned)h[0] | ((unsigned)h[1] << 16); hv.y = (unsigned)h[2] | ((unsigned)h[3] << 16);
    hv.z = (unsigned)h[4] | ((unsigned)h[5] << 16); hv.w = (unsigned)h[6] | ((unsigned)h[7] << 16);
    lv.x = (unsigned)l[0] | ((unsigned)l[1] << 16); lv.y = (unsigned)l[2] | ((unsigned)l[3] << 16);
    lv.z = (unsigned)l[4] | ((unsigned)l[5] << 16); lv.w = (unsigned)l[6] | ((unsigned)l[7] << 16);
    reinterpret_cast<uint4*>(H)[i] = hv;
    reinterpret_cast<uint4*>(L)[i] = lv;
}

// B-side converter with transpose: fp32 W[K][N] -> bf16 planes [N][K].
__global__ __launch_bounds__(256) void cvt_split_T_kernel(const float* __restrict__ W,
        unsigned short* __restrict__ H, unsigned short* __restrict__ L, int K, int N) {
    __shared__ float tile[64][65];
    const int n0 = blockIdx.x * 64, k0 = blockIdx.y * 64;
    const int t = threadIdx.x;
    {
        int r = t >> 2, c4 = (t & 3) * 16;
        #pragma unroll
        for (int u = 0; u < 4; ++u) {
            float4 w = *reinterpret_cast<const float4*>(&W[(size_t)(k0 + r) * N + n0 + c4 + u * 4]);
            tile[r][c4 + u * 4 + 0] = w.x; tile[r][c4 + u * 4 + 1] = w.y;
            tile[r][c4 + u * 4 + 2] = w.z; tile[r][c4 + u * 4 + 3] = w.w;
        }
    }
    __syncthreads();
    {
        int n = t >> 2, kc = (t & 3) * 16;
        unsigned short h[16], l[16];
        #pragma unroll
        for (int j = 0; j < 16; ++j) bf16split(tile[kc + j][n], h[j], l[j]);
        uint4 hv0, hv1, lv0, lv1;
        hv0.x = (unsigned)h[0] | ((unsigned)h[1] << 16);  hv0.y = (unsigned)h[2] | ((unsigned)h[3] << 16);
        hv0.z = (unsigned)h[4] | ((unsigned)h[5] << 16);  hv0.w = (unsigned)h[6] | ((unsigned)h[7] << 16);
        hv1.x = (unsigned)h[8] | ((unsigned)h[9] << 16);  hv1.y = (unsigned)h[10] | ((unsigned)h[11] << 16);
        hv1.z = (unsigned)h[12] | ((unsigned)h[13] << 16); hv1.w = (unsigned)h[14] | ((unsigned)h[15] << 16);
        lv0.x = (unsigned)l[0] | ((unsigned)l[1] << 16);  lv0.y = (unsigned)l[2] | ((unsigned)l[3] << 16);
        lv0.z = (unsigned)l[4] | ((unsigned)l[5] << 16);  lv0.w = (unsigned)l[6] | ((unsigned)l[7] << 16);
        lv1.x = (unsigned)l[8] | ((unsigned)l[9] << 16);  lv1.y = (unsigned)l[10] | ((unsigned)l[11] << 16);
        lv1.z = (unsigned)l[12] | ((unsigned)l[13] << 16); lv1.w = (unsigned)l[14] | ((unsigned)l[15] << 16);
        size_t o = (size_t)(n0 + n) * K + k0 + kc;
        reinterpret_cast<uint4*>(&H[o])[0] = hv0; reinterpret_cast<uint4*>(&H[o])[1] = hv1;
        reinterpret_cast<uint4*>(&L[o])[0] = lv0; reinterpret_cast<uint4*>(&L[o])[1] = lv1;
    }
}

// ---- Q+K converter: qkv -> bf16 planes [bh][t][64] ----
__global__ __launch_bounds__(256) void cvt_qk_kernel(const float* __restrict__ qkv,
        unsigned short* __restrict__ Qh, unsigned short* __restrict__ Ql,
        unsigned short* __restrict__ Kh, unsigned short* __restrict__ Kl) {
    int t = blockIdx.x * 256 + threadIdx.x;
    int dg = t & 7;
    int s = (t >> 3) & (T - 1);
    int bh = t >> 14;                 // T*8 = 16384
    int b = bh / NH, h = bh % NH;
    const float* qs = qkv + (size_t)(b * T + s) * C3 + h * 64 + dg * 8;
    const float* ks = qs + 768;
    size_t o = ((size_t)bh * T + s) * 64 + dg * 8;
    #pragma unroll
    for (int which = 0; which < 2; ++which) {
        const float* src = (which == 0) ? qs : ks;
        float4 a0 = *reinterpret_cast<const float4*>(src);
        float4 a1 = *reinterpret_cast<const float4*>(src + 4);
        float f[8] = {a0.x, a0.y, a0.z, a0.w, a1.x, a1.y, a1.z, a1.w};
        unsigned short hh[8], ll[8];
        #pragma unroll
        for (int j = 0; j < 8; ++j) bf16split(f[j], hh[j], ll[j]);
        uint4 hv, lv;
        hv.x = (unsigned)hh[0] | ((unsigned)hh[1] << 16); hv.y = (unsigned)hh[2] | ((unsigned)hh[3] << 16);
        hv.z = (unsigned)hh[4] | ((unsigned)hh[5] << 16); hv.w = (unsigned)hh[6] | ((unsigned)hh[7] << 16);
        lv.x = (unsigned)ll[0] | ((unsigned)ll[1] << 16); lv.y = (unsigned)ll[2] | ((unsigned)ll[3] << 16);
        lv.z = (unsigned)ll[4] | ((unsigned)ll[5] << 16); lv.w = (unsigned)ll[6] | ((unsigned)ll[7] << 16);
        if (which == 0) {
            *reinterpret_cast<uint4*>(&Qh[o]) = hv;
            *reinterpret_cast<uint4*>(&Ql[o]) = lv;
        } else {
            *reinterpret_cast<uint4*>(&Kh[o]) = hv;
            *reinterpret_cast<uint4*>(&Kl[o]) = lv;
        }
    }
}

// ---- V converter (transposed): qkv V-part -> bf16 planes [bh][d][T] ----
__global__ __launch_bounds__(256) void cvt_kv_vt_kernel(const float* __restrict__ qkv,
        unsigned short* __restrict__ Vh, unsigned short* __restrict__ Vl) {
    __shared__ float tile[64][65];
    const int s0 = blockIdx.x * 64;
    const int bh = blockIdx.y;
    const int b = bh / NH, h = bh % NH;
    const int tid = threadIdx.x;
    {
        int r = tid >> 2, c0 = (tid & 3) * 16;
        const float* src = qkv + (size_t)(b * T + s0 + r) * C3 + 1536 + h * 64 + c0;
        #pragma unroll
        for (int u = 0; u < 4; ++u) {
            float4 w = *reinterpret_cast<const float4*>(src + u * 4);
            tile[r][c0 + u * 4 + 0] = w.x; tile[r][c0 + u * 4 + 1] = w.y;
            tile[r][c0 + u * 4 + 2] = w.z; tile[r][c0 + u * 4 + 3] = w.w;
        }
    }
    __syncthreads();
    {
        int d = tid >> 2, cs = (tid & 3) * 16;
        unsigned short hh[16], ll[16];
        #pragma unroll
        for (int j = 0; j < 16; ++j) bf16split(tile[cs + j][d], hh[j], ll[j]);
        uint4 hv0, hv1, lv0, lv1;
        hv0.x = (unsigned)hh[0] | ((unsigned)hh[1] << 16);  hv0.y = (unsigned)hh[2] | ((unsigned)hh[3] << 16);
        hv0.z = (unsigned)hh[4] | ((unsigned)hh[5] << 16);  hv0.w = (unsigned)hh[6] | ((unsigned)hh[7] << 16);
        hv1.x = (unsigned)hh[8] | ((unsigned)hh[9] << 16);  hv1.y = (unsigned)hh[10] | ((unsigned)hh[11] << 16);
        hv1.z = (unsigned)hh[12] | ((unsigned)hh[13] << 16); hv1.w = (unsigned)hh[14] | ((unsigned)hh[15] << 16);
        lv0.x = (unsigned)ll[0] | ((unsigned)ll[1] << 16);  lv0.y = (unsigned)ll[2] | ((unsigned)ll[3] << 16);
        lv0.z = (unsigned)ll[4] | ((unsigned)ll[5] << 16);  lv0.w = (unsigned)ll[6] | ((unsigned)ll[7] << 16);
        lv1.x = (unsigned)ll[8] | ((unsigned)ll[9] << 16);  lv1.y = (unsigned)ll[10] | ((unsigned)ll[11] << 16);
        lv1.z = (unsigned)ll[12] | ((unsigned)ll[13] << 16); lv1.w = (unsigned)ll[14] | ((unsigned)ll[15] << 16);
        size_t o = ((size_t)bh * 64 + d) * T + s0 + cs;
        reinterpret_cast<uint4*>(&Vh[o])[0] = hv0; reinterpret_cast<uint4*>(&Vh[o])[1] = hv1;
        reinterpret_cast<uint4*>(&Vl[o])[0] = lv0; reinterpret_cast<uint4*>(&Vl[o])[1] = lv1;
    }
}

// ---------------- split-bf16 MFMA GEMM: C = A*B + bias ----------------
#define LDST 40
__global__ __launch_bounds__(256) void gemm_mfma_kernel(
        const unsigned short* __restrict__ Ah, const unsigned short* __restrict__ Al,
        const unsigned short* __restrict__ Bh, const unsigned short* __restrict__ Bl,
        const float* __restrict__ bias, float* __restrict__ Cm,
        int M, int N, int K) {
    __shared__ unsigned short lA[2][128 * LDST];
    __shared__ unsigned short lB[2][128 * LDST];
    const int tid = threadIdx.x;
    const int bm = blockIdx.y * 128, bn = blockIdx.x * 128;
    const int lane = tid & 63, wid = tid >> 6;
    const int wr = wid >> 1, wc = wid & 1;
    f32x4 acc[4][4];
    #pragma unroll
    for (int i = 0; i < 4; ++i)
        #pragma unroll
        for (int j = 0; j < 4; ++j) acc[i][j] = (f32x4){0.f, 0.f, 0.f, 0.f};
    const int srow = tid >> 2, sk8 = (tid & 3) * 8;
    const int arb = wr * 64 + (lane & 15);
    const int brb = wc * 64 + (lane & 15);
    const int koff = (lane >> 4) * 8;
    for (int k0 = 0; k0 < K; k0 += 32) {
        __syncthreads();
        #pragma unroll
        for (int c = 0; c < 2; ++c) {
            int row = srow + 64 * c;
            uint4 va = *reinterpret_cast<const uint4*>(&Ah[(size_t)(bm + row) * K + k0 + sk8]);
            uint4 vb = *reinterpret_cast<const uint4*>(&Al[(size_t)(bm + row) * K + k0 + sk8]);
            uint4 vc = *reinterpret_cast<const uint4*>(&Bh[(size_t)(bn + row) * K + k0 + sk8]);
            uint4 vd = *reinterpret_cast<const uint4*>(&Bl[(size_t)(bn + row) * K + k0 + sk8]);
            *reinterpret_cast<uint4*>(&lA[0][row * LDST + sk8]) = va;
            *reinterpret_cast<uint4*>(&lA[1][row * LDST + sk8]) = vb;
            *reinterpret_cast<uint4*>(&lB[0][row * LDST + sk8]) = vc;
            *reinterpret_cast<uint4*>(&lB[1][row * LDST + sk8]) = vd;
        }
        __syncthreads();
        bf16x8 fa[2][4], fb[2][4];
        #pragma unroll
        for (int fi = 0; fi < 4; ++fi) {
            fa[0][fi] = *reinterpret_cast<const bf16x8*>(&lA[0][(arb + fi * 16) * LDST + koff]);
            fa[1][fi] = *reinterpret_cast<const bf16x8*>(&lA[1][(arb + fi * 16) * LDST + koff]);
            fb[0][fi] = *reinterpret_cast<const bf16x8*>(&lB[0][(brb + fi * 16) * LDST + koff]);
            fb[1][fi] = *reinterpret_cast<const bf16x8*>(&lB[1][(brb + fi * 16) * LDST + koff]);
        }
        #pragma unroll
        for (int fi = 0; fi < 4; ++fi)
            #pragma unroll
            for (int fj = 0; fj < 4; ++fj) {
                acc[fi][fj] = __builtin_amdgcn_mfma_f32_16x16x32_bf16(fa[0][fi], fb[0][fj], acc[fi][fj], 0, 0, 0);
                acc[fi][fj] = __builtin_amdgcn_mfma_f32_16x16x32_bf16(fa[0][fi], fb[1][fj], acc[fi][fj], 0, 0, 0);
                acc[fi][fj] = __builtin_amdgcn_mfma_f32_16x16x32_bf16(fa[1][fi], fb[0][fj], acc[fi][fj], 0, 0, 0);
            }
    }
    #pragma unroll
    for (int fj = 0; fj < 4; ++fj) {
        int col = bn + wc * 64 + fj * 16 + (lane & 15);
        float bv = bias[col];
        #pragma unroll
        for (int fi = 0; fi < 4; ++fi) {
            int row0 = bm + wr * 64 + fi * 16 + (lane >> 4) * 4;
            #pragma unroll
            for (int p = 0; p < 4; ++p)
                Cm[(size_t)(row0 + p) * N + col] = acc[fi][fj][p] + bv;
        }
    }
}

// ---------------- fp32 GEMM fallback (small ws) ----------------
__global__ __launch_bounds__(256) void gemm_bias_kernel(
        const float* __restrict__ A, const float* __restrict__ B,
        const float* __restrict__ bias, float* __restrict__ Cm,
        int M, int N, int K) {
    __shared__ float As[16][64];
    __shared__ float Bs[16][68];
    const int tid = threadIdx.x;
    const int ty = tid >> 4, tx = tid & 15;
    const int bm = blockIdx.y * 64, bn = blockIdx.x * 64;
    float acc[4][4] = {};
    for (int k0 = 0; k0 < K; k0 += 16) {
        {
            int r = tid >> 2;
            int kk = (tid & 3) * 4;
            float4 a = *reinterpret_cast<const float4*>(&A[(size_t)(bm + r) * K + k0 + kk]);
            As[kk + 0][r] = a.x; As[kk + 1][r] = a.y; As[kk + 2][r] = a.z; As[kk + 3][r] = a.w;
        }
        {
            int kk = tid >> 4;
            int c = (tid & 15) * 4;
            *reinterpret_cast<float4*>(&Bs[kk][c]) =
                *reinterpret_cast<const float4*>(&B[(size_t)(k0 + kk) * N + bn + c]);
        }
        __syncthreads();
        #pragma unroll
        for (int kk = 0; kk < 16; ++kk) {
            float4 a4 = *reinterpret_cast<const float4*>(&As[kk][ty * 4]);
            float4 b4 = *reinterpret_cast<const float4*>(&Bs[kk][tx * 4]);
            float av[4] = {a4.x, a4.y, a4.z, a4.w};
            float bv[4] = {b4.x, b4.y, b4.z, b4.w};
            #pragma unroll
            for (int i = 0; i < 4; ++i)
                #pragma unroll
                for (int j = 0; j < 4; ++j)
                    acc[i][j] = fmaf(av[i], bv[j], acc[i][j]);
        }
        __syncthreads();
    }
    #pragma unroll
    for (int i = 0; i < 4; ++i) {
        int row = bm + ty * 4 + i;
        #pragma unroll
        for (int j = 0; j < 4; ++j) {
            int col = bn + tx * 4 + j;
            Cm[(size_t)row * N + col] = acc[i][j] + bias[col];
        }
    }
}

#define FST 72   // LDS row stride (bf16), 144 B = 16B-aligned rows

// ---------------- s0 via MFMA: S = masked relu(head0 scores) ----------------
__global__ __launch_bounds__(256) void s0_mfma_kernel(
        const unsigned short* __restrict__ Qh, const unsigned short* __restrict__ Ql,
        const unsigned short* __restrict__ Kh, const unsigned short* __restrict__ Kl,
        float* __restrict__ S) {
    const int kb = blockIdx.x * 64, qb = blockIdx.y * 64, b = blockIdx.z;
    const int tid = threadIdx.x;
    float* Sb = S + (size_t)b * T * T;
    if (kb > qb) {  // entire tile masked -> zero
        const int ty = tid >> 4, tx = tid & 15;
        #pragma unroll
        for (int i = 0; i < 4; ++i) {
            float4 z = {0.f, 0.f, 0.f, 0.f};
            *reinterpret_cast<float4*>(&Sb[(size_t)(qb + ty * 4 + i) * T + kb + tx * 4]) = z;
        }
        return;
    }
    const int lane = tid & 63, w = tid >> 6;
    const int fr = lane & 15, fg = lane >> 4;
    __shared__ unsigned short Ks[2][64 * FST];
    const int hb0 = b * NH;   // head 0
    {
        const int sr = tid >> 2, sc0 = (tid & 3) * 16;
        const unsigned short* kh = Kh + ((size_t)hb0 * T + kb + sr) * 64 + sc0;
        const unsigned short* kl = Kl + ((size_t)hb0 * T + kb + sr) * 64 + sc0;
        uint4 a0 = reinterpret_cast<const uint4*>(kh)[0];
        uint4 a1 = reinterpret_cast<const uint4*>(kh)[1];
        uint4 b0 = reinterpret_cast<const uint4*>(kl)[0];
        uint4 b1 = reinterpret_cast<const uint4*>(kl)[1];
        *reinterpret_cast<uint4*>(&Ks[0][sr * FST + sc0 + 0]) = a0;
        *reinterpret_cast<uint4*>(&Ks[0][sr * FST + sc0 + 8]) = a1;
        *reinterpret_cast<uint4*>(&Ks[1][sr * FST + sc0 + 0]) = b0;
        *reinterpret_cast<uint4*>(&Ks[1][sr * FST + sc0 + 8]) = b1;
    }
    bf16x8 qh[2], ql[2];
    #pragma unroll
    for (int ks = 0; ks < 2; ++ks) {
        size_t qo = ((size_t)hb0 * T + qb + w * 16 + fr) * 64 + ks * 32 + fg * 8;
        qh[ks] = *reinterpret_cast<const bf16x8*>(&Qh[qo]);
        ql[ks] = *reinterpret_cast<const bf16x8*>(&Ql[qo]);
    }
    __syncthreads();
    f32x4 qk[4];
    #pragma unroll
    for (int fj = 0; fj < 4; ++fj) qk[fj] = (f32x4){0.f, 0.f, 0.f, 0.f};
    #pragma unroll
    for (int ks = 0; ks < 2; ++ks) {
        bf16x8 kbh[4], kbl[4];
        #pragma unroll
        for (int fj = 0; fj < 4; ++fj) {
            kbh[fj] = *reinterpret_cast<const bf16x8*>(&Ks[0][(fj * 16 + fr) * FST + ks * 32 + fg * 8]);
            kbl[fj] = *reinterpret_cast<const bf16x8*>(&Ks[1][(fj * 16 + fr) * FST + ks * 32 + fg * 8]);
        }
        #pragma unroll
        for (int fj = 0; fj < 4; ++fj) {
            qk[fj] = __builtin_amdgcn_mfma_f32_16x16x32_bf16(qh[ks], kbh[fj], qk[fj], 0, 0, 0);
            qk[fj] = __builtin_amdgcn_mfma_f32_16x16x32_bf16(qh[ks], kbl[fj], qk[fj], 0, 0, 0);
            qk[fj] = __builtin_amdgcn_mfma_f32_16x16x32_bf16(ql[ks], kbh[fj], qk[fj], 0, 0, 0);
        }
    }
    #pragma unroll
    for (int p = 0; p < 4; ++p) {
        int t = qb + w * 16 + fg * 4 + p;
        #pragma unroll
        for (int fj = 0; fj < 4; ++fj) {
            int s = kb + fj * 16 + fr;
            float v = qk[fj][p] * 0.125f;
            Sb[(size_t)t * T + s] = (s >= 1 && s < t) ? fmaxf(v, 0.0f) : 0.0f;
        }
    }
}

// ---------------- fp32 s0 fallback ----------------
__global__ __launch_bounds__(256) void s0_kernel(const float* __restrict__ qkv,
                                                 float* __restrict__ S) {
    const int kb = blockIdx.x * 64, qb = blockIdx.y * 64, b = blockIdx.z;
    const int tid = threadIdx.x, ty = tid >> 4, tx = tid & 15;
    float* Sb = S + (size_t)b * T * T;
    if (kb > qb) {
        #pragma unroll
        for (int i = 0; i < 4; ++i) {
            int row = qb + ty * 4 + i;
            float4 z = {0.f, 0.f, 0.f, 0.f};
            *reinterpret_cast<float4*>(&Sb[(size_t)row * T + kb + tx * 4]) = z;
        }
        return;
    }
    __shared__ float Qt[64][68];
    __shared__ float Kt[64][68];
    {
        int r = tid >> 2;
        int c0 = (tid & 3) * 16;
        const float* qrow = qkv + (size_t)(b * T + qb + r) * C3 + 0;
        const float* krow = qkv + (size_t)(b * T + kb + r) * C3 + 768;
        #pragma unroll
        for (int u = 0; u < 4; ++u) {
            float4 q4 = *reinterpret_cast<const float4*>(&qrow[c0 + u * 4]);
            float4 k4 = *reinterpret_cast<const float4*>(&krow[c0 + u * 4]);
            int d = c0 + u * 4;
            Qt[d + 0][r] = q4.x; Qt[d + 1][r] = q4.y; Qt[d + 2][r] = q4.z; Qt[d + 3][r] = q4.w;
            Kt[d + 0][r] = k4.x; Kt[d + 1][r] = k4.y; Kt[d + 2][r] = k4.z; Kt[d + 3][r] = k4.w;
        }
    }
    __syncthreads();
    float acc[4][4] = {};
    #pragma unroll
    for (int d = 0; d < 64; ++d) {
        float4 qv = *reinterpret_cast<const float4*>(&Qt[d][ty * 4]);
        float4 kv = *reinterpret_cast<const float4*>(&Kt[d][tx * 4]);
        float qa[4] = {qv.x, qv.y, qv.z, qv.w};
        float ka[4] = {kv.x, kv.y, kv.z, kv.w};
        #pragma unroll
        for (int i = 0; i < 4; ++i)
            #pragma unroll
            for (int j = 0; j < 4; ++j)
                acc[i][j] = fmaf(qa[i], ka[j], acc[i][j]);
    }
    #pragma unroll
    for (int i = 0; i < 4; ++i) {
        int t = qb + ty * 4 + i;
        float o[4];
        #pragma unroll
        for (int j = 0; j < 4; ++j) {
            int s = kb + tx * 4 + j;
            float v = acc[i][j] * 0.125f;
            o[j] = (s >= 1 && s < t) ? fmaxf(v, 0.0f) : 0.0f;
        }
        float4 o4 = {o[0], o[1], o[2], o[3]};
        *reinterpret_cast<float4*>(&Sb[(size_t)t * T + kb + tx * 4]) = o4;
    }
}

// ---------------- segmented scan: FF = cumsum_t(S) ----------------
__global__ __launch_bounds__(256) void colsum_kernel(const float* __restrict__ S,
                                                     float* __restrict__ Psum) {
    int s = blockIdx.x * 256 + threadIdx.x;
    int j = blockIdx.y, b = blockIdx.z;
    const float* Sb = S + (size_t)b * T * T;
    float sum = 0.f;
    for (int r = 0; r < 64; ++r) sum += Sb[(size_t)(j * 64 + r) * T + s];
    Psum[((size_t)b * 32 + j) * T + s] = sum;
}

__global__ __launch_bounds__(256) void scanseg_kernel(float* __restrict__ Psum) {
    int s = blockIdx.x * 256 + threadIdx.x;
    int b = blockIdx.y;
    float run = 0.f;
    for (int j = 0; j < 32; ++j) {
        size_t idx = ((size_t)b * 32 + j) * T + s;
        float v = Psum[idx];
        Psum[idx] = run;
        run += v;
    }
}

__global__ __launch_bounds__(256) void ffscan_kernel(float* __restrict__ S,
                                                     const float* __restrict__ Psum) {
    int s = blockIdx.x * 256 + threadIdx.x;
    int j = blockIdx.y, b = blockIdx.z;
    float run = Psum[((size_t)b * 32 + j) * T + s];
    float* Sb = S + (size_t)b * T * T;
    for (int r = 0; r < 64; ++r) {
        size_t idx = (size_t)(j * 64 + r) * T + s;
        run += Sb[idx];
        Sb[idx] = run;
    }
}

// ---------------- chunk helpers (8-tile split-K) ----------------
// Row qt has nch(qt) = (qt+8)>>3 chunks; qt<8 -> 1 chunk = direct.
// chunk_base(qt): chunks stored before row qt (rows 8..qt-1). Total = 72 per (b,h).
__device__ inline int chunk_base_fn(int qt) {
    int base = 0;
    for (int q = 8; q < qt; ++q) base += (q + 8) >> 3;
    return base;
}

// ---------------- MFMA flash attention, 8-tile chunked split-K ----------------
// grid (24, 80). u -> (qt, chunk) mapped size-descending (8-tile chunks first).
// Partials (72 chunks per hb x 4224 f32: O[64][64] + m[64] + l[64]) live in the
// dead qkv buffer. LDS 36,864 B -> 4 blocks/CU.
__global__ __launch_bounds__(256) void flash_mfma_kernel(
        const unsigned short* __restrict__ Qh, const unsigned short* __restrict__ Ql,
        const unsigned short* __restrict__ Kh, const unsigned short* __restrict__ Kl,
        const unsigned short* __restrict__ Vth, const unsigned short* __restrict__ Vtl,
        const float* __restrict__ FF, float* __restrict__ Y,
        float* __restrict__ PART) {
    const int hb = blockIdx.x;
    const int h = hb % NH, b = hb / NH;
    int qt = 0, kt0 = 0, kt1 = 1;
    {   // map u -> (qt, chunk), big tasks first
        int u = blockIdx.y, cnt = 0;
        bool found = false;
        for (int sz = 8; sz >= 1 && !found; --sz) {
            for (int q = 31; q >= 0; --q) {
                int nch = (q + 8) >> 3;
                int nfull = nch - 1;
                int last = q + 1 - 8 * nfull;
                int nthis = ((sz == 8) ? nfull : 0) + ((last == sz) ? 1 : 0);
                if (u < cnt + nthis) {
                    int off = u - cnt;
                    qt = q;
                    int ci = (sz == 8 && off < nfull) ? off : nfull;
                    kt0 = ci * 8;
                    kt1 = (ci == nfull) ? (q + 1) : (kt0 + 8);
                    found = true;
                    break;
                }
                cnt += nthis;
            }
        }
    }
    const int qb = qt * 64;
    const int tid = threadIdx.x;
    const int lane = tid & 63, w = tid >> 6;
    const int fr = lane & 15, fg = lane >> 4;
    __shared__ unsigned short KP[2][64 * FST];   // K hi/lo, then P hi/lo
    __shared__ unsigned short Vt[2][64 * FST];   // V^T hi/lo [d][s]

    // Q fragments from planes (b128 loads), once per block
    bf16x8 qh[2], ql[2];
    #pragma unroll
    for (int ks = 0; ks < 2; ++ks) {
        size_t qo = ((size_t)hb * T + qb + w * 16 + fr) * 64 + ks * 32 + fg * 8;
        qh[ks] = *reinterpret_cast<const bf16x8*>(&Qh[qo]);
        ql[ks] = *reinterpret_cast<const bf16x8*>(&Ql[qo]);
    }

    float m[4], l[4];
    f32x4 Oacc[4];
    #pragma unroll
    for (int p = 0; p < 4; ++p) { m[p] = -1e30f; l[p] = 0.f; }
    #pragma unroll
    for (int fd = 0; fd < 4; ++fd) Oacc[fd] = (f32x4){0.f, 0.f, 0.f, 0.f};

    const float* FFb = FF + (size_t)b * T * T;
    const int sr = tid >> 2, sc0 = (tid & 3) * 16;

    for (int kt = kt0; kt < kt1; ++kt) {
        const int kb = kt * 64;
        __syncthreads();
        {   // stage K planes [s][d] and Vt planes [d][s]
            const unsigned short* ksrc = Kh + ((size_t)hb * T + kb + sr) * 64 + sc0;
            const unsigned short* ksrl = Kl + ((size_t)hb * T + kb + sr) * 64 + sc0;
            const unsigned short* vsrc = Vth + ((size_t)hb * 64 + sr) * T + kb + sc0;
            const unsigned short* vsrl = Vtl + ((size_t)hb * 64 + sr) * T + kb + sc0;
            uint4 k0v = reinterpret_cast<const uint4*>(ksrc)[0];
            uint4 k1v = reinterpret_cast<const uint4*>(ksrc)[1];
            uint4 k2v = reinterpret_cast<const uint4*>(ksrl)[0];
            uint4 k3v = reinterpret_cast<const uint4*>(ksrl)[1];
            uint4 v0v = reinterpret_cast<const uint4*>(vsrc)[0];
            uint4 v1v = reinterpret_cast<const uint4*>(vsrc)[1];
            uint4 v2v = reinterpret_cast<const uint4*>(vsrl)[0];
            uint4 v3v = reinterpret_cast<const uint4*>(vsrl)[1];
            *reinterpret_cast<uint4*>(&KP[0][sr * FST + sc0 + 0]) = k0v;
            *reinterpret_cast<uint4*>(&KP[0][sr * FST + sc0 + 8]) = k1v;
            *reinterpret_cast<uint4*>(&KP[1][sr * FST + sc0 + 0]) = k2v;
            *reinterpret_cast<uint4*>(&KP[1][sr * FST + sc0 + 8]) = k3v;
            *reinterpret_cast<uint4*>(&Vt[0][sr * FST + sc0 + 0]) = v0v;
            *reinterpret_cast<uint4*>(&Vt[0][sr * FST + sc0 + 8]) = v1v;
            *reinterpret_cast<uint4*>(&Vt[1][sr * FST + sc0 + 0]) = v2v;
            *reinterpret_cast<uint4*>(&Vt[1][sr * FST + sc0 + 8]) = v3v;
        }
        __syncthreads();
        // FF tile loads hoisted above MFMAs (latency hides under QK issue)
        float ffv[4][4];
        #pragma unroll
        for (int p = 0; p < 4; ++p) {
            int t = qb + w * 16 + fg * 4 + p;
            #pragma unroll
            for (int fj = 0; fj < 4; ++fj)
                ffv[p][fj] = FFb[(size_t)t * T + kb + fj * 16 + fr];
        }
        // ---- QK^T ----
        f32x4 qk[4];
        #pragma unroll
        for (int fj = 0; fj < 4; ++fj) qk[fj] = (f32x4){0.f, 0.f, 0.f, 0.f};
        #pragma unroll
        for (int ks = 0; ks < 2; ++ks) {
            bf16x8 kbh[4], kbl[4];
            #pragma unroll
            for (int fj = 0; fj < 4; ++fj) {
                kbh[fj] = *reinterpret_cast<const bf16x8*>(&KP[0][(fj * 16 + fr) * FST + ks * 32 + fg * 8]);
                kbl[fj] = *reinterpret_cast<const bf16x8*>(&KP[1][(fj * 16 + fr) * FST + ks * 32 + fg * 8]);
            }
            #pragma unroll
            for (int fj = 0; fj < 4; ++fj) {
                qk[fj] = __builtin_amdgcn_mfma_f32_16x16x32_bf16(qh[ks], kbh[fj], qk[fj], 0, 0, 0);
                qk[fj] = __builtin_amdgcn_mfma_f32_16x16x32_bf16(qh[ks], kbl[fj], qk[fj], 0, 0, 0);
                qk[fj] = __builtin_amdgcn_mfma_f32_16x16x32_bf16(ql[ks], kbh[fj], qk[fj], 0, 0, 0);
            }
        }
        // ---- scores: *0.125 - FF, causal mask ----
        float sc[4][4];
        #pragma unroll
        for (int p = 0; p < 4; ++p) {
            int t = qb + w * 16 + fg * 4 + p;
            #pragma unroll
            for (int fj = 0; fj < 4; ++fj) {
                int s = kb + fj * 16 + fr;
                float v = qk[fj][p] * 0.125f - ffv[p][fj];
                sc[fj][p] = (s <= t) ? v : -1e30f;
            }
        }
        // ---- online softmax ----
        #pragma unroll
        for (int p = 0; p < 4; ++p) {
            float tm = fmaxf(fmaxf(sc[0][p], sc[1][p]), fmaxf(sc[2][p], sc[3][p]));
            tm = fmaxf(tm, __shfl_xor(tm, 1));
            tm = fmaxf(tm, __shfl_xor(tm, 2));
            tm = fmaxf(tm, __shfl_xor(tm, 4));
            tm = fmaxf(tm, __shfl_xor(tm, 8));
            float mn = fmaxf(m[p], tm);
            float scale = __expf(m[p] - mn);
            float rs = 0.f;
            #pragma unroll
            for (int fj = 0; fj < 4; ++fj) {
                float pe = __expf(sc[fj][p] - mn);
                sc[fj][p] = pe; rs += pe;
            }
            rs += __shfl_xor(rs, 1); rs += __shfl_xor(rs, 2);
            rs += __shfl_xor(rs, 4); rs += __shfl_xor(rs, 8);
            l[p] = l[p] * scale + rs;
            m[p] = mn;
            #pragma unroll
            for (int fd = 0; fd < 4; ++fd) Oacc[fd][p] *= scale;
        }
        __syncthreads();
        // ---- write P (split bf16) into KP ----
        #pragma unroll
        for (int p = 0; p < 4; ++p) {
            int qrow = w * 16 + fg * 4 + p;
            #pragma unroll
            for (int fj = 0; fj < 4; ++fj) {
                unsigned short hh, ll;
                bf16split(sc[fj][p], hh, ll);
                KP[0][qrow * FST + fj * 16 + fr] = hh;
                KP[1][qrow * FST + fj * 16 + fr] = ll;
            }
        }
        __syncthreads();
        // ---- PV ----
        #pragma unroll
        for (int ks = 0; ks < 2; ++ks) {
            bf16x8 pah = *reinterpret_cast<const bf16x8*>(&KP[0][(w * 16 + fr) * FST + ks * 32 + fg * 8]);
            bf16x8 pal = *reinterpret_cast<const bf16x8*>(&KP[1][(w * 16 + fr) * FST + ks * 32 + fg * 8]);
            bf16x8 vbh[4], vbl[4];
            #pragma unroll
            for (int fd = 0; fd < 4; ++fd) {
                vbh[fd] = *reinterpret_cast<const bf16x8*>(&Vt[0][(fd * 16 + fr) * FST + ks * 32 + fg * 8]);
                vbl[fd] = *reinterpret_cast<const bf16x8*>(&Vt[1][(fd * 16 + fr) * FST + ks * 32 + fg * 8]);
            }
            #pragma unroll
            for (int fd = 0; fd < 4; ++fd) {
                Oacc[fd] = __builtin_amdgcn_mfma_f32_16x16x32_bf16(pah, vbh[fd], Oacc[fd], 0, 0, 0);
                Oacc[fd] = __builtin_amdgcn_mfma_f32_16x16x32_bf16(pah, vbl[fd], Oacc[fd], 0, 0, 0);
                Oacc[fd] = __builtin_amdgcn_mfma_f32_16x16x32_bf16(pal, vbh[fd], Oacc[fd], 0, 0, 0);
            }
        }
    }
    if (qt < 8) {   // direct normalized write
        #pragma unroll
        for (int p = 0; p < 4; ++p) {
            int t = qb + w * 16 + fg * 4 + p;
            float inv = 1.f / l[p];
            float* Yrow = Y + (size_t)(b * T + t) * CE + h * 64;
            #pragma unroll
            for (int fd = 0; fd < 4; ++fd)
                Yrow[fd * 16 + fr] = Oacc[fd][p] * inv;
        }
    } else {        // partial: unnormalized O + (m,l)
        const int cb = chunk_base_fn(qt) + (kt0 >> 3);
        float* Ob = PART + (size_t)(hb * 72 + cb) * 4224;
        #pragma unroll
        for (int p = 0; p < 4; ++p) {
            int rr = w * 16 + fg * 4 + p;
            #pragma unroll
            for (int fd = 0; fd < 4; ++fd)
                Ob[rr * 64 + fd * 16 + fr] = Oacc[fd][p];
            if (fr == 0) { Ob[4096 + rr] = m[p]; Ob[4096 + 64 + rr] = l[p]; }
        }
    }
}

// ---------------- merge 2..4 chunk partials per row block (qt >= 8) ----------------
__global__ __launch_bounds__(256) void merge8_kernel(const float* __restrict__ PART,
                                                     float* __restrict__ Y) {
    const int hb = blockIdx.x;          // 0..23
    const int qt = 8 + blockIdx.y;      // 8..31
    const int h = hb % NH, b = hb / NH;
    const int nch = (qt + 8) >> 3;      // 2..4
    const float* base = PART + (size_t)(hb * 72 + chunk_base_fn(qt)) * 4224;
    const int tid = threadIdx.x;
    const int r = tid >> 2, c0 = (tid & 3) * 16;
    float mm[4], ll[4];
    float M = -1e30f;
    #pragma unroll
    for (int c = 0; c < 4; ++c) {
        int cc = (c < nch) ? c : 0;     // safe address; weight zeroed below
        float mv = base[(size_t)cc * 4224 + 4096 + r];
        float lv = base[(size_t)cc * 4224 + 4096 + 64 + r];
        mm[c] = (c < nch) ? mv : -1e30f;
        ll[c] = (c < nch) ? lv : 0.f;
        M = fmaxf(M, mm[c]);
    }
    float a[4], L = 0.f;
    #pragma unroll
    for (int c = 0; c < 4; ++c) {
        a[c] = (c < nch) ? __expf(mm[c] - M) : 0.f;
        L += a[c] * ll[c];
    }
    float inv = 1.f / L;
    const int t = qt * 64 + r;
    float* Yrow = Y + (size_t)(b * T + t) * CE + h * 64;
    #pragma unroll
    for (int u = 0; u < 4; ++u) {
        float ax = 0.f, ay = 0.f, az = 0.f, aw = 0.f;
        #pragma unroll
        for (int c = 0; c < 4; ++c) {
            int cc = (c < nch) ? c : 0;
            float4 xo = *reinterpret_cast<const float4*>(&base[(size_t)cc * 4224 + r * 64 + c0 + u * 4]);
            ax += a[c] * xo.x; ay += a[c] * xo.y; az += a[c] * xo.z; aw += a[c] * xo.w;
        }
        float4 y = {ax * inv, ay * inv, az * inv, aw * inv};
        *reinterpret_cast<float4*>(&Yrow[c0 + u * 4]) = y;
    }
}

// ---------------- fp32 flash fallback (small ws) ----------------
__global__ __launch_bounds__(256) void flash_kernel(const float* __restrict__ qkv,
                                                    const float* __restrict__ FF,
                                                    float* __restrict__ Y,
                                                    float* __restrict__ PO,
                                                    float* __restrict__ PML,
                                                    int split) {
    const int hb = blockIdx.x;
    const int h = hb % NH, b = hb / NH;
    int qt, kt0, kt1, mode;
    if (split) {
        const int u = blockIdx.y;
        if (u < 16)      { qt = 16 + u; kt0 = 0;  kt1 = 16;     mode = 1; }
        else if (u < 32) { qt = 31 - u; kt0 = 0;  kt1 = qt + 1; mode = 0; }
        else             { qt = 63 - u; kt0 = 16; kt1 = qt + 1; mode = 2; }
    } else {
        qt = 31 - blockIdx.y; kt0 = 0; kt1 = qt + 1; mode = 0;
    }
    const int qb = qt * 64;
    const int tid = threadIdx.x, ty = tid >> 4, tx = tid & 15;
    __shared__ float Qt[64][68];
    __shared__ float KtPs[64][68];
    __shared__ float Vs[64][68];
    const int r = tid >> 2, c0 = (tid & 3) * 16;
    {
        const float* qrow = qkv + (size_t)(b * T + qb + r) * C3 + h * 64;
        #pragma unroll
        for (int u = 0; u < 4; ++u) {
            float4 q4 = *reinterpret_cast<const float4*>(&qrow[c0 + u * 4]);
            int d = c0 + u * 4;
            Qt[d + 0][r] = q4.x; Qt[d + 1][r] = q4.y; Qt[d + 2][r] = q4.z; Qt[d + 3][r] = q4.w;
        }
    }
    float m[4], l[4], O[4][4];
    #pragma unroll
    for (int i = 0; i < 4; ++i) {
        m[i] = -1e30f; l[i] = 0.f;
        #pragma unroll
        for (int j = 0; j < 4; ++j) O[i][j] = 0.f;
    }
    const float* FFb = FF + (size_t)b * T * T;
    for (int kt = kt0; kt < kt1; ++kt) {
        const int kb = kt * 64;
        __syncthreads();
        {
            const float* krow = qkv + (size_t)(b * T + kb + r) * C3 + 768 + h * 64;
            const float* vrow = qkv + (size_t)(b * T + kb + r) * C3 + 1536 + h * 64;
            #pragma unroll
            for (int u = 0; u < 4; ++u) {
                float4 k4 = *reinterpret_cast<const float4*>(&krow[c0 + u * 4]);
                int d = c0 + u * 4;
                KtPs[d + 0][r] = k4.x; KtPs[d + 1][r] = k4.y;
                KtPs[d + 2][r] = k4.z; KtPs[d + 3][r] = k4.w;
                *reinterpret_cast<float4*>(&Vs[r][c0 + u * 4]) =
                    *reinterpret_cast<const float4*>(&vrow[c0 + u * 4]);
            }
        }
        __syncthreads();
        float sc[4][4] = {};
        #pragma unroll
        for (int d = 0; d < 64; ++d) {
            float4 qv = *reinterpret_cast<const float4*>(&Qt[d][ty * 4]);
            float4 kv = *reinterpret_cast<const float4*>(&KtPs[d][tx * 4]);
            float qa[4] = {qv.x, qv.y, qv.z, qv.w};
            float ka[4] = {kv.x, kv.y, kv.z, kv.w};
            #pragma unroll
            for (int i = 0; i < 4; ++i)
                #pragma unroll
                for (int j = 0; j < 4; ++j)
                    sc[i][j] = fmaf(qa[i], ka[j], sc[i][j]);
        }
        #pragma unroll
        for (int i = 0; i < 4; ++i) {
            int t = qb + ty * 4 + i;
            float4 f4 = *reinterpret_cast<const float4*>(&FFb[(size_t)t * T + kb + tx * 4]);
            float fv[4] = {f4.x, f4.y, f4.z, f4.w};
            #pragma unroll
            for (int j = 0; j < 4; ++j) {
                int s = kb + tx * 4 + j;
                float v = sc[i][j] * 0.125f - fv[j];
                sc[i][j] = (s <= t) ? v : -1e30f;
            }
        }
        #pragma unroll
        for (int i = 0; i < 4; ++i) {
            float tm = fmaxf(fmaxf(sc[i][0], sc[i][1]), fmaxf(sc[i][2], sc[i][3]));
            tm = fmaxf(tm, __shfl_xor(tm, 1));
            tm = fmaxf(tm, __shfl_xor(tm, 2));
            tm = fmaxf(tm, __shfl_xor(tm, 4));
            tm = fmaxf(tm, __shfl_xor(tm, 8));
            float mn = fmaxf(m[i], tm);
            float scale = __expf(m[i] - mn);
            float rs = 0.f;
            #pragma unroll
            for (int j = 0; j < 4; ++j) {
                float p = __expf(sc[i][j] - mn);
                sc[i][j] = p; rs += p;
            }
            rs += __shfl_xor(rs, 1); rs += __shfl_xor(rs, 2);
            rs += __shfl_xor(rs, 4); rs += __shfl_xor(rs, 8);
            l[i] = l[i] * scale + rs;
            m[i] = mn;
            #pragma unroll
            for (int j = 0; j < 4; ++j) O[i][j] *= scale;
        }
        __syncthreads();
        #pragma unroll
        for (int i = 0; i < 4; ++i) {
            float4 p4 = {sc[i][0], sc[i][1], sc[i][2], sc[i][3]};
            *reinterpret_cast<float4*>(&KtPs[ty * 4 + i][tx * 4]) = p4;
        }
        __syncthreads();
        #pragma unroll
        for (int j4 = 0; j4 < 16; ++j4) {
            float pv[4][4];
            #pragma unroll
            for (int i = 0; i < 4; ++i) {
                float4 t4 = *reinterpret_cast<const float4*>(&KtPs[ty * 4 + i][j4 * 4]);
                pv[i][0] = t4.x; pv[i][1] = t4.y; pv[i][2] = t4.z; pv[i][3] = t4.w;
            }
            #pragma unroll
            for (int jj = 0; jj < 4; ++jj) {
                float4 v4 = *reinterpret_cast<const float4*>(&Vs[j4 * 4 + jj][tx * 4]);
                float vv[4] = {v4.x, v4.y, v4.z, v4.w};
                #pragma unroll
                for (int i = 0; i < 4; ++i)
                    #pragma unroll
                    for (int dd = 0; dd < 4; ++dd)
                        O[i][dd] = fmaf(pv[i][jj], vv[dd], O[i][dd]);
            }
        }
    }
    if (mode == 0) {
        #pragma unroll
        for (int i = 0; i < 4; ++i) {
            int t = qb + ty * 4 + i;
            float inv = 1.f / l[i];
            float4 o4 = {O[i][0] * inv, O[i][1] * inv, O[i][2] * inv, O[i][3] * inv};
            *reinterpret_cast<float4*>(&Y[(size_t)(b * T + t) * CE + h * 64 + tx * 4]) = o4;
        }
    } else {
        const int pidx = (b * NH + h) * 16 + (qt - 16);
        float* Ob  = PO  + (size_t)(mode - 1) * (NB * NH * 16 * 4096) + (size_t)pidx * 4096;
        float* mlb = PML + (size_t)(mode - 1) * (NB * NH * 16 * 128)  + (size_t)pidx * 128;
        #pragma unroll
        for (int i = 0; i < 4; ++i) {
            int rr = ty * 4 + i;
            float4 o4 = {O[i][0], O[i][1], O[i][2], O[i][3]};
            *reinterpret_cast<float4*>(&Ob[rr * 64 + tx * 4]) = o4;
            if (tx == 0) { mlb[rr] = m[i]; mlb[64 + rr] = l[i]; }
        }
    }
}

// ---------------- merge the two split-K partials (fp32 fallback path) ----------------
__global__ __launch_bounds__(256) void merge_kernel(const float* __restrict__ PO,
                                                    const float* __restrict__ PML,
                                                    float* __restrict__ Y) {
    const int p = blockIdx.x;
    const int q16 = p & 15;
    const int hb = p >> 4;
    const int h = hb % NH, b = hb / NH;
    const int qt = 16 + q16;
    const float* O0  = PO  + (size_t)p * 4096;
    const float* O1  = PO  + (size_t)(NB * NH * 16) * 4096 + (size_t)p * 4096;
    const float* ml0 = PML + (size_t)p * 128;
    const float* ml1 = PML + (size_t)(NB * NH * 16) * 128  + (size_t)p * 128;
    const int tid = threadIdx.x;
    const int r = tid >> 2, c0 = (tid & 3) * 16;
    float m0 = ml0[r], l0 = ml0[64 + r];
    float m1 = ml1[r], l1 = ml1[64 + r];
    float M  = fmaxf(m0, m1);
    float a0 = __expf(m0 - M), a1 = __expf(m1 - M);
    float inv = 1.f / (a0 * l0 + a1 * l1);
    const int t = qt * 64 + r;
    float* Yrow = Y + (size_t)(b * T + t) * CE + h * 64;
    #pragma unroll
    for (int u = 0; u < 4; ++u) {
        float4 x0 = *reinterpret_cast<const float4*>(&O0[r * 64 + c0 + u * 4]);
        float4 x1 = *reinterpret_cast<const float4*>(&O1[r * 64 + c0 + u * 4]);
        float4 y;
        y.x = (a0 * x0.x + a1 * x1.x) * inv;
        y.y = (a0 * x0.y + a1 * x1.y) * inv;
        y.z = (a0 * x0.z + a1 * x1.z) * inv;
        y.w = (a0 * x0.w + a1 * x1.w) * inv;
        *reinterpret_cast<float4*>(&Yrow[c0 + u * 4]) = y;
    }
}

extern "C" void kernel_launch(void* const* d_in, const int* in_sizes, int n_in,
                              void* d_out, int out_size, void* d_ws, size_t ws_size,
                              hipStream_t stream) {
    const float* x      = (const float*)d_in[0];
    const float* W_attn = (const float*)d_in[1];
    const float* b_attn = (const float*)d_in[2];
    const float* W_proj = (const float*)d_in[3];
    const float* b_proj = (const float*)d_in[4];
    float* out = (float*)d_out;

    char* ws = (char*)d_ws;
    const size_t QKV_BYTES = (size_t)NB * T * C3 * 4;       // 37,748,736
    const size_t S_BYTES   = (size_t)NB * T * T * 4;        // 33,554,432
    const size_t P_BYTES   = (size_t)NB * 32 * T * 4;       //    524,288
    const size_t Y_BYTES   = (size_t)NB * T * CE * 4;       // 12,582,912
    const size_t PO_BYTES  = (size_t)2 * NB * NH * 16 * 4096 * 4;  // 12,582,912
    const size_t PML_BYTES = (size_t)2 * NB * NH * 16 * 128 * 4;   //    393,216
    const size_t PLANE_X   = (size_t)NB * T * CE * 2;       // 6,291,456 (== per-KV/Q plane)
    const size_t PLANE_WA  = (size_t)C3 * CE * 2;           // 3,538,944
    const size_t PLANE_WP  = (size_t)CE * CE * 2;           // 1,179,648
    const size_t PLANE_KV  = (size_t)NB * NH * T * 64 * 2;  // 6,291,456

    const size_t U_OFF  = QKV_BYTES + S_BYTES + P_BYTES + Y_BYTES;
    const size_t U_SIZE = PO_BYTES + PML_BYTES;             // holds X/Q/Y planes (12.58MB) or PO/PML
    const size_t W_OFF  = U_OFF + U_SIZE;
    const size_t KV_OFF = W_OFF + 2 * PLANE_WA + 2 * PLANE_WP;

    float* qkv  = (float*)ws;                               // reused as PART during MFMA flash
    float* S    = (float*)(ws + QKV_BYTES);
    float* Psum = (float*)(ws + QKV_BYTES + S_BYTES);
    float* Yb   = (float*)(ws + QKV_BYTES + S_BYTES + P_BYTES);
    float* PO   = (float*)(ws + U_OFF);
    float* PML  = (float*)(ws + U_OFF + PO_BYTES);
    unsigned short* Xh  = (unsigned short*)(ws + U_OFF);    // X planes (gemm1), then Q planes, then Y planes
    unsigned short* Xl  = (unsigned short*)(ws + U_OFF + PLANE_X);
    unsigned short* Qhp = Xh;
    unsigned short* Qlp = Xl;
    unsigned short* Yh  = Xh;
    unsigned short* Yl  = Xl;
    unsigned short* WAh = (unsigned short*)(ws + W_OFF);
    unsigned short* WAl = (unsigned short*)(ws + W_OFF + PLANE_WA);
    unsigned short* WPh = (unsigned short*)(ws + W_OFF + 2 * PLANE_WA);
    unsigned short* WPl = (unsigned short*)(ws + W_OFF + 2 * PLANE_WA + PLANE_WP);
    unsigned short* Khp = (unsigned short*)(ws + KV_OFF);
    unsigned short* Klp = (unsigned short*)(ws + KV_OFF + PLANE_KV);
    unsigned short* VTh = (unsigned short*)(ws + KV_OFF + 2 * PLANE_KV);
    unsigned short* VTl = (unsigned short*)(ws + KV_OFF + 3 * PLANE_KV);
    float* PART = qkv;   // 24*72*4224*4 B = 29.2MB <= QKV_BYTES; qkv dead during flash

    const size_t NEED_SPLIT = U_OFF + U_SIZE;
    const size_t NEED_MFMA  = KV_OFF;
    const size_t NEED_KV    = KV_OFF + 4 * PLANE_KV;
    const int split = (ws_size >= NEED_SPLIT) ? 1 : 0;
    const int mfma  = (ws_size >= NEED_MFMA) ? 1 : 0;
    const int kv    = (ws_size >= NEED_KV && mfma) ? 1 : 0;

    const int M = NB * T;  // 4096

    // 1) qkv = x @ W_attn + b_attn
    if (mfma) {
        cvt_split_T_kernel<<<dim3(C3 / 64, CE / 64), 256, 0, stream>>>(W_attn, WAh, WAl, CE, C3);
        cvt_split_T_kernel<<<dim3(CE / 64, CE / 64), 256, 0, stream>>>(W_proj, WPh, WPl, CE, CE);
        cvt_split_kernel<<<dim3((M * CE / 8) / 256), 256, 0, stream>>>(x, Xh, Xl);
        gemm_mfma_kernel<<<dim3(C3 / 128, M / 128), 256, 0, stream>>>(Xh, Xl, WAh, WAl, b_attn, qkv, M, C3, CE);
    } else {
        gemm_bias_kernel<<<dim3(C3 / 64, M / 64), 256, 0, stream>>>(x, W_attn, b_attn, qkv, M, C3, CE);
    }
    // 2) Q/K/V -> bf16 planes (kv path); S = masked relu(head0 scores)
    if (kv) {
        cvt_qk_kernel<<<dim3((NB * NH * T * 8) / 256), 256, 0, stream>>>(qkv, Qhp, Qlp, Khp, Klp);
        cvt_kv_vt_kernel<<<dim3(T / 64, NB * NH), 256, 0, stream>>>(qkv, VTh, VTl);
        s0_mfma_kernel<<<dim3(T / 64, T / 64, NB), 256, 0, stream>>>(Qhp, Qlp, Khp, Klp, S);
    } else {
        s0_kernel<<<dim3(T / 64, T / 64, NB), 256, 0, stream>>>(qkv, S);
    }
    // 3) FF = cumsum_t(S)  (segmented scan, in place)
    colsum_kernel<<<dim3(T / 256, 32, NB), 256, 0, stream>>>(S, Psum);
    scanseg_kernel<<<dim3(T / 256, NB), 256, 0, stream>>>(Psum);
    ffscan_kernel<<<dim3(T / 256, 32, NB), 256, 0, stream>>>(S, Psum);
    // 4) flash attention with bias -FF
    if (kv) {
        flash_mfma_kernel<<<dim3(NB * NH, 80), 256, 0, stream>>>(Qhp, Qlp, Khp, Klp, VTh, VTl, S, Yb, PART);
        merge8_kernel<<<dim3(NB * NH, 24), 256, 0, stream>>>(PART, Yb);
    } else if (split) {
        flash_kernel<<<dim3(NB * NH, 48), 256, 0, stream>>>(qkv, S, Yb, PO, PML, 1);
        merge_kernel<<<dim3(NB * NH * 16), 256, 0, stream>>>(PO, PML, Yb);
    } else {
        flash_kernel<<<dim3(NB * NH, 32), 256, 0, stream>>>(qkv, S, Yb, PO, PML, 0);
    }
    // 5) out = Y @ W_proj + b_proj
    if (mfma) {
        cvt_split_kernel<<<dim3((M * CE / 8) / 256), 256, 0, stream>>>(Yb, Yh, Yl);
        gemm_mfma_kernel<<<dim3(CE / 128, M / 128), 256, 0, stream>>>(Yh, Yl, WPh, WPl, b_proj, out, M, CE, CE);
    } else {
        gemm_bias_kernel<<<dim3(CE / 64, M / 64), 256, 0, stream>>>(Yb, W_proj, b_proj, out, M, CE, CE);
    }
}

// Round 6
// 260.495 us; speedup vs baseline: 1.1383x; 1.1383x over previous
//
#include <hip/hip_runtime.h>
#include <math.h>

#define T 2048
#define NH 12
#define HD 64
#define C3 2304   // 3*768
#define CE 768
#define NB 2

typedef __attribute__((ext_vector_type(8))) short bf16x8;
typedef __attribute__((ext_vector_type(4))) float f32x4;
typedef __attribute__((ext_vector_type(16))) float f32x16;
typedef __attribute__((ext_vector_type(4))) unsigned u32x4;

// ---------------- fp32 -> (hi,lo) bf16 split, RNE both halves ----------------
__device__ inline void bf16split(float a, unsigned short& h, unsigned short& l) {
    unsigned int u = __float_as_uint(a);
    unsigned int r = (u + 0x7FFFu + ((u >> 16) & 1u)) >> 16;
    h = (unsigned short)r;
    float hf = __uint_as_float(r << 16);
    float lo = a - hf;                      // exact (Sterbenz)
    unsigned int v = __float_as_uint(lo);
    l = (unsigned short)((v + 0x7FFFu + ((v >> 16) & 1u)) >> 16);
}

__device__ inline void packP(float a, float b, unsigned& wh, unsigned& wl) {
    unsigned short ha, la, hb, lb;
    bf16split(a, ha, la); bf16split(b, hb, lb);
    wh = (unsigned)ha | ((unsigned)hb << 16);
    wl = (unsigned)la | ((unsigned)lb << 16);
}

// A-side converter: fp32 [R][C] -> bf16 planes H,L (same layout). total/8 threads.
__global__ __launch_bounds__(256) void cvt_split_kernel(const float* __restrict__ A,
        unsigned short* __restrict__ H, unsigned short* __restrict__ L) {
    int i = blockIdx.x * 256 + threadIdx.x;         // 8-element group
    float4 a0 = *(reinterpret_cast<const float4*>(A) + (size_t)i * 2);
    float4 a1 = *(reinterpret_cast<const float4*>(A) + (size_t)i * 2 + 1);
    float f[8] = {a0.x, a0.y, a0.z, a0.w, a1.x, a1.y, a1.z, a1.w};
    unsigned short h[8], l[8];
    #pragma unroll
    for (int j = 0; j < 8; ++j) bf16split(f[j], h[j], l[j]);
    uint4 hv, lv;
    hv.x = (unsigned)h[0] | ((unsigned)h[1] << 16); hv.y = (unsigned)h[2] | ((unsigned)h[3] << 16);
    hv.z = (unsigned)h[4] | ((unsigned)h[5] << 16); hv.w = (unsigned)h[6] | ((unsigned)h[7] << 16);
    lv.x = (unsigned)l[0] | ((unsigned)l[1] << 16); lv.y = (unsigned)l[2] | ((unsigned)l[3] << 16);
    lv.z = (unsigned)l[4] | ((unsigned)l[5] << 16); lv.w = (unsigned)l[6] | ((unsigned)l[7] << 16);
    reinterpret_cast<uint4*>(H)[i] = hv;
    reinterpret_cast<uint4*>(L)[i] = lv;
}

// B-side converter with transpose: fp32 W[K][N] -> bf16 planes [N][K].
__global__ __launch_bounds__(256) void cvt_split_T_kernel(const float* __restrict__ W,
        unsigned short* __restrict__ H, unsigned short* __restrict__ L, int K, int N) {
    __shared__ float tile[64][65];
    const int n0 = blockIdx.x * 64, k0 = blockIdx.y * 64;
    const int t = threadIdx.x;
    {
        int r = t >> 2, c4 = (t & 3) * 16;
        #pragma unroll
        for (int u = 0; u < 4; ++u) {
            float4 w = *reinterpret_cast<const float4*>(&W[(size_t)(k0 + r) * N + n0 + c4 + u * 4]);
            tile[r][c4 + u * 4 + 0] = w.x; tile[r][c4 + u * 4 + 1] = w.y;
            tile[r][c4 + u * 4 + 2] = w.z; tile[r][c4 + u * 4 + 3] = w.w;
        }
    }
    __syncthreads();
    {
        int n = t >> 2, kc = (t & 3) * 16;
        unsigned short h[16], l[16];
        #pragma unroll
        for (int j = 0; j < 16; ++j) bf16split(tile[kc + j][n], h[j], l[j]);
        uint4 hv0, hv1, lv0, lv1;
        hv0.x = (unsigned)h[0] | ((unsigned)h[1] << 16);  hv0.y = (unsigned)h[2] | ((unsigned)h[3] << 16);
        hv0.z = (unsigned)h[4] | ((unsigned)h[5] << 16);  hv0.w = (unsigned)h[6] | ((unsigned)h[7] << 16);
        hv1.x = (unsigned)h[8] | ((unsigned)h[9] << 16);  hv1.y = (unsigned)h[10] | ((unsigned)h[11] << 16);
        hv1.z = (unsigned)h[12] | ((unsigned)h[13] << 16); hv1.w = (unsigned)h[14] | ((unsigned)h[15] << 16);
        lv0.x = (unsigned)l[0] | ((unsigned)l[1] << 16);  lv0.y = (unsigned)l[2] | ((unsigned)l[3] << 16);
        lv0.z = (unsigned)l[4] | ((unsigned)l[5] << 16);  lv0.w = (unsigned)l[6] | ((unsigned)l[7] << 16);
        lv1.x = (unsigned)l[8] | ((unsigned)l[9] << 16);  lv1.y = (unsigned)l[10] | ((unsigned)l[11] << 16);
        lv1.z = (unsigned)l[12] | ((unsigned)l[13] << 16); lv1.w = (unsigned)l[14] | ((unsigned)l[15] << 16);
        size_t o = (size_t)(n0 + n) * K + k0 + kc;
        reinterpret_cast<uint4*>(&H[o])[0] = hv0; reinterpret_cast<uint4*>(&H[o])[1] = hv1;
        reinterpret_cast<uint4*>(&L[o])[0] = lv0; reinterpret_cast<uint4*>(&L[o])[1] = lv1;
    }
}

// ---- Q+K converter: qkv -> bf16 planes [bh][t][64] ----
__global__ __launch_bounds__(256) void cvt_qk_kernel(const float* __restrict__ qkv,
        unsigned short* __restrict__ Qh, unsigned short* __restrict__ Ql,
        unsigned short* __restrict__ Kh, unsigned short* __restrict__ Kl) {
    int t = blockIdx.x * 256 + threadIdx.x;
    int dg = t & 7;
    int s = (t >> 3) & (T - 1);
    int bh = t >> 14;                 // T*8 = 16384
    int b = bh / NH, h = bh % NH;
    const float* qs = qkv + (size_t)(b * T + s) * C3 + h * 64 + dg * 8;
    const float* ks = qs + 768;
    size_t o = ((size_t)bh * T + s) * 64 + dg * 8;
    #pragma unroll
    for (int which = 0; which < 2; ++which) {
        const float* src = (which == 0) ? qs : ks;
        float4 a0 = *reinterpret_cast<const float4*>(src);
        float4 a1 = *reinterpret_cast<const float4*>(src + 4);
        float f[8] = {a0.x, a0.y, a0.z, a0.w, a1.x, a1.y, a1.z, a1.w};
        unsigned short hh[8], ll[8];
        #pragma unroll
        for (int j = 0; j < 8; ++j) bf16split(f[j], hh[j], ll[j]);
        uint4 hv, lv;
        hv.x = (unsigned)hh[0] | ((unsigned)hh[1] << 16); hv.y = (unsigned)hh[2] | ((unsigned)hh[3] << 16);
        hv.z = (unsigned)hh[4] | ((unsigned)hh[5] << 16); hv.w = (unsigned)hh[6] | ((unsigned)hh[7] << 16);
        lv.x = (unsigned)ll[0] | ((unsigned)ll[1] << 16); lv.y = (unsigned)ll[2] | ((unsigned)ll[3] << 16);
        lv.z = (unsigned)ll[4] | ((unsigned)ll[5] << 16); lv.w = (unsigned)ll[6] | ((unsigned)ll[7] << 16);
        if (which == 0) {
            *reinterpret_cast<uint4*>(&Qh[o]) = hv;
            *reinterpret_cast<uint4*>(&Ql[o]) = lv;
        } else {
            *reinterpret_cast<uint4*>(&Kh[o]) = hv;
            *reinterpret_cast<uint4*>(&Kl[o]) = lv;
        }
    }
}

// ---- V converter (transposed): qkv V-part -> bf16 planes [bh][d][T] ----
__global__ __launch_bounds__(256) void cvt_kv_vt_kernel(const float* __restrict__ qkv,
        unsigned short* __restrict__ Vh, unsigned short* __restrict__ Vl) {
    __shared__ float tile[64][65];
    const int s0 = blockIdx.x * 64;
    const int bh = blockIdx.y;
    const int b = bh / NH, h = bh % NH;
    const int tid = threadIdx.x;
    {
        int r = tid >> 2, c0 = (tid & 3) * 16;
        const float* src = qkv + (size_t)(b * T + s0 + r) * C3 + 1536 + h * 64 + c0;
        #pragma unroll
        for (int u = 0; u < 4; ++u) {
            float4 w = *reinterpret_cast<const float4*>(src + u * 4);
            tile[r][c0 + u * 4 + 0] = w.x; tile[r][c0 + u * 4 + 1] = w.y;
            tile[r][c0 + u * 4 + 2] = w.z; tile[r][c0 + u * 4 + 3] = w.w;
        }
    }
    __syncthreads();
    {
        int d = tid >> 2, cs = (tid & 3) * 16;
        unsigned short hh[16], ll[16];
        #pragma unroll
        for (int j = 0; j < 16; ++j) bf16split(tile[cs + j][d], hh[j], ll[j]);
        uint4 hv0, hv1, lv0, lv1;
        hv0.x = (unsigned)hh[0] | ((unsigned)hh[1] << 16);  hv0.y = (unsigned)hh[2] | ((unsigned)hh[3] << 16);
        hv0.z = (unsigned)hh[4] | ((unsigned)hh[5] << 16);  hv0.w = (unsigned)hh[6] | ((unsigned)hh[7] << 16);
        hv1.x = (unsigned)hh[8] | ((unsigned)hh[9] << 16);  hv1.y = (unsigned)hh[10] | ((unsigned)hh[11] << 16);
        hv1.z = (unsigned)hh[12] | ((unsigned)hh[13] << 16); hv1.w = (unsigned)hh[14] | ((unsigned)hh[15] << 16);
        lv0.x = (unsigned)ll[0] | ((unsigned)ll[1] << 16);  lv0.y = (unsigned)ll[2] | ((unsigned)ll[3] << 16);
        lv0.z = (unsigned)ll[4] | ((unsigned)ll[5] << 16);  lv0.w = (unsigned)ll[6] | ((unsigned)ll[7] << 16);
        lv1.x = (unsigned)ll[8] | ((unsigned)ll[9] << 16);  lv1.y = (unsigned)ll[10] | ((unsigned)ll[11] << 16);
        lv1.z = (unsigned)ll[12] | ((unsigned)ll[13] << 16); lv1.w = (unsigned)ll[14] | ((unsigned)ll[15] << 16);
        size_t o = ((size_t)bh * 64 + d) * T + s0 + cs;
        reinterpret_cast<uint4*>(&Vh[o])[0] = hv0; reinterpret_cast<uint4*>(&Vh[o])[1] = hv1;
        reinterpret_cast<uint4*>(&Vl[o])[0] = lv0; reinterpret_cast<uint4*>(&Vl[o])[1] = lv1;
    }
}

// ---------------- split-bf16 MFMA GEMM: C = A*B + bias ----------------
#define LDST 40
__global__ __launch_bounds__(256) void gemm_mfma_kernel(
        const unsigned short* __restrict__ Ah, const unsigned short* __restrict__ Al,
        const unsigned short* __restrict__ Bh, const unsigned short* __restrict__ Bl,
        const float* __restrict__ bias, float* __restrict__ Cm,
        int M, int N, int K) {
    __shared__ unsigned short lA[2][128 * LDST];
    __shared__ unsigned short lB[2][128 * LDST];
    const int tid = threadIdx.x;
    const int bm = blockIdx.y * 128, bn = blockIdx.x * 128;
    const int lane = tid & 63, wid = tid >> 6;
    const int wr = wid >> 1, wc = wid & 1;
    f32x4 acc[4][4];
    #pragma unroll
    for (int i = 0; i < 4; ++i)
        #pragma unroll
        for (int j = 0; j < 4; ++j) acc[i][j] = (f32x4){0.f, 0.f, 0.f, 0.f};
    const int srow = tid >> 2, sk8 = (tid & 3) * 8;
    const int arb = wr * 64 + (lane & 15);
    const int brb = wc * 64 + (lane & 15);
    const int koff = (lane >> 4) * 8;
    for (int k0 = 0; k0 < K; k0 += 32) {
        __syncthreads();
        #pragma unroll
        for (int c = 0; c < 2; ++c) {
            int row = srow + 64 * c;
            uint4 va = *reinterpret_cast<const uint4*>(&Ah[(size_t)(bm + row) * K + k0 + sk8]);
            uint4 vb = *reinterpret_cast<const uint4*>(&Al[(size_t)(bm + row) * K + k0 + sk8]);
            uint4 vc = *reinterpret_cast<const uint4*>(&Bh[(size_t)(bn + row) * K + k0 + sk8]);
            uint4 vd = *reinterpret_cast<const uint4*>(&Bl[(size_t)(bn + row) * K + k0 + sk8]);
            *reinterpret_cast<uint4*>(&lA[0][row * LDST + sk8]) = va;
            *reinterpret_cast<uint4*>(&lA[1][row * LDST + sk8]) = vb;
            *reinterpret_cast<uint4*>(&lB[0][row * LDST + sk8]) = vc;
            *reinterpret_cast<uint4*>(&lB[1][row * LDST + sk8]) = vd;
        }
        __syncthreads();
        bf16x8 fa[2][4], fb[2][4];
        #pragma unroll
        for (int fi = 0; fi < 4; ++fi) {
            fa[0][fi] = *reinterpret_cast<const bf16x8*>(&lA[0][(arb + fi * 16) * LDST + koff]);
            fa[1][fi] = *reinterpret_cast<const bf16x8*>(&lA[1][(arb + fi * 16) * LDST + koff]);
            fb[0][fi] = *reinterpret_cast<const bf16x8*>(&lB[0][(brb + fi * 16) * LDST + koff]);
            fb[1][fi] = *reinterpret_cast<const bf16x8*>(&lB[1][(brb + fi * 16) * LDST + koff]);
        }
        #pragma unroll
        for (int fi = 0; fi < 4; ++fi)
            #pragma unroll
            for (int fj = 0; fj < 4; ++fj) {
                acc[fi][fj] = __builtin_amdgcn_mfma_f32_16x16x32_bf16(fa[0][fi], fb[0][fj], acc[fi][fj], 0, 0, 0);
                acc[fi][fj] = __builtin_amdgcn_mfma_f32_16x16x32_bf16(fa[0][fi], fb[1][fj], acc[fi][fj], 0, 0, 0);
                acc[fi][fj] = __builtin_amdgcn_mfma_f32_16x16x32_bf16(fa[1][fi], fb[0][fj], acc[fi][fj], 0, 0, 0);
            }
    }
    #pragma unroll
    for (int fj = 0; fj < 4; ++fj) {
        int col = bn + wc * 64 + fj * 16 + (lane & 15);
        float bv = bias[col];
        #pragma unroll
        for (int fi = 0; fi < 4; ++fi) {
            int row0 = bm + wr * 64 + fi * 16 + (lane >> 4) * 4;
            #pragma unroll
            for (int p = 0; p < 4; ++p)
                Cm[(size_t)(row0 + p) * N + col] = acc[fi][fj][p] + bv;
        }
    }
}

// ---------------- fp32 GEMM fallback (small ws) ----------------
__global__ __launch_bounds__(256) void gemm_bias_kernel(
        const float* __restrict__ A, const float* __restrict__ B,
        const float* __restrict__ bias, float* __restrict__ Cm,
        int M, int N, int K) {
    __shared__ float As[16][64];
    __shared__ float Bs[16][68];
    const int tid = threadIdx.x;
    const int ty = tid >> 4, tx = tid & 15;
    const int bm = blockIdx.y * 64, bn = blockIdx.x * 64;
    float acc[4][4] = {};
    for (int k0 = 0; k0 < K; k0 += 16) {
        {
            int r = tid >> 2;
            int kk = (tid & 3) * 4;
            float4 a = *reinterpret_cast<const float4*>(&A[(size_t)(bm + r) * K + k0 + kk]);
            As[kk + 0][r] = a.x; As[kk + 1][r] = a.y; As[kk + 2][r] = a.z; As[kk + 3][r] = a.w;
        }
        {
            int kk = tid >> 4;
            int c = (tid & 15) * 4;
            *reinterpret_cast<float4*>(&Bs[kk][c]) =
                *reinterpret_cast<const float4*>(&B[(size_t)(k0 + kk) * N + bn + c]);
        }
        __syncthreads();
        #pragma unroll
        for (int kk = 0; kk < 16; ++kk) {
            float4 a4 = *reinterpret_cast<const float4*>(&As[kk][ty * 4]);
            float4 b4 = *reinterpret_cast<const float4*>(&Bs[kk][tx * 4]);
            float av[4] = {a4.x, a4.y, a4.z, a4.w};
            float bv[4] = {b4.x, b4.y, b4.z, b4.w};
            #pragma unroll
            for (int i = 0; i < 4; ++i)
                #pragma unroll
                for (int j = 0; j < 4; ++j)
                    acc[i][j] = fmaf(av[i], bv[j], acc[i][j]);
        }
        __syncthreads();
    }
    #pragma unroll
    for (int i = 0; i < 4; ++i) {
        int row = bm + ty * 4 + i;
        #pragma unroll
        for (int j = 0; j < 4; ++j) {
            int col = bn + tx * 4 + j;
            Cm[(size_t)row * N + col] = acc[i][j] + bias[col];
        }
    }
}

#define FST 72   // LDS row stride (bf16), 144 B = 16B-aligned rows

// ---------------- s0 via MFMA: S = masked relu(head0 scores) ----------------
__global__ __launch_bounds__(256) void s0_mfma_kernel(
        const unsigned short* __restrict__ Qh, const unsigned short* __restrict__ Ql,
        const unsigned short* __restrict__ Kh, const unsigned short* __restrict__ Kl,
        float* __restrict__ S) {
    const int kb = blockIdx.x * 64, qb = blockIdx.y * 64, b = blockIdx.z;
    const int tid = threadIdx.x;
    float* Sb = S + (size_t)b * T * T;
    if (kb > qb) {  // entire tile masked -> zero
        const int ty = tid >> 4, tx = tid & 15;
        #pragma unroll
        for (int i = 0; i < 4; ++i) {
            float4 z = {0.f, 0.f, 0.f, 0.f};
            *reinterpret_cast<float4*>(&Sb[(size_t)(qb + ty * 4 + i) * T + kb + tx * 4]) = z;
        }
        return;
    }
    const int lane = tid & 63, w = tid >> 6;
    const int fr = lane & 15, fg = lane >> 4;
    __shared__ unsigned short Ks[2][64 * FST];
    const int hb0 = b * NH;   // head 0
    {
        const int sr = tid >> 2, sc0 = (tid & 3) * 16;
        const unsigned short* kh = Kh + ((size_t)hb0 * T + kb + sr) * 64 + sc0;
        const unsigned short* kl = Kl + ((size_t)hb0 * T + kb + sr) * 64 + sc0;
        uint4 a0 = reinterpret_cast<const uint4*>(kh)[0];
        uint4 a1 = reinterpret_cast<const uint4*>(kh)[1];
        uint4 b0 = reinterpret_cast<const uint4*>(kl)[0];
        uint4 b1 = reinterpret_cast<const uint4*>(kl)[1];
        *reinterpret_cast<uint4*>(&Ks[0][sr * FST + sc0 + 0]) = a0;
        *reinterpret_cast<uint4*>(&Ks[0][sr * FST + sc0 + 8]) = a1;
        *reinterpret_cast<uint4*>(&Ks[1][sr * FST + sc0 + 0]) = b0;
        *reinterpret_cast<uint4*>(&Ks[1][sr * FST + sc0 + 8]) = b1;
    }
    bf16x8 qh[2], ql[2];
    #pragma unroll
    for (int ks = 0; ks < 2; ++ks) {
        size_t qo = ((size_t)hb0 * T + qb + w * 16 + fr) * 64 + ks * 32 + fg * 8;
        qh[ks] = *reinterpret_cast<const bf16x8*>(&Qh[qo]);
        ql[ks] = *reinterpret_cast<const bf16x8*>(&Ql[qo]);
    }
    __syncthreads();
    f32x4 qk[4];
    #pragma unroll
    for (int fj = 0; fj < 4; ++fj) qk[fj] = (f32x4){0.f, 0.f, 0.f, 0.f};
    #pragma unroll
    for (int ks = 0; ks < 2; ++ks) {
        bf16x8 kbh[4], kbl[4];
        #pragma unroll
        for (int fj = 0; fj < 4; ++fj) {
            kbh[fj] = *reinterpret_cast<const bf16x8*>(&Ks[0][(fj * 16 + fr) * FST + ks * 32 + fg * 8]);
            kbl[fj] = *reinterpret_cast<const bf16x8*>(&Ks[1][(fj * 16 + fr) * FST + ks * 32 + fg * 8]);
        }
        #pragma unroll
        for (int fj = 0; fj < 4; ++fj) {
            qk[fj] = __builtin_amdgcn_mfma_f32_16x16x32_bf16(qh[ks], kbh[fj], qk[fj], 0, 0, 0);
            qk[fj] = __builtin_amdgcn_mfma_f32_16x16x32_bf16(qh[ks], kbl[fj], qk[fj], 0, 0, 0);
            qk[fj] = __builtin_amdgcn_mfma_f32_16x16x32_bf16(ql[ks], kbh[fj], qk[fj], 0, 0, 0);
        }
    }
    #pragma unroll
    for (int p = 0; p < 4; ++p) {
        int t = qb + w * 16 + fg * 4 + p;
        #pragma unroll
        for (int fj = 0; fj < 4; ++fj) {
            int s = kb + fj * 16 + fr;
            float v = qk[fj][p] * 0.125f;
            Sb[(size_t)t * T + s] = (s >= 1 && s < t) ? fmaxf(v, 0.0f) : 0.0f;
        }
    }
}

// ---------------- fp32 s0 fallback ----------------
__global__ __launch_bounds__(256) void s0_kernel(const float* __restrict__ qkv,
                                                 float* __restrict__ S) {
    const int kb = blockIdx.x * 64, qb = blockIdx.y * 64, b = blockIdx.z;
    const int tid = threadIdx.x, ty = tid >> 4, tx = tid & 15;
    float* Sb = S + (size_t)b * T * T;
    if (kb > qb) {
        #pragma unroll
        for (int i = 0; i < 4; ++i) {
            int row = qb + ty * 4 + i;
            float4 z = {0.f, 0.f, 0.f, 0.f};
            *reinterpret_cast<float4*>(&Sb[(size_t)row * T + kb + tx * 4]) = z;
        }
        return;
    }
    __shared__ float Qt[64][68];
    __shared__ float Kt[64][68];
    {
        int r = tid >> 2;
        int c0 = (tid & 3) * 16;
        const float* qrow = qkv + (size_t)(b * T + qb + r) * C3 + 0;
        const float* krow = qkv + (size_t)(b * T + kb + r) * C3 + 768;
        #pragma unroll
        for (int u = 0; u < 4; ++u) {
            float4 q4 = *reinterpret_cast<const float4*>(&qrow[c0 + u * 4]);
            float4 k4 = *reinterpret_cast<const float4*>(&krow[c0 + u * 4]);
            int d = c0 + u * 4;
            Qt[d + 0][r] = q4.x; Qt[d + 1][r] = q4.y; Qt[d + 2][r] = q4.z; Qt[d + 3][r] = q4.w;
            Kt[d + 0][r] = k4.x; Kt[d + 1][r] = k4.y; Kt[d + 2][r] = k4.z; Kt[d + 3][r] = k4.w;
        }
    }
    __syncthreads();
    float acc[4][4] = {};
    #pragma unroll
    for (int d = 0; d < 64; ++d) {
        float4 qv = *reinterpret_cast<const float4*>(&Qt[d][ty * 4]);
        float4 kv = *reinterpret_cast<const float4*>(&Kt[d][tx * 4]);
        float qa[4] = {qv.x, qv.y, qv.z, qv.w};
        float ka[4] = {kv.x, kv.y, kv.z, kv.w};
        #pragma unroll
        for (int i = 0; i < 4; ++i)
            #pragma unroll
            for (int j = 0; j < 4; ++j)
                acc[i][j] = fmaf(qa[i], ka[j], acc[i][j]);
    }
    #pragma unroll
    for (int i = 0; i < 4; ++i) {
        int t = qb + ty * 4 + i;
        float o[4];
        #pragma unroll
        for (int j = 0; j < 4; ++j) {
            int s = kb + tx * 4 + j;
            float v = acc[i][j] * 0.125f;
            o[j] = (s >= 1 && s < t) ? fmaxf(v, 0.0f) : 0.0f;
        }
        float4 o4 = {o[0], o[1], o[2], o[3]};
        *reinterpret_cast<float4*>(&Sb[(size_t)t * T + kb + tx * 4]) = o4;
    }
}

// ---------------- segmented scan: FF = cumsum_t(S) ----------------
__global__ __launch_bounds__(256) void colsum_kernel(const float* __restrict__ S,
                                                     float* __restrict__ Psum) {
    int s = blockIdx.x * 256 + threadIdx.x;
    int j = blockIdx.y, b = blockIdx.z;
    const float* Sb = S + (size_t)b * T * T;
    float sum = 0.f;
    for (int r = 0; r < 64; ++r) sum += Sb[(size_t)(j * 64 + r) * T + s];
    Psum[((size_t)b * 32 + j) * T + s] = sum;
}

__global__ __launch_bounds__(256) void scanseg_kernel(float* __restrict__ Psum) {
    int s = blockIdx.x * 256 + threadIdx.x;
    int b = blockIdx.y;
    float run = 0.f;
    for (int j = 0; j < 32; ++j) {
        size_t idx = ((size_t)b * 32 + j) * T + s;
        float v = Psum[idx];
        Psum[idx] = run;
        run += v;
    }
}

__global__ __launch_bounds__(256) void ffscan_kernel(float* __restrict__ S,
                                                     const float* __restrict__ Psum) {
    int s = blockIdx.x * 256 + threadIdx.x;
    int j = blockIdx.y, b = blockIdx.z;
    float run = Psum[((size_t)b * 32 + j) * T + s];
    float* Sb = S + (size_t)b * T * T;
    for (int r = 0; r < 64; ++r) {
        size_t idx = (size_t)(j * 64 + r) * T + s;
        run += Sb[idx];
        Sb[idx] = run;
    }
}

// ---------------- task table: 40 tasks/(b,h), size-descending ----------------
// Q-tiles of 128 rows (16 per (b,h)); k-chunks of <=8 64-tiles; Q<4 direct.
__device__ const int FTQ[40] = {15,15,15,15,14,14,14,13,13,13,12,12,12,11,11,11,10,10,9,9,8,8,7,7,6,5,4,3,14,10,6,2,13,9,5,1,12,8,4,0};
__device__ const int FK0[40] = {0,8,16,24,0,8,16,0,8,16,0,8,16,0,8,16,0,8,0,8,0,8,0,8,0,0,0,0,24,16,8,0,24,16,8,0,24,16,8,0};
__device__ const int FK1[40] = {8,16,24,32,8,16,24,8,16,24,8,16,24,8,16,24,8,16,8,16,8,16,8,16,8,8,8,8,30,22,14,6,28,20,12,4,26,18,10,2};
__device__ const int FCB[12] = {0,2,4,6,8,11,14,17,20,24,28,32};   // chunk base per Q-4

// ---------------- 32x32 swapped-operand MFMA flash attention ----------------
// grid (NB*NH, 40), 256 thr = 4 waves; each wave owns 32 q-rows (QBLK=128/block).
// Swapped QK: mfma(K, Q) -> lane holds ONE q-row's scores. Softmax = in-lane
// reduce + 1 shfl_xor(32). P stays in registers (bf16 hi/lo packs); PV B-frag
// other half via shfl_xor(32). PV: mfma(V^T, P) -> O in same per-q-row layout.
// LDS = K + V^T hi/lo only = 36,864 B. 2 barriers/tile.
__global__ __launch_bounds__(256) void flash_mfma_kernel(
        const unsigned short* __restrict__ Qh, const unsigned short* __restrict__ Ql,
        const unsigned short* __restrict__ Kh, const unsigned short* __restrict__ Kl,
        const unsigned short* __restrict__ Vth, const unsigned short* __restrict__ Vtl,
        const float* __restrict__ FF, float* __restrict__ Y,
        float* __restrict__ PART) {
    const int hb = blockIdx.x;
    const int h = hb % NH, b = hb / NH;
    const int u = blockIdx.y;
    const int tq = FTQ[u], kt0 = FK0[u], kt1 = FK1[u];
    const int qb = tq * 128;
    const int tid = threadIdx.x;
    const int lane = tid & 63, w = tid >> 6;
    const int q31 = lane & 31, hi = lane >> 5;
    const int trow = qb + w * 32 + q31;      // this lane's q-row (absolute t)
    __shared__ unsigned short KS[2][64 * FST];   // K [s][d] hi/lo
    __shared__ unsigned short VS[2][64 * FST];   // V^T [d][s] hi/lo

    // Q fragments (B operand): row q31, k = dblk*16 + hi*8 + e
    bf16x8 qfh[4], qfl[4];
    #pragma unroll
    for (int dblk = 0; dblk < 4; ++dblk) {
        size_t qo = ((size_t)hb * T + trow) * 64 + dblk * 16 + hi * 8;
        qfh[dblk] = *reinterpret_cast<const bf16x8*>(&Qh[qo]);
        qfl[dblk] = *reinterpret_cast<const bf16x8*>(&Ql[qo]);
    }

    f32x16 oacc0 = (f32x16)(0.f), oacc1 = (f32x16)(0.f);
    float m = -1e30f, l = 0.f;
    const float* FFb = FF + (size_t)b * T * T;
    const int sr = tid >> 2, sc0 = (tid & 3) * 16;

    for (int kt = kt0; kt < kt1; ++kt) {
        const int kb = kt * 64;
        __syncthreads();
        {   // stage K [s][d] and V^T [d][s], hi/lo
            const unsigned short* ksrc = Kh + ((size_t)hb * T + kb + sr) * 64 + sc0;
            const unsigned short* ksrl = Kl + ((size_t)hb * T + kb + sr) * 64 + sc0;
            const unsigned short* vsrc = Vth + ((size_t)hb * 64 + sr) * T + kb + sc0;
            const unsigned short* vsrl = Vtl + ((size_t)hb * 64 + sr) * T + kb + sc0;
            uint4 k0v = reinterpret_cast<const uint4*>(ksrc)[0];
            uint4 k1v = reinterpret_cast<const uint4*>(ksrc)[1];
            uint4 k2v = reinterpret_cast<const uint4*>(ksrl)[0];
            uint4 k3v = reinterpret_cast<const uint4*>(ksrl)[1];
            uint4 v0v = reinterpret_cast<const uint4*>(vsrc)[0];
            uint4 v1v = reinterpret_cast<const uint4*>(vsrc)[1];
            uint4 v2v = reinterpret_cast<const uint4*>(vsrl)[0];
            uint4 v3v = reinterpret_cast<const uint4*>(vsrl)[1];
            *reinterpret_cast<uint4*>(&KS[0][sr * FST + sc0 + 0]) = k0v;
            *reinterpret_cast<uint4*>(&KS[0][sr * FST + sc0 + 8]) = k1v;
            *reinterpret_cast<uint4*>(&KS[1][sr * FST + sc0 + 0]) = k2v;
            *reinterpret_cast<uint4*>(&KS[1][sr * FST + sc0 + 8]) = k3v;
            *reinterpret_cast<uint4*>(&VS[0][sr * FST + sc0 + 0]) = v0v;
            *reinterpret_cast<uint4*>(&VS[0][sr * FST + sc0 + 8]) = v1v;
            *reinterpret_cast<uint4*>(&VS[1][sr * FST + sc0 + 0]) = v2v;
            *reinterpret_cast<uint4*>(&VS[1][sr * FST + sc0 + 8]) = v3v;
        }
        __syncthreads();
        // ---- QK^T (swapped): acc[sb] = mfma32(K, Q): D[s][q], q = q31 ----
        f32x16 acc[2];
        acc[0] = (f32x16)(0.f); acc[1] = (f32x16)(0.f);
        #pragma unroll
        for (int sb = 0; sb < 2; ++sb) {
            #pragma unroll
            for (int dblk = 0; dblk < 4; ++dblk) {
                bf16x8 kfh = *reinterpret_cast<const bf16x8*>(&KS[0][(sb * 32 + q31) * FST + dblk * 16 + hi * 8]);
                bf16x8 kfl = *reinterpret_cast<const bf16x8*>(&KS[1][(sb * 32 + q31) * FST + dblk * 16 + hi * 8]);
                acc[sb] = __builtin_amdgcn_mfma_f32_32x32x16_bf16(kfh, qfh[dblk], acc[sb], 0, 0, 0);
                acc[sb] = __builtin_amdgcn_mfma_f32_32x32x16_bf16(kfh, qfl[dblk], acc[sb], 0, 0, 0);
                acc[sb] = __builtin_amdgcn_mfma_f32_32x32x16_bf16(kfl, qfh[dblk], acc[sb], 0, 0, 0);
            }
        }
        // ---- scores: lane holds row trow, s = kb + sb*32 + (r&3)+8*(r>>2)+4*hi ----
        float pv[2][16];
        #pragma unroll
        for (int sb = 0; sb < 2; ++sb) {
            #pragma unroll
            for (int g = 0; g < 4; ++g) {
                float4 f4 = *reinterpret_cast<const float4*>(
                    &FFb[(size_t)trow * T + kb + sb * 32 + g * 8 + hi * 4]);
                float fv[4] = {f4.x, f4.y, f4.z, f4.w};
                #pragma unroll
                for (int a = 0; a < 4; ++a) {
                    int r = g * 4 + a;
                    int s = kb + sb * 32 + a + g * 8 + hi * 4;
                    float val = acc[sb][r] * 0.125f - fv[a];
                    pv[sb][r] = (s <= trow) ? val : -1e30f;
                }
            }
        }
        // ---- online softmax: in-lane over 32 + one xor-32 exchange ----
        float tm = pv[0][0];
        #pragma unroll
        for (int sb = 0; sb < 2; ++sb)
            #pragma unroll
            for (int r = 0; r < 16; ++r) tm = fmaxf(tm, pv[sb][r]);
        tm = fmaxf(tm, __shfl_xor(tm, 32));
        float mn = fmaxf(m, tm);
        float scale = __expf(m - mn);
        float rs = 0.f;
        #pragma unroll
        for (int sb = 0; sb < 2; ++sb)
            #pragma unroll
            for (int r = 0; r < 16; ++r) {
                float pe = __expf(pv[sb][r] - mn);
                pv[sb][r] = pe; rs += pe;
            }
        rs += __shfl_xor(rs, 32);
        l = l * scale + rs;
        m = mn;
        oacc0 *= scale; oacc1 *= scale;
        // ---- pack P to bf16 hi/lo words: wh[sb][bq][h2] = P(s32 = 8bq+4hi+2h2 +{0,1}) ----
        unsigned wh[2][4][2], wl[2][4][2];
        #pragma unroll
        for (int sb = 0; sb < 2; ++sb)
            #pragma unroll
            for (int bq = 0; bq < 4; ++bq)
                #pragma unroll
                for (int h2 = 0; h2 < 2; ++h2)
                    packP(pv[sb][4 * bq + 2 * h2], pv[sb][4 * bq + 2 * h2 + 1],
                          wh[sb][bq][h2], wl[sb][bq][h2]);
        // ---- PV: B-frag[kk] assembled from own + lane^32 words ----
        #pragma unroll
        for (int kk = 0; kk < 4; ++kk) {
            const int sb = kk >> 1;
            const int b0 = 2 * (kk & 1), b1 = b0 + 1;
            unsigned sh_b1_0 = (unsigned)__shfl_xor((int)wh[sb][b1][0], 32);
            unsigned sh_b1_1 = (unsigned)__shfl_xor((int)wh[sb][b1][1], 32);
            unsigned sh_b0_0 = (unsigned)__shfl_xor((int)wh[sb][b0][0], 32);
            unsigned sh_b0_1 = (unsigned)__shfl_xor((int)wh[sb][b0][1], 32);
            unsigned sl_b1_0 = (unsigned)__shfl_xor((int)wl[sb][b1][0], 32);
            unsigned sl_b1_1 = (unsigned)__shfl_xor((int)wl[sb][b1][1], 32);
            unsigned sl_b0_0 = (unsigned)__shfl_xor((int)wl[sb][b0][0], 32);
            unsigned sl_b0_1 = (unsigned)__shfl_xor((int)wl[sb][b0][1], 32);
            u32x4 th, tl;
            th[0] = hi ? sh_b1_0 : wh[sb][b0][0];
            th[1] = hi ? sh_b1_1 : wh[sb][b0][1];
            th[2] = hi ? wh[sb][b1][0] : sh_b0_0;
            th[3] = hi ? wh[sb][b1][1] : sh_b0_1;
            tl[0] = hi ? sl_b1_0 : wl[sb][b0][0];
            tl[1] = hi ? sl_b1_1 : wl[sb][b0][1];
            tl[2] = hi ? wl[sb][b1][0] : sl_b0_0;
            tl[3] = hi ? wl[sb][b1][1] : sl_b0_1;
            bf16x8 pbh = __builtin_bit_cast(bf16x8, th);
            bf16x8 pbl = __builtin_bit_cast(bf16x8, tl);
            {   // db = 0
                bf16x8 vfh = *reinterpret_cast<const bf16x8*>(&VS[0][(q31) * FST + kk * 16 + hi * 8]);
                bf16x8 vfl = *reinterpret_cast<const bf16x8*>(&VS[1][(q31) * FST + kk * 16 + hi * 8]);
                oacc0 = __builtin_amdgcn_mfma_f32_32x32x16_bf16(vfh, pbh, oacc0, 0, 0, 0);
                oacc0 = __builtin_amdgcn_mfma_f32_32x32x16_bf16(vfh, pbl, oacc0, 0, 0, 0);
                oacc0 = __builtin_amdgcn_mfma_f32_32x32x16_bf16(vfl, pbh, oacc0, 0, 0, 0);
            }
            {   // db = 1
                bf16x8 vfh = *reinterpret_cast<const bf16x8*>(&VS[0][(32 + q31) * FST + kk * 16 + hi * 8]);
                bf16x8 vfl = *reinterpret_cast<const bf16x8*>(&VS[1][(32 + q31) * FST + kk * 16 + hi * 8]);
                oacc1 = __builtin_amdgcn_mfma_f32_32x32x16_bf16(vfh, pbh, oacc1, 0, 0, 0);
                oacc1 = __builtin_amdgcn_mfma_f32_32x32x16_bf16(vfh, pbl, oacc1, 0, 0, 0);
                oacc1 = __builtin_amdgcn_mfma_f32_32x32x16_bf16(vfl, pbh, oacc1, 0, 0, 0);
            }
        }
    }
    // ---- epilogue: oaccN[r] = O[q=trow][d = N*32 + (r&3)+8*(r>>2)+4*hi] ----
    if (tq < 4) {   // direct normalized write
        float inv = 1.f / l;
        float* Yrow = Y + (size_t)(b * T + trow) * CE + h * 64;
        #pragma unroll
        for (int g = 0; g < 4; ++g) {
            float4 o0 = {oacc0[4 * g + 0] * inv, oacc0[4 * g + 1] * inv,
                         oacc0[4 * g + 2] * inv, oacc0[4 * g + 3] * inv};
            float4 o1 = {oacc1[4 * g + 0] * inv, oacc1[4 * g + 1] * inv,
                         oacc1[4 * g + 2] * inv, oacc1[4 * g + 3] * inv};
            *reinterpret_cast<float4*>(&Yrow[g * 8 + hi * 4]) = o0;
            *reinterpret_cast<float4*>(&Yrow[32 + g * 8 + hi * 4]) = o1;
        }
    } else {        // partial chunk: unnormalized O + (m,l)
        const int ci = FCB[tq - 4] + (kt0 >> 3);
        float* Ob = PART + (size_t)(hb * 36 + ci) * 8448;
        const int rr = w * 32 + q31;
        #pragma unroll
        for (int g = 0; g < 4; ++g) {
            float4 o0 = {oacc0[4 * g + 0], oacc0[4 * g + 1], oacc0[4 * g + 2], oacc0[4 * g + 3]};
            float4 o1 = {oacc1[4 * g + 0], oacc1[4 * g + 1], oacc1[4 * g + 2], oacc1[4 * g + 3]};
            *reinterpret_cast<float4*>(&Ob[rr * 64 + g * 8 + hi * 4]) = o0;
            *reinterpret_cast<float4*>(&Ob[rr * 64 + 32 + g * 8 + hi * 4]) = o1;
        }
        if (hi == 0) { Ob[8192 + rr] = m; Ob[8192 + 128 + rr] = l; }
    }
}

// ---------------- merge 2..4 chunk partials per 128-row block (Q >= 4) ----------------
__global__ __launch_bounds__(256) void merge128_kernel(const float* __restrict__ PART,
                                                       float* __restrict__ Y) {
    const int hb = blockIdx.x;          // 0..23
    const int tq = 4 + blockIdx.y;      // 4..15
    const int h = hb % NH, b = hb / NH;
    const int nch = (tq >= 12) ? 4 : (tq >= 8) ? 3 : 2;
    const float* base = PART + (size_t)(hb * 36 + FCB[tq - 4]) * 8448;
    const int tid = threadIdx.x;
    const int r = tid >> 1, half = tid & 1;
    float mm[4], la[4];
    float M = -1e30f;
    #pragma unroll
    for (int c = 0; c < 4; ++c) {
        int cc = (c < nch) ? c : 0;
        float mv = base[(size_t)cc * 8448 + 8192 + r];
        float lv = base[(size_t)cc * 8448 + 8192 + 128 + r];
        mm[c] = (c < nch) ? mv : -1e30f;
        la[c] = (c < nch) ? lv : 0.f;
        M = fmaxf(M, mm[c]);
    }
    float a[4], L = 0.f;
    #pragma unroll
    for (int c = 0; c < 4; ++c) {
        a[c] = (c < nch) ? __expf(mm[c] - M) : 0.f;
        L += a[c] * la[c];
    }
    float inv = 1.f / L;
    const int t = tq * 128 + r;
    float* Yrow = Y + (size_t)(b * T + t) * CE + h * 64 + half * 32;
    #pragma unroll
    for (int uu = 0; uu < 8; ++uu) {
        float ax = 0.f, ay = 0.f, az = 0.f, aw = 0.f;
        #pragma unroll
        for (int c = 0; c < 4; ++c) {
            int cc = (c < nch) ? c : 0;
            float4 x = *reinterpret_cast<const float4*>(
                &base[(size_t)cc * 8448 + r * 64 + half * 32 + uu * 4]);
            ax += a[c] * x.x; ay += a[c] * x.y; az += a[c] * x.z; aw += a[c] * x.w;
        }
        float4 y = {ax * inv, ay * inv, az * inv, aw * inv};
        *reinterpret_cast<float4*>(&Yrow[uu * 4]) = y;
    }
}

// ---------------- fp32 flash fallback (small ws) ----------------
__global__ __launch_bounds__(256) void flash_kernel(const float* __restrict__ qkv,
                                                    const float* __restrict__ FF,
                                                    float* __restrict__ Y,
                                                    float* __restrict__ PO,
                                                    float* __restrict__ PML,
                                                    int split) {
    const int hb = blockIdx.x;
    const int h = hb % NH, b = hb / NH;
    int qt, kt0, kt1, mode;
    if (split) {
        const int u = blockIdx.y;
        if (u < 16)      { qt = 16 + u; kt0 = 0;  kt1 = 16;     mode = 1; }
        else if (u < 32) { qt = 31 - u; kt0 = 0;  kt1 = qt + 1; mode = 0; }
        else             { qt = 63 - u; kt0 = 16; kt1 = qt + 1; mode = 2; }
    } else {
        qt = 31 - blockIdx.y; kt0 = 0; kt1 = qt + 1; mode = 0;
    }
    const int qb = qt * 64;
    const int tid = threadIdx.x, ty = tid >> 4, tx = tid & 15;
    __shared__ float Qt[64][68];
    __shared__ float KtPs[64][68];
    __shared__ float Vs[64][68];
    const int r = tid >> 2, c0 = (tid & 3) * 16;
    {
        const float* qrow = qkv + (size_t)(b * T + qb + r) * C3 + h * 64;
        #pragma unroll
        for (int u = 0; u < 4; ++u) {
            float4 q4 = *reinterpret_cast<const float4*>(&qrow[c0 + u * 4]);
            int d = c0 + u * 4;
            Qt[d + 0][r] = q4.x; Qt[d + 1][r] = q4.y; Qt[d + 2][r] = q4.z; Qt[d + 3][r] = q4.w;
        }
    }
    float m[4], l[4], O[4][4];
    #pragma unroll
    for (int i = 0; i < 4; ++i) {
        m[i] = -1e30f; l[i] = 0.f;
        #pragma unroll
        for (int j = 0; j < 4; ++j) O[i][j] = 0.f;
    }
    const float* FFb = FF + (size_t)b * T * T;
    for (int kt = kt0; kt < kt1; ++kt) {
        const int kb = kt * 64;
        __syncthreads();
        {
            const float* krow = qkv + (size_t)(b * T + kb + r) * C3 + 768 + h * 64;
            const float* vrow = qkv + (size_t)(b * T + kb + r) * C3 + 1536 + h * 64;
            #pragma unroll
            for (int u = 0; u < 4; ++u) {
                float4 k4 = *reinterpret_cast<const float4*>(&krow[c0 + u * 4]);
                int d = c0 + u * 4;
                KtPs[d + 0][r] = k4.x; KtPs[d + 1][r] = k4.y;
                KtPs[d + 2][r] = k4.z; KtPs[d + 3][r] = k4.w;
                *reinterpret_cast<float4*>(&Vs[r][c0 + u * 4]) =
                    *reinterpret_cast<const float4*>(&vrow[c0 + u * 4]);
            }
        }
        __syncthreads();
        float sc[4][4] = {};
        #pragma unroll
        for (int d = 0; d < 64; ++d) {
            float4 qv = *reinterpret_cast<const float4*>(&Qt[d][ty * 4]);
            float4 kv = *reinterpret_cast<const float4*>(&KtPs[d][tx * 4]);
            float qa[4] = {qv.x, qv.y, qv.z, qv.w};
            float ka[4] = {kv.x, kv.y, kv.z, kv.w};
            #pragma unroll
            for (int i = 0; i < 4; ++i)
                #pragma unroll
                for (int j = 0; j < 4; ++j)
                    sc[i][j] = fmaf(qa[i], ka[j], sc[i][j]);
        }
        #pragma unroll
        for (int i = 0; i < 4; ++i) {
            int t = qb + ty * 4 + i;
            float4 f4 = *reinterpret_cast<const float4*>(&FFb[(size_t)t * T + kb + tx * 4]);
            float fv[4] = {f4.x, f4.y, f4.z, f4.w};
            #pragma unroll
            for (int j = 0; j < 4; ++j) {
                int s = kb + tx * 4 + j;
                float v = sc[i][j] * 0.125f - fv[j];
                sc[i][j] = (s <= t) ? v : -1e30f;
            }
        }
        #pragma unroll
        for (int i = 0; i < 4; ++i) {
            float tm = fmaxf(fmaxf(sc[i][0], sc[i][1]), fmaxf(sc[i][2], sc[i][3]));
            tm = fmaxf(tm, __shfl_xor(tm, 1));
            tm = fmaxf(tm, __shfl_xor(tm, 2));
            tm = fmaxf(tm, __shfl_xor(tm, 4));
            tm = fmaxf(tm, __shfl_xor(tm, 8));
            float mn = fmaxf(m[i], tm);
            float scale = __expf(m[i] - mn);
            float rs = 0.f;
            #pragma unroll
            for (int j = 0; j < 4; ++j) {
                float p = __expf(sc[i][j] - mn);
                sc[i][j] = p; rs += p;
            }
            rs += __shfl_xor(rs, 1); rs += __shfl_xor(rs, 2);
            rs += __shfl_xor(rs, 4); rs += __shfl_xor(rs, 8);
            l[i] = l[i] * scale + rs;
            m[i] = mn;
            #pragma unroll
            for (int j = 0; j < 4; ++j) O[i][j] *= scale;
        }
        __syncthreads();
        #pragma unroll
        for (int i = 0; i < 4; ++i) {
            float4 p4 = {sc[i][0], sc[i][1], sc[i][2], sc[i][3]};
            *reinterpret_cast<float4*>(&KtPs[ty * 4 + i][tx * 4]) = p4;
        }
        __syncthreads();
        #pragma unroll
        for (int j4 = 0; j4 < 16; ++j4) {
            float pvv[4][4];
            #pragma unroll
            for (int i = 0; i < 4; ++i) {
                float4 t4 = *reinterpret_cast<const float4*>(&KtPs[ty * 4 + i][j4 * 4]);
                pvv[i][0] = t4.x; pvv[i][1] = t4.y; pvv[i][2] = t4.z; pvv[i][3] = t4.w;
            }
            #pragma unroll
            for (int jj = 0; jj < 4; ++jj) {
                float4 v4 = *reinterpret_cast<const float4*>(&Vs[j4 * 4 + jj][tx * 4]);
                float vv[4] = {v4.x, v4.y, v4.z, v4.w};
                #pragma unroll
                for (int i = 0; i < 4; ++i)
                    #pragma unroll
                    for (int dd = 0; dd < 4; ++dd)
                        O[i][dd] = fmaf(pvv[i][jj], vv[dd], O[i][dd]);
            }
        }
    }
    if (mode == 0) {
        #pragma unroll
        for (int i = 0; i < 4; ++i) {
            int t = qb + ty * 4 + i;
            float inv = 1.f / l[i];
            float4 o4 = {O[i][0] * inv, O[i][1] * inv, O[i][2] * inv, O[i][3] * inv};
            *reinterpret_cast<float4*>(&Y[(size_t)(b * T + t) * CE + h * 64 + tx * 4]) = o4;
        }
    } else {
        const int pidx = (b * NH + h) * 16 + (qt - 16);
        float* Ob  = PO  + (size_t)(mode - 1) * (NB * NH * 16 * 4096) + (size_t)pidx * 4096;
        float* mlb = PML + (size_t)(mode - 1) * (NB * NH * 16 * 128)  + (size_t)pidx * 128;
        #pragma unroll
        for (int i = 0; i < 4; ++i) {
            int rr = ty * 4 + i;
            float4 o4 = {O[i][0], O[i][1], O[i][2], O[i][3]};
            *reinterpret_cast<float4*>(&Ob[rr * 64 + tx * 4]) = o4;
            if (tx == 0) { mlb[rr] = m[i]; mlb[64 + rr] = l[i]; }
        }
    }
}

// ---------------- merge the two split-K partials (fp32 fallback path) ----------------
__global__ __launch_bounds__(256) void merge_kernel(const float* __restrict__ PO,
                                                    const float* __restrict__ PML,
                                                    float* __restrict__ Y) {
    const int p = blockIdx.x;
    const int q16 = p & 15;
    const int hb = p >> 4;
    const int h = hb % NH, b = hb / NH;
    const int qt = 16 + q16;
    const float* O0  = PO  + (size_t)p * 4096;
    const float* O1  = PO  + (size_t)(NB * NH * 16) * 4096 + (size_t)p * 4096;
    const float* ml0 = PML + (size_t)p * 128;
    const float* ml1 = PML + (size_t)(NB * NH * 16) * 128  + (size_t)p * 128;
    const int tid = threadIdx.x;
    const int r = tid >> 2, c0 = (tid & 3) * 16;
    float m0 = ml0[r], l0 = ml0[64 + r];
    float m1 = ml1[r], l1 = ml1[64 + r];
    float M  = fmaxf(m0, m1);
    float a0 = __expf(m0 - M), a1 = __expf(m1 - M);
    float inv = 1.f / (a0 * l0 + a1 * l1);
    const int t = qt * 64 + r;
    float* Yrow = Y + (size_t)(b * T + t) * CE + h * 64;
    #pragma unroll
    for (int u = 0; u < 4; ++u) {
        float4 x0 = *reinterpret_cast<const float4*>(&O0[r * 64 + c0 + u * 4]);
        float4 x1 = *reinterpret_cast<const float4*>(&O1[r * 64 + c0 + u * 4]);
        float4 y;
        y.x = (a0 * x0.x + a1 * x1.x) * inv;
        y.y = (a0 * x0.y + a1 * x1.y) * inv;
        y.z = (a0 * x0.z + a1 * x1.z) * inv;
        y.w = (a0 * x0.w + a1 * x1.w) * inv;
        *reinterpret_cast<float4*>(&Yrow[c0 + u * 4]) = y;
    }
}

extern "C" void kernel_launch(void* const* d_in, const int* in_sizes, int n_in,
                              void* d_out, int out_size, void* d_ws, size_t ws_size,
                              hipStream_t stream) {
    const float* x      = (const float*)d_in[0];
    const float* W_attn = (const float*)d_in[1];
    const float* b_attn = (const float*)d_in[2];
    const float* W_proj = (const float*)d_in[3];
    const float* b_proj = (const float*)d_in[4];
    float* out = (float*)d_out;

    char* ws = (char*)d_ws;
    const size_t QKV_BYTES = (size_t)NB * T * C3 * 4;       // 37,748,736
    const size_t S_BYTES   = (size_t)NB * T * T * 4;        // 33,554,432
    const size_t P_BYTES   = (size_t)NB * 32 * T * 4;       //    524,288
    const size_t Y_BYTES   = (size_t)NB * T * CE * 4;       // 12,582,912
    const size_t PO_BYTES  = (size_t)2 * NB * NH * 16 * 4096 * 4;  // 12,582,912
    const size_t PML_BYTES = (size_t)2 * NB * NH * 16 * 128 * 4;   //    393,216
    const size_t PLANE_X   = (size_t)NB * T * CE * 2;       // 6,291,456
    const size_t PLANE_WA  = (size_t)C3 * CE * 2;           // 3,538,944
    const size_t PLANE_WP  = (size_t)CE * CE * 2;           // 1,179,648
    const size_t PLANE_KV  = (size_t)NB * NH * T * 64 * 2;  // 6,291,456

    const size_t U_OFF  = QKV_BYTES + S_BYTES + P_BYTES + Y_BYTES;
    const size_t U_SIZE = PO_BYTES + PML_BYTES;
    const size_t W_OFF  = U_OFF + U_SIZE;
    const size_t KV_OFF = W_OFF + 2 * PLANE_WA + 2 * PLANE_WP;

    float* qkv  = (float*)ws;                               // reused as PART during MFMA flash
    float* S    = (float*)(ws + QKV_BYTES);
    float* Psum = (float*)(ws + QKV_BYTES + S_BYTES);
    float* Yb   = (float*)(ws + QKV_BYTES + S_BYTES + P_BYTES);
    float* PO   = (float*)(ws + U_OFF);
    float* PML  = (float*)(ws + U_OFF + PO_BYTES);
    unsigned short* Xh  = (unsigned short*)(ws + U_OFF);    // X planes, then Q planes, then Y planes
    unsigned short* Xl  = (unsigned short*)(ws + U_OFF + PLANE_X);
    unsigned short* Qhp = Xh;
    unsigned short* Qlp = Xl;
    unsigned short* Yh  = Xh;
    unsigned short* Yl  = Xl;
    unsigned short* WAh = (unsigned short*)(ws + W_OFF);
    unsigned short* WAl = (unsigned short*)(ws + W_OFF + PLANE_WA);
    unsigned short* WPh = (unsigned short*)(ws + W_OFF + 2 * PLANE_WA);
    unsigned short* WPl = (unsigned short*)(ws + W_OFF + 2 * PLANE_WA + PLANE_WP);
    unsigned short* Khp = (unsigned short*)(ws + KV_OFF);
    unsigned short* Klp = (unsigned short*)(ws + KV_OFF + PLANE_KV);
    unsigned short* VTh = (unsigned short*)(ws + KV_OFF + 2 * PLANE_KV);
    unsigned short* VTl = (unsigned short*)(ws + KV_OFF + 3 * PLANE_KV);
    float* PART = qkv;   // 24*36*8448*4 B = 29.2MB <= QKV_BYTES; qkv dead during flash

    const size_t NEED_SPLIT = U_OFF + U_SIZE;
    const size_t NEED_MFMA  = KV_OFF;
    const size_t NEED_KV    = KV_OFF + 4 * PLANE_KV;
    const int split = (ws_size >= NEED_SPLIT) ? 1 : 0;
    const int mfma  = (ws_size >= NEED_MFMA) ? 1 : 0;
    const int kv    = (ws_size >= NEED_KV && mfma) ? 1 : 0;

    const int M = NB * T;  // 4096

    // 1) qkv = x @ W_attn + b_attn
    if (mfma) {
        cvt_split_T_kernel<<<dim3(C3 / 64, CE / 64), 256, 0, stream>>>(W_attn, WAh, WAl, CE, C3);
        cvt_split_T_kernel<<<dim3(CE / 64, CE / 64), 256, 0, stream>>>(W_proj, WPh, WPl, CE, CE);
        cvt_split_kernel<<<dim3((M * CE / 8) / 256), 256, 0, stream>>>(x, Xh, Xl);
        gemm_mfma_kernel<<<dim3(C3 / 128, M / 128), 256, 0, stream>>>(Xh, Xl, WAh, WAl, b_attn, qkv, M, C3, CE);
    } else {
        gemm_bias_kernel<<<dim3(C3 / 64, M / 64), 256, 0, stream>>>(x, W_attn, b_attn, qkv, M, C3, CE);
    }
    // 2) Q/K/V -> bf16 planes (kv path); S = masked relu(head0 scores)
    if (kv) {
        cvt_qk_kernel<<<dim3((NB * NH * T * 8) / 256), 256, 0, stream>>>(qkv, Qhp, Qlp, Khp, Klp);
        cvt_kv_vt_kernel<<<dim3(T / 64, NB * NH), 256, 0, stream>>>(qkv, VTh, VTl);
        s0_mfma_kernel<<<dim3(T / 64, T / 64, NB), 256, 0, stream>>>(Qhp, Qlp, Khp, Klp, S);
    } else {
        s0_kernel<<<dim3(T / 64, T / 64, NB), 256, 0, stream>>>(qkv, S);
    }
    // 3) FF = cumsum_t(S)  (segmented scan, in place)
    colsum_kernel<<<dim3(T / 256, 32, NB), 256, 0, stream>>>(S, Psum);
    scanseg_kernel<<<dim3(T / 256, NB), 256, 0, stream>>>(Psum);
    ffscan_kernel<<<dim3(T / 256, 32, NB), 256, 0, stream>>>(S, Psum);
    // 4) flash attention with bias -FF
    if (kv) {
        flash_mfma_kernel<<<dim3(NB * NH, 40), 256, 0, stream>>>(Qhp, Qlp, Khp, Klp, VTh, VTl, S, Yb, PART);
        merge128_kernel<<<dim3(NB * NH, 12), 256, 0, stream>>>(PART, Yb);
    } else if (split) {
        flash_kernel<<<dim3(NB * NH, 48), 256, 0, stream>>>(qkv, S, Yb, PO, PML, 1);
        merge_kernel<<<dim3(NB * NH * 16), 256, 0, stream>>>(PO, PML, Yb);
    } else {
        flash_kernel<<<dim3(NB * NH, 32), 256, 0, stream>>>(qkv, S, Yb, PO, PML, 0);
    }
    // 5) out = Y @ W_proj + b_proj
    if (mfma) {
        cvt_split_kernel<<<dim3((M * CE / 8) / 256), 256, 0, stream>>>(Yb, Yh, Yl);
        gemm_mfma_kernel<<<dim3(CE / 128, M / 128), 256, 0, stream>>>(Yh, Yl, WPh, WPl, b_proj, out, M, CE, CE);
    } else {
        gemm_bias_kernel<<<dim3(CE / 64, M / 64), 256, 0, stream>>>(Yb, W_proj, b_proj, out, M, CE, CE);
    }
}

// Round 7
// 251.553 us; speedup vs baseline: 1.1787x; 1.0355x over previous
//
#include <hip/hip_runtime.h>
#include <math.h>

#define T 2048
#define NH 12
#define HD 64
#define C3 2304   // 3*768
#define CE 768
#define NB 2

typedef __attribute__((ext_vector_type(8))) short bf16x8;
typedef __attribute__((ext_vector_type(4))) float f32x4;
typedef __attribute__((ext_vector_type(16))) float f32x16;
typedef __attribute__((ext_vector_type(4))) unsigned u32x4;

// ---------------- fp32 -> (hi,lo) bf16 split, RNE both halves ----------------
__device__ inline void bf16split(float a, unsigned short& h, unsigned short& l) {
    unsigned int u = __float_as_uint(a);
    unsigned int r = (u + 0x7FFFu + ((u >> 16) & 1u)) >> 16;
    h = (unsigned short)r;
    float hf = __uint_as_float(r << 16);
    float lo = a - hf;                      // exact (Sterbenz)
    unsigned int v = __float_as_uint(lo);
    l = (unsigned short)((v + 0x7FFFu + ((v >> 16) & 1u)) >> 16);
}

__device__ inline void packP(float a, float b, unsigned& wh, unsigned& wl) {
    unsigned short ha, la, hb, lb;
    bf16split(a, ha, la); bf16split(b, hb, lb);
    wh = (unsigned)ha | ((unsigned)hb << 16);
    wl = (unsigned)la | ((unsigned)lb << 16);
}

// A-side converter: fp32 [R][C] -> bf16 planes H,L (same layout). total/8 threads.
__global__ __launch_bounds__(256) void cvt_split_kernel(const float* __restrict__ A,
        unsigned short* __restrict__ H, unsigned short* __restrict__ L) {
    int i = blockIdx.x * 256 + threadIdx.x;         // 8-element group
    float4 a0 = *(reinterpret_cast<const float4*>(A) + (size_t)i * 2);
    float4 a1 = *(reinterpret_cast<const float4*>(A) + (size_t)i * 2 + 1);
    float f[8] = {a0.x, a0.y, a0.z, a0.w, a1.x, a1.y, a1.z, a1.w};
    unsigned short h[8], l[8];
    #pragma unroll
    for (int j = 0; j < 8; ++j) bf16split(f[j], h[j], l[j]);
    uint4 hv, lv;
    hv.x = (unsigned)h[0] | ((unsigned)h[1] << 16); hv.y = (unsigned)h[2] | ((unsigned)h[3] << 16);
    hv.z = (unsigned)h[4] | ((unsigned)h[5] << 16); hv.w = (unsigned)h[6] | ((unsigned)h[7] << 16);
    lv.x = (unsigned)l[0] | ((unsigned)l[1] << 16); lv.y = (unsigned)l[2] | ((unsigned)l[3] << 16);
    lv.z = (unsigned)l[4] | ((unsigned)l[5] << 16); lv.w = (unsigned)l[6] | ((unsigned)l[7] << 16);
    reinterpret_cast<uint4*>(H)[i] = hv;
    reinterpret_cast<uint4*>(L)[i] = lv;
}

// B-side converter with transpose: fp32 W[K][N] -> bf16 planes [N][K].
__global__ __launch_bounds__(256) void cvt_split_T_kernel(const float* __restrict__ W,
        unsigned short* __restrict__ H, unsigned short* __restrict__ L, int K, int N) {
    __shared__ float tile[64][65];
    const int n0 = blockIdx.x * 64, k0 = blockIdx.y * 64;
    const int t = threadIdx.x;
    {
        int r = t >> 2, c4 = (t & 3) * 16;
        #pragma unroll
        for (int u = 0; u < 4; ++u) {
            float4 w = *reinterpret_cast<const float4*>(&W[(size_t)(k0 + r) * N + n0 + c4 + u * 4]);
            tile[r][c4 + u * 4 + 0] = w.x; tile[r][c4 + u * 4 + 1] = w.y;
            tile[r][c4 + u * 4 + 2] = w.z; tile[r][c4 + u * 4 + 3] = w.w;
        }
    }
    __syncthreads();
    {
        int n = t >> 2, kc = (t & 3) * 16;
        unsigned short h[16], l[16];
        #pragma unroll
        for (int j = 0; j < 16; ++j) bf16split(tile[kc + j][n], h[j], l[j]);
        uint4 hv0, hv1, lv0, lv1;
        hv0.x = (unsigned)h[0] | ((unsigned)h[1] << 16);  hv0.y = (unsigned)h[2] | ((unsigned)h[3] << 16);
        hv0.z = (unsigned)h[4] | ((unsigned)h[5] << 16);  hv0.w = (unsigned)h[6] | ((unsigned)h[7] << 16);
        hv1.x = (unsigned)h[8] | ((unsigned)h[9] << 16);  hv1.y = (unsigned)h[10] | ((unsigned)h[11] << 16);
        hv1.z = (unsigned)h[12] | ((unsigned)h[13] << 16); hv1.w = (unsigned)h[14] | ((unsigned)h[15] << 16);
        lv0.x = (unsigned)l[0] | ((unsigned)l[1] << 16);  lv0.y = (unsigned)l[2] | ((unsigned)l[3] << 16);
        lv0.z = (unsigned)l[4] | ((unsigned)l[5] << 16);  lv0.w = (unsigned)l[6] | ((unsigned)l[7] << 16);
        lv1.x = (unsigned)l[8] | ((unsigned)l[9] << 16);  lv1.y = (unsigned)l[10] | ((unsigned)l[11] << 16);
        lv1.z = (unsigned)l[12] | ((unsigned)l[13] << 16); lv1.w = (unsigned)l[14] | ((unsigned)l[15] << 16);
        size_t o = (size_t)(n0 + n) * K + k0 + kc;
        reinterpret_cast<uint4*>(&H[o])[0] = hv0; reinterpret_cast<uint4*>(&H[o])[1] = hv1;
        reinterpret_cast<uint4*>(&L[o])[0] = lv0; reinterpret_cast<uint4*>(&L[o])[1] = lv1;
    }
}

// ---- V converter (transposed): Vtmp [bh][t][64] fp32 -> bf16 planes [bh][d][T] ----
__global__ __launch_bounds__(256) void cvt_kv_vt_kernel(const float* __restrict__ Vtmp,
        unsigned short* __restrict__ Vh, unsigned short* __restrict__ Vl) {
    __shared__ float tile[64][65];
    const int s0 = blockIdx.x * 64;
    const int bh = blockIdx.y;
    const int tid = threadIdx.x;
    {
        int r = tid >> 2, c0 = (tid & 3) * 16;
        const float* src = Vtmp + ((size_t)bh * T + s0 + r) * 64 + c0;
        #pragma unroll
        for (int u = 0; u < 4; ++u) {
            float4 w = *reinterpret_cast<const float4*>(src + u * 4);
            tile[r][c0 + u * 4 + 0] = w.x; tile[r][c0 + u * 4 + 1] = w.y;
            tile[r][c0 + u * 4 + 2] = w.z; tile[r][c0 + u * 4 + 3] = w.w;
        }
    }
    __syncthreads();
    {
        int d = tid >> 2, cs = (tid & 3) * 16;
        unsigned short hh[16], ll[16];
        #pragma unroll
        for (int j = 0; j < 16; ++j) bf16split(tile[cs + j][d], hh[j], ll[j]);
        uint4 hv0, hv1, lv0, lv1;
        hv0.x = (unsigned)hh[0] | ((unsigned)hh[1] << 16);  hv0.y = (unsigned)hh[2] | ((unsigned)hh[3] << 16);
        hv0.z = (unsigned)hh[4] | ((unsigned)hh[5] << 16);  hv0.w = (unsigned)hh[6] | ((unsigned)hh[7] << 16);
        hv1.x = (unsigned)hh[8] | ((unsigned)hh[9] << 16);  hv1.y = (unsigned)hh[10] | ((unsigned)hh[11] << 16);
        hv1.z = (unsigned)hh[12] | ((unsigned)hh[13] << 16); hv1.w = (unsigned)hh[14] | ((unsigned)hh[15] << 16);
        lv0.x = (unsigned)ll[0] | ((unsigned)ll[1] << 16);  lv0.y = (unsigned)ll[2] | ((unsigned)ll[3] << 16);
        lv0.z = (unsigned)ll[4] | ((unsigned)ll[5] << 16);  lv0.w = (unsigned)ll[6] | ((unsigned)ll[7] << 16);
        lv1.x = (unsigned)ll[8] | ((unsigned)ll[9] << 16);  lv1.y = (unsigned)ll[10] | ((unsigned)ll[11] << 16);
        lv1.z = (unsigned)ll[12] | ((unsigned)ll[13] << 16); lv1.w = (unsigned)ll[14] | ((unsigned)ll[15] << 16);
        size_t o = ((size_t)bh * 64 + d) * T + s0 + cs;
        reinterpret_cast<uint4*>(&Vh[o])[0] = hv0; reinterpret_cast<uint4*>(&Vh[o])[1] = hv1;
        reinterpret_cast<uint4*>(&Vl[o])[0] = lv0; reinterpret_cast<uint4*>(&Vl[o])[1] = lv1;
    }
}

// ---------------- split-bf16 MFMA GEMM (generic): C = A*B + bias ----------------
#define LDST 40
__global__ __launch_bounds__(256) void gemm_mfma_kernel(
        const unsigned short* __restrict__ Ah, const unsigned short* __restrict__ Al,
        const unsigned short* __restrict__ Bh, const unsigned short* __restrict__ Bl,
        const float* __restrict__ bias, float* __restrict__ Cm,
        int M, int N, int K) {
    __shared__ unsigned short lA[2][128 * LDST];
    __shared__ unsigned short lB[2][128 * LDST];
    const int tid = threadIdx.x;
    const int bm = blockIdx.y * 128, bn = blockIdx.x * 128;
    const int lane = tid & 63, wid = tid >> 6;
    const int wr = wid >> 1, wc = wid & 1;
    f32x4 acc[4][4];
    #pragma unroll
    for (int i = 0; i < 4; ++i)
        #pragma unroll
        for (int j = 0; j < 4; ++j) acc[i][j] = (f32x4){0.f, 0.f, 0.f, 0.f};
    const int srow = tid >> 2, sk8 = (tid & 3) * 8;
    const int arb = wr * 64 + (lane & 15);
    const int brb = wc * 64 + (lane & 15);
    const int koff = (lane >> 4) * 8;
    for (int k0 = 0; k0 < K; k0 += 32) {
        __syncthreads();
        #pragma unroll
        for (int c = 0; c < 2; ++c) {
            int row = srow + 64 * c;
            uint4 va = *reinterpret_cast<const uint4*>(&Ah[(size_t)(bm + row) * K + k0 + sk8]);
            uint4 vb = *reinterpret_cast<const uint4*>(&Al[(size_t)(bm + row) * K + k0 + sk8]);
            uint4 vc = *reinterpret_cast<const uint4*>(&Bh[(size_t)(bn + row) * K + k0 + sk8]);
            uint4 vd = *reinterpret_cast<const uint4*>(&Bl[(size_t)(bn + row) * K + k0 + sk8]);
            *reinterpret_cast<uint4*>(&lA[0][row * LDST + sk8]) = va;
            *reinterpret_cast<uint4*>(&lA[1][row * LDST + sk8]) = vb;
            *reinterpret_cast<uint4*>(&lB[0][row * LDST + sk8]) = vc;
            *reinterpret_cast<uint4*>(&lB[1][row * LDST + sk8]) = vd;
        }
        __syncthreads();
        bf16x8 fa[2][4], fb[2][4];
        #pragma unroll
        for (int fi = 0; fi < 4; ++fi) {
            fa[0][fi] = *reinterpret_cast<const bf16x8*>(&lA[0][(arb + fi * 16) * LDST + koff]);
            fa[1][fi] = *reinterpret_cast<const bf16x8*>(&lA[1][(arb + fi * 16) * LDST + koff]);
            fb[0][fi] = *reinterpret_cast<const bf16x8*>(&lB[0][(brb + fi * 16) * LDST + koff]);
            fb[1][fi] = *reinterpret_cast<const bf16x8*>(&lB[1][(brb + fi * 16) * LDST + koff]);
        }
        #pragma unroll
        for (int fi = 0; fi < 4; ++fi)
            #pragma unroll
            for (int fj = 0; fj < 4; ++fj) {
                acc[fi][fj] = __builtin_amdgcn_mfma_f32_16x16x32_bf16(fa[0][fi], fb[0][fj], acc[fi][fj], 0, 0, 0);
                acc[fi][fj] = __builtin_amdgcn_mfma_f32_16x16x32_bf16(fa[0][fi], fb[1][fj], acc[fi][fj], 0, 0, 0);
                acc[fi][fj] = __builtin_amdgcn_mfma_f32_16x16x32_bf16(fa[1][fi], fb[0][fj], acc[fi][fj], 0, 0, 0);
            }
    }
    #pragma unroll
    for (int fj = 0; fj < 4; ++fj) {
        int col = bn + wc * 64 + fj * 16 + (lane & 15);
        float bv = bias[col];
        #pragma unroll
        for (int fi = 0; fi < 4; ++fi) {
            int row0 = bm + wr * 64 + fi * 16 + (lane >> 4) * 4;
            #pragma unroll
            for (int p = 0; p < 4; ++p)
                Cm[(size_t)(row0 + p) * N + col] = acc[fi][fj][p] + bv;
        }
    }
}

// ---------------- gemm1 specialized: qkv = x@W_attn + b, writing planes directly ----
// Q cols [0,768) -> Qh/Ql planes [bh][t][64]; K cols [768,1536) -> Kh/Kl;
// V cols [1536,2304) -> Vtmp fp32 [bh][t][64]. Skips the fp32 qkv round-trip.
__global__ __launch_bounds__(256) void gemm_qkv_mfma_kernel(
        const unsigned short* __restrict__ Ah, const unsigned short* __restrict__ Al,
        const unsigned short* __restrict__ Bh, const unsigned short* __restrict__ Bl,
        const float* __restrict__ bias,
        unsigned short* __restrict__ Qh, unsigned short* __restrict__ Ql,
        unsigned short* __restrict__ Kh, unsigned short* __restrict__ Kl,
        float* __restrict__ Vtmp) {
    const int N = C3, K = CE;
    __shared__ unsigned short lA[2][128 * LDST];
    __shared__ unsigned short lB[2][128 * LDST];
    const int tid = threadIdx.x;
    const int bm = blockIdx.y * 128, bn = blockIdx.x * 128;
    const int lane = tid & 63, wid = tid >> 6;
    const int wr = wid >> 1, wc = wid & 1;
    f32x4 acc[4][4];
    #pragma unroll
    for (int i = 0; i < 4; ++i)
        #pragma unroll
        for (int j = 0; j < 4; ++j) acc[i][j] = (f32x4){0.f, 0.f, 0.f, 0.f};
    const int srow = tid >> 2, sk8 = (tid & 3) * 8;
    const int arb = wr * 64 + (lane & 15);
    const int brb = wc * 64 + (lane & 15);
    const int koff = (lane >> 4) * 8;
    for (int k0 = 0; k0 < K; k0 += 32) {
        __syncthreads();
        #pragma unroll
        for (int c = 0; c < 2; ++c) {
            int row = srow + 64 * c;
            uint4 va = *reinterpret_cast<const uint4*>(&Ah[(size_t)(bm + row) * K + k0 + sk8]);
            uint4 vb = *reinterpret_cast<const uint4*>(&Al[(size_t)(bm + row) * K + k0 + sk8]);
            uint4 vc = *reinterpret_cast<const uint4*>(&Bh[(size_t)(bn + row) * K + k0 + sk8]);
            uint4 vd = *reinterpret_cast<const uint4*>(&Bl[(size_t)(bn + row) * K + k0 + sk8]);
            *reinterpret_cast<uint4*>(&lA[0][row * LDST + sk8]) = va;
            *reinterpret_cast<uint4*>(&lA[1][row * LDST + sk8]) = vb;
            *reinterpret_cast<uint4*>(&lB[0][row * LDST + sk8]) = vc;
            *reinterpret_cast<uint4*>(&lB[1][row * LDST + sk8]) = vd;
        }
        __syncthreads();
        bf16x8 fa[2][4], fb[2][4];
        #pragma unroll
        for (int fi = 0; fi < 4; ++fi) {
            fa[0][fi] = *reinterpret_cast<const bf16x8*>(&lA[0][(arb + fi * 16) * LDST + koff]);
            fa[1][fi] = *reinterpret_cast<const bf16x8*>(&lA[1][(arb + fi * 16) * LDST + koff]);
            fb[0][fi] = *reinterpret_cast<const bf16x8*>(&lB[0][(brb + fi * 16) * LDST + koff]);
            fb[1][fi] = *reinterpret_cast<const bf16x8*>(&lB[1][(brb + fi * 16) * LDST + koff]);
        }
        #pragma unroll
        for (int fi = 0; fi < 4; ++fi)
            #pragma unroll
            for (int fj = 0; fj < 4; ++fj) {
                acc[fi][fj] = __builtin_amdgcn_mfma_f32_16x16x32_bf16(fa[0][fi], fb[0][fj], acc[fi][fj], 0, 0, 0);
                acc[fi][fj] = __builtin_amdgcn_mfma_f32_16x16x32_bf16(fa[0][fi], fb[1][fj], acc[fi][fj], 0, 0, 0);
                acc[fi][fj] = __builtin_amdgcn_mfma_f32_16x16x32_bf16(fa[1][fi], fb[0][fj], acc[fi][fj], 0, 0, 0);
            }
    }
    // epilogue: wave's 64 cols = one head of one region (wave-uniform branch)
    const int colbase = bn + wc * 64;
    const int region = colbase / 768;           // 0=Q, 1=K, 2=V
    const int h = (colbase % 768) >> 6;
    #pragma unroll
    for (int fj = 0; fj < 4; ++fj) {
        int col = colbase + fj * 16 + (lane & 15);
        float bv = bias[col];
        int d = fj * 16 + (lane & 15);
        #pragma unroll
        for (int fi = 0; fi < 4; ++fi) {
            int row0 = bm + wr * 64 + fi * 16 + (lane >> 4) * 4;
            #pragma unroll
            for (int p = 0; p < 4; ++p) {
                int tg = row0 + p;
                int bb = tg >> 11, t = tg & (T - 1);
                size_t o = ((size_t)(bb * NH + h) * T + t) * 64 + d;
                float val = acc[fi][fj][p] + bv;
                if (region == 0) {
                    unsigned short hh, ll; bf16split(val, hh, ll);
                    Qh[o] = hh; Ql[o] = ll;
                } else if (region == 1) {
                    unsigned short hh, ll; bf16split(val, hh, ll);
                    Kh[o] = hh; Kl[o] = ll;
                } else {
                    Vtmp[o] = val;
                }
            }
        }
    }
}

// ---------------- fp32 GEMM fallback (small ws) ----------------
__global__ __launch_bounds__(256) void gemm_bias_kernel(
        const float* __restrict__ A, const float* __restrict__ B,
        const float* __restrict__ bias, float* __restrict__ Cm,
        int M, int N, int K) {
    __shared__ float As[16][64];
    __shared__ float Bs[16][68];
    const int tid = threadIdx.x;
    const int ty = tid >> 4, tx = tid & 15;
    const int bm = blockIdx.y * 64, bn = blockIdx.x * 64;
    float acc[4][4] = {};
    for (int k0 = 0; k0 < K; k0 += 16) {
        {
            int r = tid >> 2;
            int kk = (tid & 3) * 4;
            float4 a = *reinterpret_cast<const float4*>(&A[(size_t)(bm + r) * K + k0 + kk]);
            As[kk + 0][r] = a.x; As[kk + 1][r] = a.y; As[kk + 2][r] = a.z; As[kk + 3][r] = a.w;
        }
        {
            int kk = tid >> 4;
            int c = (tid & 15) * 4;
            *reinterpret_cast<float4*>(&Bs[kk][c]) =
                *reinterpret_cast<const float4*>(&B[(size_t)(k0 + kk) * N + bn + c]);
        }
        __syncthreads();
        #pragma unroll
        for (int kk = 0; kk < 16; ++kk) {
            float4 a4 = *reinterpret_cast<const float4*>(&As[kk][ty * 4]);
            float4 b4 = *reinterpret_cast<const float4*>(&Bs[kk][tx * 4]);
            float av[4] = {a4.x, a4.y, a4.z, a4.w};
            float bv[4] = {b4.x, b4.y, b4.z, b4.w};
            #pragma unroll
            for (int i = 0; i < 4; ++i)
                #pragma unroll
                for (int j = 0; j < 4; ++j)
                    acc[i][j] = fmaf(av[i], bv[j], acc[i][j]);
        }
        __syncthreads();
    }
    #pragma unroll
    for (int i = 0; i < 4; ++i) {
        int row = bm + ty * 4 + i;
        #pragma unroll
        for (int j = 0; j < 4; ++j) {
            int col = bn + tx * 4 + j;
            Cm[(size_t)row * N + col] = acc[i][j] + bias[col];
        }
    }
}

#define FST 72   // LDS row stride (bf16), 144 B = 16B-aligned rows

// ---------------- s0 via MFMA + fused column sums: S, Psum ----------------
__global__ __launch_bounds__(256) void s0_mfma_kernel(
        const unsigned short* __restrict__ Qh, const unsigned short* __restrict__ Ql,
        const unsigned short* __restrict__ Kh, const unsigned short* __restrict__ Kl,
        float* __restrict__ S, float* __restrict__ Psum) {
    const int kb = blockIdx.x * 64, qb = blockIdx.y * 64, b = blockIdx.z;
    const int tid = threadIdx.x;
    float* Sb = S + (size_t)b * T * T;
    if (kb > qb) {  // entire tile masked -> zero S tile + zero Psum entries
        const int ty = tid >> 4, tx = tid & 15;
        #pragma unroll
        for (int i = 0; i < 4; ++i) {
            float4 z = {0.f, 0.f, 0.f, 0.f};
            *reinterpret_cast<float4*>(&Sb[(size_t)(qb + ty * 4 + i) * T + kb + tx * 4]) = z;
        }
        if (tid < 64) Psum[((size_t)(b * 32 + (qb >> 6)) * T) + kb + tid] = 0.f;
        return;
    }
    const int lane = tid & 63, w = tid >> 6;
    const int fr = lane & 15, fg = lane >> 4;
    __shared__ unsigned short Ks[2][64 * FST];
    __shared__ float csum[4][64];
    const int hb0 = b * NH;   // head 0
    {
        const int sr = tid >> 2, sc0 = (tid & 3) * 16;
        const unsigned short* kh = Kh + ((size_t)hb0 * T + kb + sr) * 64 + sc0;
        const unsigned short* kl = Kl + ((size_t)hb0 * T + kb + sr) * 64 + sc0;
        uint4 a0 = reinterpret_cast<const uint4*>(kh)[0];
        uint4 a1 = reinterpret_cast<const uint4*>(kh)[1];
        uint4 b0 = reinterpret_cast<const uint4*>(kl)[0];
        uint4 b1 = reinterpret_cast<const uint4*>(kl)[1];
        *reinterpret_cast<uint4*>(&Ks[0][sr * FST + sc0 + 0]) = a0;
        *reinterpret_cast<uint4*>(&Ks[0][sr * FST + sc0 + 8]) = a1;
        *reinterpret_cast<uint4*>(&Ks[1][sr * FST + sc0 + 0]) = b0;
        *reinterpret_cast<uint4*>(&Ks[1][sr * FST + sc0 + 8]) = b1;
    }
    bf16x8 qh[2], ql[2];
    #pragma unroll
    for (int ks = 0; ks < 2; ++ks) {
        size_t qo = ((size_t)hb0 * T + qb + w * 16 + fr) * 64 + ks * 32 + fg * 8;
        qh[ks] = *reinterpret_cast<const bf16x8*>(&Qh[qo]);
        ql[ks] = *reinterpret_cast<const bf16x8*>(&Ql[qo]);
    }
    __syncthreads();
    f32x4 qk[4];
    #pragma unroll
    for (int fj = 0; fj < 4; ++fj) qk[fj] = (f32x4){0.f, 0.f, 0.f, 0.f};
    #pragma unroll
    for (int ks = 0; ks < 2; ++ks) {
        bf16x8 kbh[4], kbl[4];
        #pragma unroll
        for (int fj = 0; fj < 4; ++fj) {
            kbh[fj] = *reinterpret_cast<const bf16x8*>(&Ks[0][(fj * 16 + fr) * FST + ks * 32 + fg * 8]);
            kbl[fj] = *reinterpret_cast<const bf16x8*>(&Ks[1][(fj * 16 + fr) * FST + ks * 32 + fg * 8]);
        }
        #pragma unroll
        for (int fj = 0; fj < 4; ++fj) {
            qk[fj] = __builtin_amdgcn_mfma_f32_16x16x32_bf16(qh[ks], kbh[fj], qk[fj], 0, 0, 0);
            qk[fj] = __builtin_amdgcn_mfma_f32_16x16x32_bf16(qh[ks], kbl[fj], qk[fj], 0, 0, 0);
            qk[fj] = __builtin_amdgcn_mfma_f32_16x16x32_bf16(ql[ks], kbh[fj], qk[fj], 0, 0, 0);
        }
    }
    float colsum[4] = {0.f, 0.f, 0.f, 0.f};
    #pragma unroll
    for (int p = 0; p < 4; ++p) {
        int t = qb + w * 16 + fg * 4 + p;
        #pragma unroll
        for (int fj = 0; fj < 4; ++fj) {
            int s = kb + fj * 16 + fr;
            float v = qk[fj][p] * 0.125f;
            float o = (s >= 1 && s < t) ? fmaxf(v, 0.0f) : 0.0f;
            Sb[(size_t)t * T + s] = o;
            colsum[fj] += o;
        }
    }
    // fused colsum: reduce over fg (xor16, xor32) then across waves via LDS
    #pragma unroll
    for (int fj = 0; fj < 4; ++fj) {
        colsum[fj] += __shfl_xor(colsum[fj], 16);
        colsum[fj] += __shfl_xor(colsum[fj], 32);
    }
    if (lane < 16) {
        #pragma unroll
        for (int fj = 0; fj < 4; ++fj) csum[w][fj * 16 + lane] = colsum[fj];
    }
    __syncthreads();
    if (tid < 64) {
        float v = csum[0][tid] + csum[1][tid] + csum[2][tid] + csum[3][tid];
        Psum[((size_t)(b * 32 + (qb >> 6)) * T) + kb + tid] = v;
    }
}

// ---------------- fp32 s0 fallback ----------------
__global__ __launch_bounds__(256) void s0_kernel(const float* __restrict__ qkv,
                                                 float* __restrict__ S) {
    const int kb = blockIdx.x * 64, qb = blockIdx.y * 64, b = blockIdx.z;
    const int tid = threadIdx.x, ty = tid >> 4, tx = tid & 15;
    float* Sb = S + (size_t)b * T * T;
    if (kb > qb) {
        #pragma unroll
        for (int i = 0; i < 4; ++i) {
            int row = qb + ty * 4 + i;
            float4 z = {0.f, 0.f, 0.f, 0.f};
            *reinterpret_cast<float4*>(&Sb[(size_t)row * T + kb + tx * 4]) = z;
        }
        return;
    }
    __shared__ float Qt[64][68];
    __shared__ float Kt[64][68];
    {
        int r = tid >> 2;
        int c0 = (tid & 3) * 16;
        const float* qrow = qkv + (size_t)(b * T + qb + r) * C3 + 0;
        const float* krow = qkv + (size_t)(b * T + kb + r) * C3 + 768;
        #pragma unroll
        for (int u = 0; u < 4; ++u) {
            float4 q4 = *reinterpret_cast<const float4*>(&qrow[c0 + u * 4]);
            float4 k4 = *reinterpret_cast<const float4*>(&krow[c0 + u * 4]);
            int d = c0 + u * 4;
            Qt[d + 0][r] = q4.x; Qt[d + 1][r] = q4.y; Qt[d + 2][r] = q4.z; Qt[d + 3][r] = q4.w;
            Kt[d + 0][r] = k4.x; Kt[d + 1][r] = k4.y; Kt[d + 2][r] = k4.z; Kt[d + 3][r] = k4.w;
        }
    }
    __syncthreads();
    float acc[4][4] = {};
    #pragma unroll
    for (int d = 0; d < 64; ++d) {
        float4 qv = *reinterpret_cast<const float4*>(&Qt[d][ty * 4]);
        float4 kv = *reinterpret_cast<const float4*>(&Kt[d][tx * 4]);
        float qa[4] = {qv.x, qv.y, qv.z, qv.w};
        float ka[4] = {kv.x, kv.y, kv.z, kv.w};
        #pragma unroll
        for (int i = 0; i < 4; ++i)
            #pragma unroll
            for (int j = 0; j < 4; ++j)
                acc[i][j] = fmaf(qa[i], ka[j], acc[i][j]);
    }
    #pragma unroll
    for (int i = 0; i < 4; ++i) {
        int t = qb + ty * 4 + i;
        float o[4];
        #pragma unroll
        for (int j = 0; j < 4; ++j) {
            int s = kb + tx * 4 + j;
            float v = acc[i][j] * 0.125f;
            o[j] = (s >= 1 && s < t) ? fmaxf(v, 0.0f) : 0.0f;
        }
        float4 o4 = {o[0], o[1], o[2], o[3]};
        *reinterpret_cast<float4*>(&Sb[(size_t)t * T + kb + tx * 4]) = o4;
    }
}

// ---------------- segmented scan: FF = cumsum_t(S) ----------------
__global__ __launch_bounds__(256) void colsum_kernel(const float* __restrict__ S,
                                                     float* __restrict__ Psum) {
    int s = blockIdx.x * 256 + threadIdx.x;
    int j = blockIdx.y, b = blockIdx.z;
    const float* Sb = S + (size_t)b * T * T;
    float sum = 0.f;
    for (int r = 0; r < 64; ++r) sum += Sb[(size_t)(j * 64 + r) * T + s];
    Psum[((size_t)b * 32 + j) * T + s] = sum;
}

// prefetch all 32 loads (independent), then scan in registers: 32x latency -> 1x
__global__ __launch_bounds__(256) void scanseg_kernel(float* __restrict__ Psum) {
    int s = blockIdx.x * 256 + threadIdx.x;
    int b = blockIdx.y;
    float v[32];
    #pragma unroll
    for (int j = 0; j < 32; ++j)
        v[j] = Psum[((size_t)(b * 32 + j)) * T + s];
    float run = 0.f;
    #pragma unroll
    for (int j = 0; j < 32; ++j) {
        Psum[((size_t)(b * 32 + j)) * T + s] = run;
        run += v[j];
    }
}

__global__ __launch_bounds__(256) void ffscan_kernel(float* __restrict__ S,
                                                     const float* __restrict__ Psum) {
    int s = blockIdx.x * 256 + threadIdx.x;
    int j = blockIdx.y, b = blockIdx.z;
    float run = Psum[((size_t)b * 32 + j) * T + s];
    float* Sb = S + (size_t)b * T * T;
    for (int r = 0; r < 64; ++r) {
        size_t idx = (size_t)(j * 64 + r) * T + s;
        run += Sb[idx];
        Sb[idx] = run;
    }
}

// ---------------- task table: 40 tasks/(b,h), size-descending ----------------
__device__ const int FTQ[40] = {15,15,15,15,14,14,14,13,13,13,12,12,12,11,11,11,10,10,9,9,8,8,7,7,6,5,4,3,14,10,6,2,13,9,5,1,12,8,4,0};
__device__ const int FK0[40] = {0,8,16,24,0,8,16,0,8,16,0,8,16,0,8,16,0,8,0,8,0,8,0,8,0,0,0,0,24,16,8,0,24,16,8,0,24,16,8,0};
__device__ const int FK1[40] = {8,16,24,32,8,16,24,8,16,24,8,16,24,8,16,24,8,16,8,16,8,16,8,16,8,8,8,8,30,22,14,6,28,20,12,4,26,18,10,2};
__device__ const int FCB[12] = {0,2,4,6,8,11,14,17,20,24,28,32};   // chunk base per Q-4

// ---------------- 32x32 swapped-operand MFMA flash attention ----------------
// Direct rows + merged rows both emit Y as bf16 hi/lo planes (gemm2 input).
__global__ __launch_bounds__(256) void flash_mfma_kernel(
        const unsigned short* __restrict__ Qh, const unsigned short* __restrict__ Ql,
        const unsigned short* __restrict__ Kh, const unsigned short* __restrict__ Kl,
        const unsigned short* __restrict__ Vth, const unsigned short* __restrict__ Vtl,
        const float* __restrict__ FF,
        unsigned short* __restrict__ Yh, unsigned short* __restrict__ Yl,
        float* __restrict__ PART) {
    const int hb = blockIdx.x;
    const int h = hb % NH, b = hb / NH;
    const int u = blockIdx.y;
    const int tq = FTQ[u], kt0 = FK0[u], kt1 = FK1[u];
    const int qb = tq * 128;
    const int tid = threadIdx.x;
    const int lane = tid & 63, w = tid >> 6;
    const int q31 = lane & 31, hi = lane >> 5;
    const int trow = qb + w * 32 + q31;      // this lane's q-row (absolute t)
    __shared__ unsigned short KS[2][64 * FST];   // K [s][d] hi/lo
    __shared__ unsigned short VS[2][64 * FST];   // V^T [d][s] hi/lo

    bf16x8 qfh[4], qfl[4];
    #pragma unroll
    for (int dblk = 0; dblk < 4; ++dblk) {
        size_t qo = ((size_t)hb * T + trow) * 64 + dblk * 16 + hi * 8;
        qfh[dblk] = *reinterpret_cast<const bf16x8*>(&Qh[qo]);
        qfl[dblk] = *reinterpret_cast<const bf16x8*>(&Ql[qo]);
    }

    f32x16 oacc0 = (f32x16)(0.f), oacc1 = (f32x16)(0.f);
    float m = -1e30f, l = 0.f;
    const float* FFb = FF + (size_t)b * T * T;
    const int sr = tid >> 2, sc0 = (tid & 3) * 16;

    for (int kt = kt0; kt < kt1; ++kt) {
        const int kb = kt * 64;
        __syncthreads();
        {
            const unsigned short* ksrc = Kh + ((size_t)hb * T + kb + sr) * 64 + sc0;
            const unsigned short* ksrl = Kl + ((size_t)hb * T + kb + sr) * 64 + sc0;
            const unsigned short* vsrc = Vth + ((size_t)hb * 64 + sr) * T + kb + sc0;
            const unsigned short* vsrl = Vtl + ((size_t)hb * 64 + sr) * T + kb + sc0;
            uint4 k0v = reinterpret_cast<const uint4*>(ksrc)[0];
            uint4 k1v = reinterpret_cast<const uint4*>(ksrc)[1];
            uint4 k2v = reinterpret_cast<const uint4*>(ksrl)[0];
            uint4 k3v = reinterpret_cast<const uint4*>(ksrl)[1];
            uint4 v0v = reinterpret_cast<const uint4*>(vsrc)[0];
            uint4 v1v = reinterpret_cast<const uint4*>(vsrc)[1];
            uint4 v2v = reinterpret_cast<const uint4*>(vsrl)[0];
            uint4 v3v = reinterpret_cast<const uint4*>(vsrl)[1];
            *reinterpret_cast<uint4*>(&KS[0][sr * FST + sc0 + 0]) = k0v;
            *reinterpret_cast<uint4*>(&KS[0][sr * FST + sc0 + 8]) = k1v;
            *reinterpret_cast<uint4*>(&KS[1][sr * FST + sc0 + 0]) = k2v;
            *reinterpret_cast<uint4*>(&KS[1][sr * FST + sc0 + 8]) = k3v;
            *reinterpret_cast<uint4*>(&VS[0][sr * FST + sc0 + 0]) = v0v;
            *reinterpret_cast<uint4*>(&VS[0][sr * FST + sc0 + 8]) = v1v;
            *reinterpret_cast<uint4*>(&VS[1][sr * FST + sc0 + 0]) = v2v;
            *reinterpret_cast<uint4*>(&VS[1][sr * FST + sc0 + 8]) = v3v;
        }
        __syncthreads();
        f32x16 acc[2];
        acc[0] = (f32x16)(0.f); acc[1] = (f32x16)(0.f);
        #pragma unroll
        for (int sb = 0; sb < 2; ++sb) {
            #pragma unroll
            for (int dblk = 0; dblk < 4; ++dblk) {
                bf16x8 kfh = *reinterpret_cast<const bf16x8*>(&KS[0][(sb * 32 + q31) * FST + dblk * 16 + hi * 8]);
                bf16x8 kfl = *reinterpret_cast<const bf16x8*>(&KS[1][(sb * 32 + q31) * FST + dblk * 16 + hi * 8]);
                acc[sb] = __builtin_amdgcn_mfma_f32_32x32x16_bf16(kfh, qfh[dblk], acc[sb], 0, 0, 0);
                acc[sb] = __builtin_amdgcn_mfma_f32_32x32x16_bf16(kfh, qfl[dblk], acc[sb], 0, 0, 0);
                acc[sb] = __builtin_amdgcn_mfma_f32_32x32x16_bf16(kfl, qfh[dblk], acc[sb], 0, 0, 0);
            }
        }
        float pv[2][16];
        #pragma unroll
        for (int sb = 0; sb < 2; ++sb) {
            #pragma unroll
            for (int g = 0; g < 4; ++g) {
                float4 f4 = *reinterpret_cast<const float4*>(
                    &FFb[(size_t)trow * T + kb + sb * 32 + g * 8 + hi * 4]);
                float fv[4] = {f4.x, f4.y, f4.z, f4.w};
                #pragma unroll
                for (int a = 0; a < 4; ++a) {
                    int r = g * 4 + a;
                    int s = kb + sb * 32 + a + g * 8 + hi * 4;
                    float val = acc[sb][r] * 0.125f - fv[a];
                    pv[sb][r] = (s <= trow) ? val : -1e30f;
                }
            }
        }
        float tm = pv[0][0];
        #pragma unroll
        for (int sb = 0; sb < 2; ++sb)
            #pragma unroll
            for (int r = 0; r < 16; ++r) tm = fmaxf(tm, pv[sb][r]);
        tm = fmaxf(tm, __shfl_xor(tm, 32));
        float mn = fmaxf(m, tm);
        float scale = __expf(m - mn);
        float rs = 0.f;
        #pragma unroll
        for (int sb = 0; sb < 2; ++sb)
            #pragma unroll
            for (int r = 0; r < 16; ++r) {
                float pe = __expf(pv[sb][r] - mn);
                pv[sb][r] = pe; rs += pe;
            }
        rs += __shfl_xor(rs, 32);
        l = l * scale + rs;
        m = mn;
        oacc0 *= scale; oacc1 *= scale;
        unsigned wh[2][4][2], wl[2][4][2];
        #pragma unroll
        for (int sb = 0; sb < 2; ++sb)
            #pragma unroll
            for (int bq = 0; bq < 4; ++bq)
                #pragma unroll
                for (int h2 = 0; h2 < 2; ++h2)
                    packP(pv[sb][4 * bq + 2 * h2], pv[sb][4 * bq + 2 * h2 + 1],
                          wh[sb][bq][h2], wl[sb][bq][h2]);
        #pragma unroll
        for (int kk = 0; kk < 4; ++kk) {
            const int sb = kk >> 1;
            const int b0 = 2 * (kk & 1), b1 = b0 + 1;
            unsigned sh_b1_0 = (unsigned)__shfl_xor((int)wh[sb][b1][0], 32);
            unsigned sh_b1_1 = (unsigned)__shfl_xor((int)wh[sb][b1][1], 32);
            unsigned sh_b0_0 = (unsigned)__shfl_xor((int)wh[sb][b0][0], 32);
            unsigned sh_b0_1 = (unsigned)__shfl_xor((int)wh[sb][b0][1], 32);
            unsigned sl_b1_0 = (unsigned)__shfl_xor((int)wl[sb][b1][0], 32);
            unsigned sl_b1_1 = (unsigned)__shfl_xor((int)wl[sb][b1][1], 32);
            unsigned sl_b0_0 = (unsigned)__shfl_xor((int)wl[sb][b0][0], 32);
            unsigned sl_b0_1 = (unsigned)__shfl_xor((int)wl[sb][b0][1], 32);
            u32x4 th, tl;
            th[0] = hi ? sh_b1_0 : wh[sb][b0][0];
            th[1] = hi ? sh_b1_1 : wh[sb][b0][1];
            th[2] = hi ? wh[sb][b1][0] : sh_b0_0;
            th[3] = hi ? wh[sb][b1][1] : sh_b0_1;
            tl[0] = hi ? sl_b1_0 : wl[sb][b0][0];
            tl[1] = hi ? sl_b1_1 : wl[sb][b0][1];
            tl[2] = hi ? wl[sb][b1][0] : sl_b0_0;
            tl[3] = hi ? wl[sb][b1][1] : sl_b0_1;
            bf16x8 pbh = __builtin_bit_cast(bf16x8, th);
            bf16x8 pbl = __builtin_bit_cast(bf16x8, tl);
            {   // db = 0
                bf16x8 vfh = *reinterpret_cast<const bf16x8*>(&VS[0][(q31) * FST + kk * 16 + hi * 8]);
                bf16x8 vfl = *reinterpret_cast<const bf16x8*>(&VS[1][(q31) * FST + kk * 16 + hi * 8]);
                oacc0 = __builtin_amdgcn_mfma_f32_32x32x16_bf16(vfh, pbh, oacc0, 0, 0, 0);
                oacc0 = __builtin_amdgcn_mfma_f32_32x32x16_bf16(vfh, pbl, oacc0, 0, 0, 0);
                oacc0 = __builtin_amdgcn_mfma_f32_32x32x16_bf16(vfl, pbh, oacc0, 0, 0, 0);
            }
            {   // db = 1
                bf16x8 vfh = *reinterpret_cast<const bf16x8*>(&VS[0][(32 + q31) * FST + kk * 16 + hi * 8]);
                bf16x8 vfl = *reinterpret_cast<const bf16x8*>(&VS[1][(32 + q31) * FST + kk * 16 + hi * 8]);
                oacc1 = __builtin_amdgcn_mfma_f32_32x32x16_bf16(vfh, pbh, oacc1, 0, 0, 0);
                oacc1 = __builtin_amdgcn_mfma_f32_32x32x16_bf16(vfh, pbl, oacc1, 0, 0, 0);
                oacc1 = __builtin_amdgcn_mfma_f32_32x32x16_bf16(vfl, pbh, oacc1, 0, 0, 0);
            }
        }
    }
    if (tq < 4) {   // direct: normalized bf16-plane write
        float inv = 1.f / l;
        size_t ybase = ((size_t)(b * T + trow)) * CE + h * 64;
        #pragma unroll
        for (int g = 0; g < 4; ++g) {
            unsigned short h0[4], l0[4], h1[4], l1[4];
            #pragma unroll
            for (int i = 0; i < 4; ++i) {
                bf16split(oacc0[4 * g + i] * inv, h0[i], l0[i]);
                bf16split(oacc1[4 * g + i] * inv, h1[i], l1[i]);
            }
            uint2 ph0 = {(unsigned)h0[0] | ((unsigned)h0[1] << 16), (unsigned)h0[2] | ((unsigned)h0[3] << 16)};
            uint2 pl0 = {(unsigned)l0[0] | ((unsigned)l0[1] << 16), (unsigned)l0[2] | ((unsigned)l0[3] << 16)};
            uint2 ph1 = {(unsigned)h1[0] | ((unsigned)h1[1] << 16), (unsigned)h1[2] | ((unsigned)h1[3] << 16)};
            uint2 pl1 = {(unsigned)l1[0] | ((unsigned)l1[1] << 16), (unsigned)l1[2] | ((unsigned)l1[3] << 16)};
            *reinterpret_cast<uint2*>(&Yh[ybase + g * 8 + hi * 4]) = ph0;
            *reinterpret_cast<uint2*>(&Yl[ybase + g * 8 + hi * 4]) = pl0;
            *reinterpret_cast<uint2*>(&Yh[ybase + 32 + g * 8 + hi * 4]) = ph1;
            *reinterpret_cast<uint2*>(&Yl[ybase + 32 + g * 8 + hi * 4]) = pl1;
        }
    } else {        // partial chunk: unnormalized O + (m,l)
        const int ci = FCB[tq - 4] + (kt0 >> 3);
        float* Ob = PART + (size_t)(hb * 36 + ci) * 8448;
        const int rr = w * 32 + q31;
        #pragma unroll
        for (int g = 0; g < 4; ++g) {
            float4 o0 = {oacc0[4 * g + 0], oacc0[4 * g + 1], oacc0[4 * g + 2], oacc0[4 * g + 3]};
            float4 o1 = {oacc1[4 * g + 0], oacc1[4 * g + 1], oacc1[4 * g + 2], oacc1[4 * g + 3]};
            *reinterpret_cast<float4*>(&Ob[rr * 64 + g * 8 + hi * 4]) = o0;
            *reinterpret_cast<float4*>(&Ob[rr * 64 + 32 + g * 8 + hi * 4]) = o1;
        }
        if (hi == 0) { Ob[8192 + rr] = m; Ob[8192 + 128 + rr] = l; }
    }
}

// ---------------- merge 2..4 chunk partials per 128-row block -> Y planes ----------------
__global__ __launch_bounds__(256) void merge128_kernel(const float* __restrict__ PART,
                                                       unsigned short* __restrict__ Yh,
                                                       unsigned short* __restrict__ Yl) {
    const int hb = blockIdx.x;          // 0..23
    const int tq = 4 + blockIdx.y;      // 4..15
    const int h = hb % NH, b = hb / NH;
    const int nch = (tq >= 12) ? 4 : (tq >= 8) ? 3 : 2;
    const float* base = PART + (size_t)(hb * 36 + FCB[tq - 4]) * 8448;
    const int tid = threadIdx.x;
    const int r = tid >> 1, half = tid & 1;
    float mm[4], la[4];
    float M = -1e30f;
    #pragma unroll
    for (int c = 0; c < 4; ++c) {
        int cc = (c < nch) ? c : 0;
        float mv = base[(size_t)cc * 8448 + 8192 + r];
        float lv = base[(size_t)cc * 8448 + 8192 + 128 + r];
        mm[c] = (c < nch) ? mv : -1e30f;
        la[c] = (c < nch) ? lv : 0.f;
        M = fmaxf(M, mm[c]);
    }
    float a[4], L = 0.f;
    #pragma unroll
    for (int c = 0; c < 4; ++c) {
        a[c] = (c < nch) ? __expf(mm[c] - M) : 0.f;
        L += a[c] * la[c];
    }
    float inv = 1.f / L;
    const int t = tq * 128 + r;
    size_t ybase = ((size_t)(b * T + t)) * CE + h * 64 + half * 32;
    #pragma unroll
    for (int uu = 0; uu < 8; ++uu) {
        float ax = 0.f, ay = 0.f, az = 0.f, aw = 0.f;
        #pragma unroll
        for (int c = 0; c < 4; ++c) {
            int cc = (c < nch) ? c : 0;
            float4 x = *reinterpret_cast<const float4*>(
                &base[(size_t)cc * 8448 + r * 64 + half * 32 + uu * 4]);
            ax += a[c] * x.x; ay += a[c] * x.y; az += a[c] * x.z; aw += a[c] * x.w;
        }
        unsigned short hh[4], ll[4];
        bf16split(ax * inv, hh[0], ll[0]); bf16split(ay * inv, hh[1], ll[1]);
        bf16split(az * inv, hh[2], ll[2]); bf16split(aw * inv, hh[3], ll[3]);
        uint2 ph = {(unsigned)hh[0] | ((unsigned)hh[1] << 16), (unsigned)hh[2] | ((unsigned)hh[3] << 16)};
        uint2 pl = {(unsigned)ll[0] | ((unsigned)ll[1] << 16), (unsigned)ll[2] | ((unsigned)ll[3] << 16)};
        *reinterpret_cast<uint2*>(&Yh[ybase + uu * 4]) = ph;
        *reinterpret_cast<uint2*>(&Yl[ybase + uu * 4]) = pl;
    }
}

// ---------------- fp32 flash fallback (small ws) ----------------
__global__ __launch_bounds__(256) void flash_kernel(const float* __restrict__ qkv,
                                                    const float* __restrict__ FF,
                                                    float* __restrict__ Y,
                                                    float* __restrict__ PO,
                                                    float* __restrict__ PML,
                                                    int split) {
    const int hb = blockIdx.x;
    const int h = hb % NH, b = hb / NH;
    int qt, kt0, kt1, mode;
    if (split) {
        const int u = blockIdx.y;
        if (u < 16)      { qt = 16 + u; kt0 = 0;  kt1 = 16;     mode = 1; }
        else if (u < 32) { qt = 31 - u; kt0 = 0;  kt1 = qt + 1; mode = 0; }
        else             { qt = 63 - u; kt0 = 16; kt1 = qt + 1; mode = 2; }
    } else {
        qt = 31 - blockIdx.y; kt0 = 0; kt1 = qt + 1; mode = 0;
    }
    const int qb = qt * 64;
    const int tid = threadIdx.x, ty = tid >> 4, tx = tid & 15;
    __shared__ float Qt[64][68];
    __shared__ float KtPs[64][68];
    __shared__ float Vs[64][68];
    const int r = tid >> 2, c0 = (tid & 3) * 16;
    {
        const float* qrow = qkv + (size_t)(b * T + qb + r) * C3 + h * 64;
        #pragma unroll
        for (int u = 0; u < 4; ++u) {
            float4 q4 = *reinterpret_cast<const float4*>(&qrow[c0 + u * 4]);
            int d = c0 + u * 4;
            Qt[d + 0][r] = q4.x; Qt[d + 1][r] = q4.y; Qt[d + 2][r] = q4.z; Qt[d + 3][r] = q4.w;
        }
    }
    float m[4], l[4], O[4][4];
    #pragma unroll
    for (int i = 0; i < 4; ++i) {
        m[i] = -1e30f; l[i] = 0.f;
        #pragma unroll
        for (int j = 0; j < 4; ++j) O[i][j] = 0.f;
    }
    const float* FFb = FF + (size_t)b * T * T;
    for (int kt = kt0; kt < kt1; ++kt) {
        const int kb = kt * 64;
        __syncthreads();
        {
            const float* krow = qkv + (size_t)(b * T + kb + r) * C3 + 768 + h * 64;
            const float* vrow = qkv + (size_t)(b * T + kb + r) * C3 + 1536 + h * 64;
            #pragma unroll
            for (int u = 0; u < 4; ++u) {
                float4 k4 = *reinterpret_cast<const float4*>(&krow[c0 + u * 4]);
                int d = c0 + u * 4;
                KtPs[d + 0][r] = k4.x; KtPs[d + 1][r] = k4.y;
                KtPs[d + 2][r] = k4.z; KtPs[d + 3][r] = k4.w;
                *reinterpret_cast<float4*>(&Vs[r][c0 + u * 4]) =
                    *reinterpret_cast<const float4*>(&vrow[c0 + u * 4]);
            }
        }
        __syncthreads();
        float sc[4][4] = {};
        #pragma unroll
        for (int d = 0; d < 64; ++d) {
            float4 qv = *reinterpret_cast<const float4*>(&Qt[d][ty * 4]);
            float4 kv = *reinterpret_cast<const float4*>(&KtPs[d][tx * 4]);
            float qa[4] = {qv.x, qv.y, qv.z, qv.w};
            float ka[4] = {kv.x, kv.y, kv.z, kv.w};
            #pragma unroll
            for (int i = 0; i < 4; ++i)
                #pragma unroll
                for (int j = 0; j < 4; ++j)
                    sc[i][j] = fmaf(qa[i], ka[j], sc[i][j]);
        }
        #pragma unroll
        for (int i = 0; i < 4; ++i) {
            int t = qb + ty * 4 + i;
            float4 f4 = *reinterpret_cast<const float4*>(&FFb[(size_t)t * T + kb + tx * 4]);
            float fv[4] = {f4.x, f4.y, f4.z, f4.w};
            #pragma unroll
            for (int j = 0; j < 4; ++j) {
                int s = kb + tx * 4 + j;
                float v = sc[i][j] * 0.125f - fv[j];
                sc[i][j] = (s <= t) ? v : -1e30f;
            }
        }
        #pragma unroll
        for (int i = 0; i < 4; ++i) {
            float tm = fmaxf(fmaxf(sc[i][0], sc[i][1]), fmaxf(sc[i][2], sc[i][3]));
            tm = fmaxf(tm, __shfl_xor(tm, 1));
            tm = fmaxf(tm, __shfl_xor(tm, 2));
            tm = fmaxf(tm, __shfl_xor(tm, 4));
            tm = fmaxf(tm, __shfl_xor(tm, 8));
            float mn = fmaxf(m[i], tm);
            float scale = __expf(m[i] - mn);
            float rs = 0.f;
            #pragma unroll
            for (int j = 0; j < 4; ++j) {
                float p = __expf(sc[i][j] - mn);
                sc[i][j] = p; rs += p;
            }
            rs += __shfl_xor(rs, 1); rs += __shfl_xor(rs, 2);
            rs += __shfl_xor(rs, 4); rs += __shfl_xor(rs, 8);
            l[i] = l[i] * scale + rs;
            m[i] = mn;
            #pragma unroll
            for (int j = 0; j < 4; ++j) O[i][j] *= scale;
        }
        __syncthreads();
        #pragma unroll
        for (int i = 0; i < 4; ++i) {
            float4 p4 = {sc[i][0], sc[i][1], sc[i][2], sc[i][3]};
            *reinterpret_cast<float4*>(&KtPs[ty * 4 + i][tx * 4]) = p4;
        }
        __syncthreads();
        #pragma unroll
        for (int j4 = 0; j4 < 16; ++j4) {
            float pvv[4][4];
            #pragma unroll
            for (int i = 0; i < 4; ++i) {
                float4 t4 = *reinterpret_cast<const float4*>(&KtPs[ty * 4 + i][j4 * 4]);
                pvv[i][0] = t4.x; pvv[i][1] = t4.y; pvv[i][2] = t4.z; pvv[i][3] = t4.w;
            }
            #pragma unroll
            for (int jj = 0; jj < 4; ++jj) {
                float4 v4 = *reinterpret_cast<const float4*>(&Vs[j4 * 4 + jj][tx * 4]);
                float vv[4] = {v4.x, v4.y, v4.z, v4.w};
                #pragma unroll
                for (int i = 0; i < 4; ++i)
                    #pragma unroll
                    for (int dd = 0; dd < 4; ++dd)
                        O[i][dd] = fmaf(pvv[i][jj], vv[dd], O[i][dd]);
            }
        }
    }
    if (mode == 0) {
        #pragma unroll
        for (int i = 0; i < 4; ++i) {
            int t = qb + ty * 4 + i;
            float inv = 1.f / l[i];
            float4 o4 = {O[i][0] * inv, O[i][1] * inv, O[i][2] * inv, O[i][3] * inv};
            *reinterpret_cast<float4*>(&Y[(size_t)(b * T + t) * CE + h * 64 + tx * 4]) = o4;
        }
    } else {
        const int pidx = (b * NH + h) * 16 + (qt - 16);
        float* Ob  = PO  + (size_t)(mode - 1) * (NB * NH * 16 * 4096) + (size_t)pidx * 4096;
        float* mlb = PML + (size_t)(mode - 1) * (NB * NH * 16 * 128)  + (size_t)pidx * 128;
        #pragma unroll
        for (int i = 0; i < 4; ++i) {
            int rr = ty * 4 + i;
            float4 o4 = {O[i][0], O[i][1], O[i][2], O[i][3]};
            *reinterpret_cast<float4*>(&Ob[rr * 64 + tx * 4]) = o4;
            if (tx == 0) { mlb[rr] = m[i]; mlb[64 + rr] = l[i]; }
        }
    }
}

// ---------------- merge the two split-K partials (fp32 fallback path) ----------------
__global__ __launch_bounds__(256) void merge_kernel(const float* __restrict__ PO,
                                                    const float* __restrict__ PML,
                                                    float* __restrict__ Y) {
    const int p = blockIdx.x;
    const int q16 = p & 15;
    const int hb = p >> 4;
    const int h = hb % NH, b = hb / NH;
    const int qt = 16 + q16;
    const float* O0  = PO  + (size_t)p * 4096;
    const float* O1  = PO  + (size_t)(NB * NH * 16) * 4096 + (size_t)p * 4096;
    const float* ml0 = PML + (size_t)p * 128;
    const float* ml1 = PML + (size_t)(NB * NH * 16) * 128  + (size_t)p * 128;
    const int tid = threadIdx.x;
    const int r = tid >> 2, c0 = (tid & 3) * 16;
    float m0 = ml0[r], l0 = ml0[64 + r];
    float m1 = ml1[r], l1 = ml1[64 + r];
    float M  = fmaxf(m0, m1);
    float a0 = __expf(m0 - M), a1 = __expf(m1 - M);
    float inv = 1.f / (a0 * l0 + a1 * l1);
    const int t = qt * 64 + r;
    float* Yrow = Y + (size_t)(b * T + t) * CE + h * 64;
    #pragma unroll
    for (int u = 0; u < 4; ++u) {
        float4 x0 = *reinterpret_cast<const float4*>(&O0[r * 64 + c0 + u * 4]);
        float4 x1 = *reinterpret_cast<const float4*>(&O1[r * 64 + c0 + u * 4]);
        float4 y;
        y.x = (a0 * x0.x + a1 * x1.x) * inv;
        y.y = (a0 * x0.y + a1 * x1.y) * inv;
        y.z = (a0 * x0.z + a1 * x1.z) * inv;
        y.w = (a0 * x0.w + a1 * x1.w) * inv;
        *reinterpret_cast<float4*>(&Yrow[c0 + u * 4]) = y;
    }
}

extern "C" void kernel_launch(void* const* d_in, const int* in_sizes, int n_in,
                              void* d_out, int out_size, void* d_ws, size_t ws_size,
                              hipStream_t stream) {
    const float* x      = (const float*)d_in[0];
    const float* W_attn = (const float*)d_in[1];
    const float* b_attn = (const float*)d_in[2];
    const float* W_proj = (const float*)d_in[3];
    const float* b_proj = (const float*)d_in[4];
    float* out = (float*)d_out;

    char* ws = (char*)d_ws;
    const size_t QKV_BYTES = (size_t)NB * T * C3 * 4;       // 37,748,736
    const size_t S_BYTES   = (size_t)NB * T * T * 4;        // 33,554,432
    const size_t P_BYTES   = (size_t)NB * 32 * T * 4;       //    524,288
    const size_t Y_BYTES   = (size_t)NB * T * CE * 4;       // 12,582,912
    const size_t PO_BYTES  = (size_t)2 * NB * NH * 16 * 4096 * 4;  // 12,582,912
    const size_t PML_BYTES = (size_t)2 * NB * NH * 16 * 128 * 4;   //    393,216
    const size_t PLANE_X   = (size_t)NB * T * CE * 2;       // 6,291,456
    const size_t PLANE_WA  = (size_t)C3 * CE * 2;           // 3,538,944
    const size_t PLANE_WP  = (size_t)CE * CE * 2;           // 1,179,648
    const size_t PLANE_KV  = (size_t)NB * NH * T * 64 * 2;  // 6,291,456

    const size_t U_OFF  = QKV_BYTES + S_BYTES + P_BYTES + Y_BYTES;
    const size_t U_SIZE = PO_BYTES + PML_BYTES;
    const size_t W_OFF  = U_OFF + U_SIZE;
    const size_t KV_OFF = W_OFF + 2 * PLANE_WA + 2 * PLANE_WP;

    float* qkv  = (float*)ws;                               // fallback paths only
    float* Vtmp = (float*)ws;                               // kv: gemm1 V output (12.6MB)
    float* PART = (float*)ws;                               // kv: flash partials (29.2MB, after Vtmp dead)
    float* S    = (float*)(ws + QKV_BYTES);
    float* Psum = (float*)(ws + QKV_BYTES + S_BYTES);
    float* Yb   = (float*)(ws + QKV_BYTES + S_BYTES + P_BYTES);   // fp32 Y (fallback)
    unsigned short* Qhp = (unsigned short*)(ws + QKV_BYTES + S_BYTES + P_BYTES);  // kv: Q planes in Yb region
    unsigned short* Qlp = (unsigned short*)(ws + QKV_BYTES + S_BYTES + P_BYTES + PLANE_X);
    float* PO   = (float*)(ws + U_OFF);
    float* PML  = (float*)(ws + U_OFF + PO_BYTES);
    unsigned short* Xh  = (unsigned short*)(ws + U_OFF);    // X planes; reused as Y planes after gemm1
    unsigned short* Xl  = (unsigned short*)(ws + U_OFF + PLANE_X);
    unsigned short* Yhp = Xh;
    unsigned short* Ylp = Xl;
    unsigned short* WAh = (unsigned short*)(ws + W_OFF);
    unsigned short* WAl = (unsigned short*)(ws + W_OFF + PLANE_WA);
    unsigned short* WPh = (unsigned short*)(ws + W_OFF + 2 * PLANE_WA);
    unsigned short* WPl = (unsigned short*)(ws + W_OFF + 2 * PLANE_WA + PLANE_WP);
    unsigned short* Khp = (unsigned short*)(ws + KV_OFF);
    unsigned short* Klp = (unsigned short*)(ws + KV_OFF + PLANE_KV);
    unsigned short* VTh = (unsigned short*)(ws + KV_OFF + 2 * PLANE_KV);
    unsigned short* VTl = (unsigned short*)(ws + KV_OFF + 3 * PLANE_KV);

    const size_t NEED_SPLIT = U_OFF + U_SIZE;
    const size_t NEED_MFMA  = KV_OFF;
    const size_t NEED_KV    = KV_OFF + 4 * PLANE_KV;
    const int split = (ws_size >= NEED_SPLIT) ? 1 : 0;
    const int mfma  = (ws_size >= NEED_MFMA) ? 1 : 0;
    const int kv    = (ws_size >= NEED_KV && mfma) ? 1 : 0;

    const int M = NB * T;  // 4096

    if (kv) {
        // weights + x to planes
        cvt_split_T_kernel<<<dim3(C3 / 64, CE / 64), 256, 0, stream>>>(W_attn, WAh, WAl, CE, C3);
        cvt_split_T_kernel<<<dim3(CE / 64, CE / 64), 256, 0, stream>>>(W_proj, WPh, WPl, CE, CE);
        cvt_split_kernel<<<dim3((M * CE / 8) / 256), 256, 0, stream>>>(x, Xh, Xl);
        // gemm1 -> Q/K planes + Vtmp directly (no fp32 qkv)
        gemm_qkv_mfma_kernel<<<dim3(C3 / 128, M / 128), 256, 0, stream>>>(
            Xh, Xl, WAh, WAl, b_attn, Qhp, Qlp, Khp, Klp, Vtmp);
        cvt_kv_vt_kernel<<<dim3(T / 64, NB * NH), 256, 0, stream>>>(Vtmp, VTh, VTl);
        // s0 (+fused colsum -> Psum)
        s0_mfma_kernel<<<dim3(T / 64, T / 64, NB), 256, 0, stream>>>(Qhp, Qlp, Khp, Klp, S, Psum);
        // scan
        scanseg_kernel<<<dim3(T / 256, NB), 256, 0, stream>>>(Psum);
        ffscan_kernel<<<dim3(T / 256, 32, NB), 256, 0, stream>>>(S, Psum);
        // flash -> Y planes (+ PART) ; merge -> Y planes
        flash_mfma_kernel<<<dim3(NB * NH, 40), 256, 0, stream>>>(
            Qhp, Qlp, Khp, Klp, VTh, VTl, S, Yhp, Ylp, PART);
        merge128_kernel<<<dim3(NB * NH, 12), 256, 0, stream>>>(PART, Yhp, Ylp);
        // gemm2 from Y planes
        gemm_mfma_kernel<<<dim3(CE / 128, M / 128), 256, 0, stream>>>(
            Yhp, Ylp, WPh, WPl, b_proj, out, M, CE, CE);
        return;
    }

    // ---------------- fallback paths (small ws) ----------------
    if (mfma) {
        cvt_split_T_kernel<<<dim3(C3 / 64, CE / 64), 256, 0, stream>>>(W_attn, WAh, WAl, CE, C3);
        cvt_split_T_kernel<<<dim3(CE / 64, CE / 64), 256, 0, stream>>>(W_proj, WPh, WPl, CE, CE);
        cvt_split_kernel<<<dim3((M * CE / 8) / 256), 256, 0, stream>>>(x, Xh, Xl);
        gemm_mfma_kernel<<<dim3(C3 / 128, M / 128), 256, 0, stream>>>(Xh, Xl, WAh, WAl, b_attn, qkv, M, C3, CE);
    } else {
        gemm_bias_kernel<<<dim3(C3 / 64, M / 64), 256, 0, stream>>>(x, W_attn, b_attn, qkv, M, C3, CE);
    }
    s0_kernel<<<dim3(T / 64, T / 64, NB), 256, 0, stream>>>(qkv, S);
    colsum_kernel<<<dim3(T / 256, 32, NB), 256, 0, stream>>>(S, Psum);
    scanseg_kernel<<<dim3(T / 256, NB), 256, 0, stream>>>(Psum);
    ffscan_kernel<<<dim3(T / 256, 32, NB), 256, 0, stream>>>(S, Psum);
    if (split) {
        flash_kernel<<<dim3(NB * NH, 48), 256, 0, stream>>>(qkv, S, Yb, PO, PML, 1);
        merge_kernel<<<dim3(NB * NH * 16), 256, 0, stream>>>(PO, PML, Yb);
    } else {
        flash_kernel<<<dim3(NB * NH, 32), 256, 0, stream>>>(qkv, S, Yb, PO, PML, 0);
    }
    if (mfma) {
        cvt_split_kernel<<<dim3((M * CE / 8) / 256), 256, 0, stream>>>(Yb, Xh, Xl);
        gemm_mfma_kernel<<<dim3(CE / 128, M / 128), 256, 0, stream>>>(Xh, Xl, WPh, WPl, b_proj, out, M, CE, CE);
    } else {
        gemm_bias_kernel<<<dim3(CE / 64, M / 64), 256, 0, stream>>>(Yb, W_proj, b_proj, out, M, CE, CE);
    }
}

// Round 8
// 250.450 us; speedup vs baseline: 1.1839x; 1.0044x over previous
//
#include <hip/hip_runtime.h>
#include <math.h>

#define T 2048
#define NH 12
#define HD 64
#define C3 2304   // 3*768
#define CE 768
#define NB 2

typedef __attribute__((ext_vector_type(8))) short bf16x8;
typedef __attribute__((ext_vector_type(4))) float f32x4;
typedef __attribute__((ext_vector_type(16))) float f32x16;
typedef __attribute__((ext_vector_type(4))) unsigned u32x4;

// ---------------- fp32 -> (hi,lo) bf16 split, RNE both halves ----------------
__device__ inline void bf16split(float a, unsigned short& h, unsigned short& l) {
    unsigned int u = __float_as_uint(a);
    unsigned int r = (u + 0x7FFFu + ((u >> 16) & 1u)) >> 16;
    h = (unsigned short)r;
    float hf = __uint_as_float(r << 16);
    float lo = a - hf;                      // exact (Sterbenz)
    unsigned int v = __float_as_uint(lo);
    l = (unsigned short)((v + 0x7FFFu + ((v >> 16) & 1u)) >> 16);
}

__device__ inline void packP(float a, float b, unsigned& wh, unsigned& wl) {
    unsigned short ha, la, hb, lb;
    bf16split(a, ha, la); bf16split(b, hb, lb);
    wh = (unsigned)ha | ((unsigned)hb << 16);
    wl = (unsigned)la | ((unsigned)lb << 16);
}

// A-side converter: fp32 [R][C] -> bf16 planes H,L (same layout). total/8 threads.
__global__ __launch_bounds__(256) void cvt_split_kernel(const float* __restrict__ A,
        unsigned short* __restrict__ H, unsigned short* __restrict__ L) {
    int i = blockIdx.x * 256 + threadIdx.x;         // 8-element group
    float4 a0 = *(reinterpret_cast<const float4*>(A) + (size_t)i * 2);
    float4 a1 = *(reinterpret_cast<const float4*>(A) + (size_t)i * 2 + 1);
    float f[8] = {a0.x, a0.y, a0.z, a0.w, a1.x, a1.y, a1.z, a1.w};
    unsigned short h[8], l[8];
    #pragma unroll
    for (int j = 0; j < 8; ++j) bf16split(f[j], h[j], l[j]);
    uint4 hv, lv;
    hv.x = (unsigned)h[0] | ((unsigned)h[1] << 16); hv.y = (unsigned)h[2] | ((unsigned)h[3] << 16);
    hv.z = (unsigned)h[4] | ((unsigned)h[5] << 16); hv.w = (unsigned)h[6] | ((unsigned)h[7] << 16);
    lv.x = (unsigned)l[0] | ((unsigned)l[1] << 16); lv.y = (unsigned)l[2] | ((unsigned)l[3] << 16);
    lv.z = (unsigned)l[4] | ((unsigned)l[5] << 16); lv.w = (unsigned)l[6] | ((unsigned)l[7] << 16);
    reinterpret_cast<uint4*>(H)[i] = hv;
    reinterpret_cast<uint4*>(L)[i] = lv;
}

// B-side converter with transpose: fp32 W[K][N] -> bf16 planes [N][K].
__global__ __launch_bounds__(256) void cvt_split_T_kernel(const float* __restrict__ W,
        unsigned short* __restrict__ H, unsigned short* __restrict__ L, int K, int N) {
    __shared__ float tile[64][65];
    const int n0 = blockIdx.x * 64, k0 = blockIdx.y * 64;
    const int t = threadIdx.x;
    {
        int r = t >> 2, c4 = (t & 3) * 16;
        #pragma unroll
        for (int u = 0; u < 4; ++u) {
            float4 w = *reinterpret_cast<const float4*>(&W[(size_t)(k0 + r) * N + n0 + c4 + u * 4]);
            tile[r][c4 + u * 4 + 0] = w.x; tile[r][c4 + u * 4 + 1] = w.y;
            tile[r][c4 + u * 4 + 2] = w.z; tile[r][c4 + u * 4 + 3] = w.w;
        }
    }
    __syncthreads();
    {
        int n = t >> 2, kc = (t & 3) * 16;
        unsigned short h[16], l[16];
        #pragma unroll
        for (int j = 0; j < 16; ++j) bf16split(tile[kc + j][n], h[j], l[j]);
        uint4 hv0, hv1, lv0, lv1;
        hv0.x = (unsigned)h[0] | ((unsigned)h[1] << 16);  hv0.y = (unsigned)h[2] | ((unsigned)h[3] << 16);
        hv0.z = (unsigned)h[4] | ((unsigned)h[5] << 16);  hv0.w = (unsigned)h[6] | ((unsigned)h[7] << 16);
        hv1.x = (unsigned)h[8] | ((unsigned)h[9] << 16);  hv1.y = (unsigned)h[10] | ((unsigned)h[11] << 16);
        hv1.z = (unsigned)h[12] | ((unsigned)h[13] << 16); hv1.w = (unsigned)h[14] | ((unsigned)h[15] << 16);
        lv0.x = (unsigned)l[0] | ((unsigned)l[1] << 16);  lv0.y = (unsigned)l[2] | ((unsigned)l[3] << 16);
        lv0.z = (unsigned)l[4] | ((unsigned)l[5] << 16);  lv0.w = (unsigned)l[6] | ((unsigned)l[7] << 16);
        lv1.x = (unsigned)l[8] | ((unsigned)l[9] << 16);  lv1.y = (unsigned)l[10] | ((unsigned)l[11] << 16);
        lv1.z = (unsigned)l[12] | ((unsigned)l[13] << 16); lv1.w = (unsigned)l[14] | ((unsigned)l[15] << 16);
        size_t o = (size_t)(n0 + n) * K + k0 + kc;
        reinterpret_cast<uint4*>(&H[o])[0] = hv0; reinterpret_cast<uint4*>(&H[o])[1] = hv1;
        reinterpret_cast<uint4*>(&L[o])[0] = lv0; reinterpret_cast<uint4*>(&L[o])[1] = lv1;
    }
}

// ---- V converter (transposed): Vtmp [bh][t][64] fp32 -> bf16 planes [bh][d][T] ----
__global__ __launch_bounds__(256) void cvt_kv_vt_kernel(const float* __restrict__ Vtmp,
        unsigned short* __restrict__ Vh, unsigned short* __restrict__ Vl) {
    __shared__ float tile[64][65];
    const int s0 = blockIdx.x * 64;
    const int bh = blockIdx.y;
    const int tid = threadIdx.x;
    {
        int r = tid >> 2, c0 = (tid & 3) * 16;
        const float* src = Vtmp + ((size_t)bh * T + s0 + r) * 64 + c0;
        #pragma unroll
        for (int u = 0; u < 4; ++u) {
            float4 w = *reinterpret_cast<const float4*>(src + u * 4);
            tile[r][c0 + u * 4 + 0] = w.x; tile[r][c0 + u * 4 + 1] = w.y;
            tile[r][c0 + u * 4 + 2] = w.z; tile[r][c0 + u * 4 + 3] = w.w;
        }
    }
    __syncthreads();
    {
        int d = tid >> 2, cs = (tid & 3) * 16;
        unsigned short hh[16], ll[16];
        #pragma unroll
        for (int j = 0; j < 16; ++j) bf16split(tile[cs + j][d], hh[j], ll[j]);
        uint4 hv0, hv1, lv0, lv1;
        hv0.x = (unsigned)hh[0] | ((unsigned)hh[1] << 16);  hv0.y = (unsigned)hh[2] | ((unsigned)hh[3] << 16);
        hv0.z = (unsigned)hh[4] | ((unsigned)hh[5] << 16);  hv0.w = (unsigned)hh[6] | ((unsigned)hh[7] << 16);
        hv1.x = (unsigned)hh[8] | ((unsigned)hh[9] << 16);  hv1.y = (unsigned)hh[10] | ((unsigned)hh[11] << 16);
        hv1.z = (unsigned)hh[12] | ((unsigned)hh[13] << 16); hv1.w = (unsigned)hh[14] | ((unsigned)hh[15] << 16);
        lv0.x = (unsigned)ll[0] | ((unsigned)ll[1] << 16);  lv0.y = (unsigned)ll[2] | ((unsigned)ll[3] << 16);
        lv0.z = (unsigned)ll[4] | ((unsigned)ll[5] << 16);  lv0.w = (unsigned)ll[6] | ((unsigned)ll[7] << 16);
        lv1.x = (unsigned)ll[8] | ((unsigned)ll[9] << 16);  lv1.y = (unsigned)ll[10] | ((unsigned)ll[11] << 16);
        lv1.z = (unsigned)ll[12] | ((unsigned)ll[13] << 16); lv1.w = (unsigned)ll[14] | ((unsigned)ll[15] << 16);
        size_t o = ((size_t)bh * 64 + d) * T + s0 + cs;
        reinterpret_cast<uint4*>(&Vh[o])[0] = hv0; reinterpret_cast<uint4*>(&Vh[o])[1] = hv1;
        reinterpret_cast<uint4*>(&Vl[o])[0] = lv0; reinterpret_cast<uint4*>(&Vl[o])[1] = lv1;
    }
}

// ---------------- split-bf16 MFMA GEMM (generic): C = A*B + bias ----------------
// Swapped operand order: mfma(B,A) -> lane holds 4 consecutive n (cols) at one m
// (row). Epilogue = float4 stores (was 64 scalar stores).
#define LDST 40
__global__ __launch_bounds__(256) void gemm_mfma_kernel(
        const unsigned short* __restrict__ Ah, const unsigned short* __restrict__ Al,
        const unsigned short* __restrict__ Bh, const unsigned short* __restrict__ Bl,
        const float* __restrict__ bias, float* __restrict__ Cm,
        int M, int N, int K) {
    __shared__ unsigned short lA[2][128 * LDST];
    __shared__ unsigned short lB[2][128 * LDST];
    const int tid = threadIdx.x;
    const int bm = blockIdx.y * 128, bn = blockIdx.x * 128;
    const int lane = tid & 63, wid = tid >> 6;
    const int wr = wid >> 1, wc = wid & 1;
    f32x4 acc[4][4];
    #pragma unroll
    for (int i = 0; i < 4; ++i)
        #pragma unroll
        for (int j = 0; j < 4; ++j) acc[i][j] = (f32x4){0.f, 0.f, 0.f, 0.f};
    const int srow = tid >> 2, sk8 = (tid & 3) * 8;
    const int arb = wr * 64 + (lane & 15);
    const int brb = wc * 64 + (lane & 15);
    const int koff = (lane >> 4) * 8;
    for (int k0 = 0; k0 < K; k0 += 32) {
        __syncthreads();
        #pragma unroll
        for (int c = 0; c < 2; ++c) {
            int row = srow + 64 * c;
            uint4 va = *reinterpret_cast<const uint4*>(&Ah[(size_t)(bm + row) * K + k0 + sk8]);
            uint4 vb = *reinterpret_cast<const uint4*>(&Al[(size_t)(bm + row) * K + k0 + sk8]);
            uint4 vc = *reinterpret_cast<const uint4*>(&Bh[(size_t)(bn + row) * K + k0 + sk8]);
            uint4 vd = *reinterpret_cast<const uint4*>(&Bl[(size_t)(bn + row) * K + k0 + sk8]);
            *reinterpret_cast<uint4*>(&lA[0][row * LDST + sk8]) = va;
            *reinterpret_cast<uint4*>(&lA[1][row * LDST + sk8]) = vb;
            *reinterpret_cast<uint4*>(&lB[0][row * LDST + sk8]) = vc;
            *reinterpret_cast<uint4*>(&lB[1][row * LDST + sk8]) = vd;
        }
        __syncthreads();
        bf16x8 fa[2][4], fb[2][4];
        #pragma unroll
        for (int fi = 0; fi < 4; ++fi) {
            fa[0][fi] = *reinterpret_cast<const bf16x8*>(&lA[0][(arb + fi * 16) * LDST + koff]);
            fa[1][fi] = *reinterpret_cast<const bf16x8*>(&lA[1][(arb + fi * 16) * LDST + koff]);
            fb[0][fi] = *reinterpret_cast<const bf16x8*>(&lB[0][(brb + fi * 16) * LDST + koff]);
            fb[1][fi] = *reinterpret_cast<const bf16x8*>(&lB[1][(brb + fi * 16) * LDST + koff]);
        }
        #pragma unroll
        for (int fi = 0; fi < 4; ++fi)
            #pragma unroll
            for (int fj = 0; fj < 4; ++fj) {
                // swapped: D[n][m]; products Bh*Ah + Bh*Al + Bl*Ah (same 3 cross terms)
                acc[fi][fj] = __builtin_amdgcn_mfma_f32_16x16x32_bf16(fb[0][fj], fa[0][fi], acc[fi][fj], 0, 0, 0);
                acc[fi][fj] = __builtin_amdgcn_mfma_f32_16x16x32_bf16(fb[0][fj], fa[1][fi], acc[fi][fj], 0, 0, 0);
                acc[fi][fj] = __builtin_amdgcn_mfma_f32_16x16x32_bf16(fb[1][fj], fa[0][fi], acc[fi][fj], 0, 0, 0);
            }
    }
    // epilogue: lane holds m = ...+(lane&15); p walks n -> float4 stores
    const int mloc = lane & 15, ng = (lane >> 4) * 4;
    #pragma unroll
    for (int fi = 0; fi < 4; ++fi) {
        int row = bm + wr * 64 + fi * 16 + mloc;
        #pragma unroll
        for (int fj = 0; fj < 4; ++fj) {
            int n0 = bn + wc * 64 + fj * 16 + ng;
            float4 bv = *reinterpret_cast<const float4*>(&bias[n0]);
            float4 o4 = {acc[fi][fj][0] + bv.x, acc[fi][fj][1] + bv.y,
                         acc[fi][fj][2] + bv.z, acc[fi][fj][3] + bv.w};
            *reinterpret_cast<float4*>(&Cm[(size_t)row * N + n0]) = o4;
        }
    }
}

// ---------------- gemm1 specialized: qkv = x@W_attn + b, writing planes directly ----
// Swapped operand order: lane holds 4 consecutive d at one t -> uint2/float4 stores.
__global__ __launch_bounds__(256) void gemm_qkv_mfma_kernel(
        const unsigned short* __restrict__ Ah, const unsigned short* __restrict__ Al,
        const unsigned short* __restrict__ Bh, const unsigned short* __restrict__ Bl,
        const float* __restrict__ bias,
        unsigned short* __restrict__ Qh, unsigned short* __restrict__ Ql,
        unsigned short* __restrict__ Kh, unsigned short* __restrict__ Kl,
        float* __restrict__ Vtmp) {
    const int K = CE;
    __shared__ unsigned short lA[2][128 * LDST];
    __shared__ unsigned short lB[2][128 * LDST];
    const int tid = threadIdx.x;
    const int bm = blockIdx.y * 128, bn = blockIdx.x * 128;
    const int lane = tid & 63, wid = tid >> 6;
    const int wr = wid >> 1, wc = wid & 1;
    f32x4 acc[4][4];
    #pragma unroll
    for (int i = 0; i < 4; ++i)
        #pragma unroll
        for (int j = 0; j < 4; ++j) acc[i][j] = (f32x4){0.f, 0.f, 0.f, 0.f};
    const int srow = tid >> 2, sk8 = (tid & 3) * 8;
    const int arb = wr * 64 + (lane & 15);
    const int brb = wc * 64 + (lane & 15);
    const int koff = (lane >> 4) * 8;
    for (int k0 = 0; k0 < K; k0 += 32) {
        __syncthreads();
        #pragma unroll
        for (int c = 0; c < 2; ++c) {
            int row = srow + 64 * c;
            uint4 va = *reinterpret_cast<const uint4*>(&Ah[(size_t)(bm + row) * K + k0 + sk8]);
            uint4 vb = *reinterpret_cast<const uint4*>(&Al[(size_t)(bm + row) * K + k0 + sk8]);
            uint4 vc = *reinterpret_cast<const uint4*>(&Bh[(size_t)(bn + row) * K + k0 + sk8]);
            uint4 vd = *reinterpret_cast<const uint4*>(&Bl[(size_t)(bn + row) * K + k0 + sk8]);
            *reinterpret_cast<uint4*>(&lA[0][row * LDST + sk8]) = va;
            *reinterpret_cast<uint4*>(&lA[1][row * LDST + sk8]) = vb;
            *reinterpret_cast<uint4*>(&lB[0][row * LDST + sk8]) = vc;
            *reinterpret_cast<uint4*>(&lB[1][row * LDST + sk8]) = vd;
        }
        __syncthreads();
        bf16x8 fa[2][4], fb[2][4];
        #pragma unroll
        for (int fi = 0; fi < 4; ++fi) {
            fa[0][fi] = *reinterpret_cast<const bf16x8*>(&lA[0][(arb + fi * 16) * LDST + koff]);
            fa[1][fi] = *reinterpret_cast<const bf16x8*>(&lA[1][(arb + fi * 16) * LDST + koff]);
            fb[0][fi] = *reinterpret_cast<const bf16x8*>(&lB[0][(brb + fi * 16) * LDST + koff]);
            fb[1][fi] = *reinterpret_cast<const bf16x8*>(&lB[1][(brb + fi * 16) * LDST + koff]);
        }
        #pragma unroll
        for (int fi = 0; fi < 4; ++fi)
            #pragma unroll
            for (int fj = 0; fj < 4; ++fj) {
                acc[fi][fj] = __builtin_amdgcn_mfma_f32_16x16x32_bf16(fb[0][fj], fa[0][fi], acc[fi][fj], 0, 0, 0);
                acc[fi][fj] = __builtin_amdgcn_mfma_f32_16x16x32_bf16(fb[0][fj], fa[1][fi], acc[fi][fj], 0, 0, 0);
                acc[fi][fj] = __builtin_amdgcn_mfma_f32_16x16x32_bf16(fb[1][fj], fa[0][fi], acc[fi][fj], 0, 0, 0);
            }
    }
    // epilogue: wave's 64 cols = one head of one region; lane holds one t,
    // p walks d -> vectorized plane stores
    const int colbase = bn + wc * 64;
    const int region = colbase / 768;           // 0=Q, 1=K, 2=V
    const int h = (colbase % 768) >> 6;
    const int mloc = lane & 15, ng = (lane >> 4) * 4;
    #pragma unroll
    for (int fi = 0; fi < 4; ++fi) {
        int tg = bm + wr * 64 + fi * 16 + mloc;
        int bb = tg >> 11, t = tg & (T - 1);
        #pragma unroll
        for (int fj = 0; fj < 4; ++fj) {
            int dbase = fj * 16 + ng;
            float4 bv = *reinterpret_cast<const float4*>(&bias[colbase + dbase]);
            float v0 = acc[fi][fj][0] + bv.x, v1 = acc[fi][fj][1] + bv.y;
            float v2 = acc[fi][fj][2] + bv.z, v3 = acc[fi][fj][3] + bv.w;
            size_t o = ((size_t)(bb * NH + h) * T + t) * 64 + dbase;
            if (region == 2) {
                float4 o4 = {v0, v1, v2, v3};
                *reinterpret_cast<float4*>(&Vtmp[o]) = o4;
            } else {
                unsigned short hh[4], ll[4];
                bf16split(v0, hh[0], ll[0]); bf16split(v1, hh[1], ll[1]);
                bf16split(v2, hh[2], ll[2]); bf16split(v3, hh[3], ll[3]);
                uint2 ph = {(unsigned)hh[0] | ((unsigned)hh[1] << 16),
                            (unsigned)hh[2] | ((unsigned)hh[3] << 16)};
                uint2 pl = {(unsigned)ll[0] | ((unsigned)ll[1] << 16),
                            (unsigned)ll[2] | ((unsigned)ll[3] << 16)};
                if (region == 0) {
                    *reinterpret_cast<uint2*>(&Qh[o]) = ph;
                    *reinterpret_cast<uint2*>(&Ql[o]) = pl;
                } else {
                    *reinterpret_cast<uint2*>(&Kh[o]) = ph;
                    *reinterpret_cast<uint2*>(&Kl[o]) = pl;
                }
            }
        }
    }
}

// ---------------- fp32 GEMM fallback (small ws) ----------------
__global__ __launch_bounds__(256) void gemm_bias_kernel(
        const float* __restrict__ A, const float* __restrict__ B,
        const float* __restrict__ bias, float* __restrict__ Cm,
        int M, int N, int K) {
    __shared__ float As[16][64];
    __shared__ float Bs[16][68];
    const int tid = threadIdx.x;
    const int ty = tid >> 4, tx = tid & 15;
    const int bm = blockIdx.y * 64, bn = blockIdx.x * 64;
    float acc[4][4] = {};
    for (int k0 = 0; k0 < K; k0 += 16) {
        {
            int r = tid >> 2;
            int kk = (tid & 3) * 4;
            float4 a = *reinterpret_cast<const float4*>(&A[(size_t)(bm + r) * K + k0 + kk]);
            As[kk + 0][r] = a.x; As[kk + 1][r] = a.y; As[kk + 2][r] = a.z; As[kk + 3][r] = a.w;
        }
        {
            int kk = tid >> 4;
            int c = (tid & 15) * 4;
            *reinterpret_cast<float4*>(&Bs[kk][c]) =
                *reinterpret_cast<const float4*>(&B[(size_t)(k0 + kk) * N + bn + c]);
        }
        __syncthreads();
        #pragma unroll
        for (int kk = 0; kk < 16; ++kk) {
            float4 a4 = *reinterpret_cast<const float4*>(&As[kk][ty * 4]);
            float4 b4 = *reinterpret_cast<const float4*>(&Bs[kk][tx * 4]);
            float av[4] = {a4.x, a4.y, a4.z, a4.w};
            float bv[4] = {b4.x, b4.y, b4.z, b4.w};
            #pragma unroll
            for (int i = 0; i < 4; ++i)
                #pragma unroll
                for (int j = 0; j < 4; ++j)
                    acc[i][j] = fmaf(av[i], bv[j], acc[i][j]);
        }
        __syncthreads();
    }
    #pragma unroll
    for (int i = 0; i < 4; ++i) {
        int row = bm + ty * 4 + i;
        #pragma unroll
        for (int j = 0; j < 4; ++j) {
            int col = bn + tx * 4 + j;
            Cm[(size_t)row * N + col] = acc[i][j] + bias[col];
        }
    }
}

#define FST 72   // LDS row stride (bf16), 144 B = 16B-aligned rows

// ---------------- s0 via MFMA + fused column sums: S, Psum ----------------
__global__ __launch_bounds__(256) void s0_mfma_kernel(
        const unsigned short* __restrict__ Qh, const unsigned short* __restrict__ Ql,
        const unsigned short* __restrict__ Kh, const unsigned short* __restrict__ Kl,
        float* __restrict__ S, float* __restrict__ Psum) {
    const int kb = blockIdx.x * 64, qb = blockIdx.y * 64, b = blockIdx.z;
    const int tid = threadIdx.x;
    float* Sb = S + (size_t)b * T * T;
    if (kb > qb) {  // entire tile masked -> zero S tile + zero Psum entries
        const int ty = tid >> 4, tx = tid & 15;
        #pragma unroll
        for (int i = 0; i < 4; ++i) {
            float4 z = {0.f, 0.f, 0.f, 0.f};
            *reinterpret_cast<float4*>(&Sb[(size_t)(qb + ty * 4 + i) * T + kb + tx * 4]) = z;
        }
        if (tid < 64) Psum[((size_t)(b * 32 + (qb >> 6)) * T) + kb + tid] = 0.f;
        return;
    }
    const int lane = tid & 63, w = tid >> 6;
    const int fr = lane & 15, fg = lane >> 4;
    __shared__ unsigned short Ks[2][64 * FST];
    __shared__ float csum[4][64];
    const int hb0 = b * NH;   // head 0
    {
        const int sr = tid >> 2, sc0 = (tid & 3) * 16;
        const unsigned short* kh = Kh + ((size_t)hb0 * T + kb + sr) * 64 + sc0;
        const unsigned short* kl = Kl + ((size_t)hb0 * T + kb + sr) * 64 + sc0;
        uint4 a0 = reinterpret_cast<const uint4*>(kh)[0];
        uint4 a1 = reinterpret_cast<const uint4*>(kh)[1];
        uint4 b0 = reinterpret_cast<const uint4*>(kl)[0];
        uint4 b1 = reinterpret_cast<const uint4*>(kl)[1];
        *reinterpret_cast<uint4*>(&Ks[0][sr * FST + sc0 + 0]) = a0;
        *reinterpret_cast<uint4*>(&Ks[0][sr * FST + sc0 + 8]) = a1;
        *reinterpret_cast<uint4*>(&Ks[1][sr * FST + sc0 + 0]) = b0;
        *reinterpret_cast<uint4*>(&Ks[1][sr * FST + sc0 + 8]) = b1;
    }
    bf16x8 qh[2], ql[2];
    #pragma unroll
    for (int ks = 0; ks < 2; ++ks) {
        size_t qo = ((size_t)hb0 * T + qb + w * 16 + fr) * 64 + ks * 32 + fg * 8;
        qh[ks] = *reinterpret_cast<const bf16x8*>(&Qh[qo]);
        ql[ks] = *reinterpret_cast<const bf16x8*>(&Ql[qo]);
    }
    __syncthreads();
    f32x4 qk[4];
    #pragma unroll
    for (int fj = 0; fj < 4; ++fj) qk[fj] = (f32x4){0.f, 0.f, 0.f, 0.f};
    #pragma unroll
    for (int ks = 0; ks < 2; ++ks) {
        bf16x8 kbh[4], kbl[4];
        #pragma unroll
        for (int fj = 0; fj < 4; ++fj) {
            kbh[fj] = *reinterpret_cast<const bf16x8*>(&Ks[0][(fj * 16 + fr) * FST + ks * 32 + fg * 8]);
            kbl[fj] = *reinterpret_cast<const bf16x8*>(&Ks[1][(fj * 16 + fr) * FST + ks * 32 + fg * 8]);
        }
        #pragma unroll
        for (int fj = 0; fj < 4; ++fj) {
            qk[fj] = __builtin_amdgcn_mfma_f32_16x16x32_bf16(qh[ks], kbh[fj], qk[fj], 0, 0, 0);
            qk[fj] = __builtin_amdgcn_mfma_f32_16x16x32_bf16(qh[ks], kbl[fj], qk[fj], 0, 0, 0);
            qk[fj] = __builtin_amdgcn_mfma_f32_16x16x32_bf16(ql[ks], kbh[fj], qk[fj], 0, 0, 0);
        }
    }
    float colsum[4] = {0.f, 0.f, 0.f, 0.f};
    #pragma unroll
    for (int p = 0; p < 4; ++p) {
        int t = qb + w * 16 + fg * 4 + p;
        #pragma unroll
        for (int fj = 0; fj < 4; ++fj) {
            int s = kb + fj * 16 + fr;
            float v = qk[fj][p] * 0.125f;
            float o = (s >= 1 && s < t) ? fmaxf(v, 0.0f) : 0.0f;
            Sb[(size_t)t * T + s] = o;
            colsum[fj] += o;
        }
    }
    // fused colsum: reduce over fg (xor16, xor32) then across waves via LDS
    #pragma unroll
    for (int fj = 0; fj < 4; ++fj) {
        colsum[fj] += __shfl_xor(colsum[fj], 16);
        colsum[fj] += __shfl_xor(colsum[fj], 32);
    }
    if (lane < 16) {
        #pragma unroll
        for (int fj = 0; fj < 4; ++fj) csum[w][fj * 16 + lane] = colsum[fj];
    }
    __syncthreads();
    if (tid < 64) {
        float v = csum[0][tid] + csum[1][tid] + csum[2][tid] + csum[3][tid];
        Psum[((size_t)(b * 32 + (qb >> 6)) * T) + kb + tid] = v;
    }
}

// ---------------- fp32 s0 fallback ----------------
__global__ __launch_bounds__(256) void s0_kernel(const float* __restrict__ qkv,
                                                 float* __restrict__ S) {
    const int kb = blockIdx.x * 64, qb = blockIdx.y * 64, b = blockIdx.z;
    const int tid = threadIdx.x, ty = tid >> 4, tx = tid & 15;
    float* Sb = S + (size_t)b * T * T;
    if (kb > qb) {
        #pragma unroll
        for (int i = 0; i < 4; ++i) {
            int row = qb + ty * 4 + i;
            float4 z = {0.f, 0.f, 0.f, 0.f};
            *reinterpret_cast<float4*>(&Sb[(size_t)row * T + kb + tx * 4]) = z;
        }
        return;
    }
    __shared__ float Qt[64][68];
    __shared__ float Kt[64][68];
    {
        int r = tid >> 2;
        int c0 = (tid & 3) * 16;
        const float* qrow = qkv + (size_t)(b * T + qb + r) * C3 + 0;
        const float* krow = qkv + (size_t)(b * T + kb + r) * C3 + 768;
        #pragma unroll
        for (int u = 0; u < 4; ++u) {
            float4 q4 = *reinterpret_cast<const float4*>(&qrow[c0 + u * 4]);
            float4 k4 = *reinterpret_cast<const float4*>(&krow[c0 + u * 4]);
            int d = c0 + u * 4;
            Qt[d + 0][r] = q4.x; Qt[d + 1][r] = q4.y; Qt[d + 2][r] = q4.z; Qt[d + 3][r] = q4.w;
            Kt[d + 0][r] = k4.x; Kt[d + 1][r] = k4.y; Kt[d + 2][r] = k4.z; Kt[d + 3][r] = k4.w;
        }
    }
    __syncthreads();
    float acc[4][4] = {};
    #pragma unroll
    for (int d = 0; d < 64; ++d) {
        float4 qv = *reinterpret_cast<const float4*>(&Qt[d][ty * 4]);
        float4 kv = *reinterpret_cast<const float4*>(&Kt[d][tx * 4]);
        float qa[4] = {qv.x, qv.y, qv.z, qv.w};
        float ka[4] = {kv.x, kv.y, kv.z, kv.w};
        #pragma unroll
        for (int i = 0; i < 4; ++i)
            #pragma unroll
            for (int j = 0; j < 4; ++j)
                acc[i][j] = fmaf(qa[i], ka[j], acc[i][j]);
    }
    #pragma unroll
    for (int i = 0; i < 4; ++i) {
        int t = qb + ty * 4 + i;
        float o[4];
        #pragma unroll
        for (int j = 0; j < 4; ++j) {
            int s = kb + tx * 4 + j;
            float v = acc[i][j] * 0.125f;
            o[j] = (s >= 1 && s < t) ? fmaxf(v, 0.0f) : 0.0f;
        }
        float4 o4 = {o[0], o[1], o[2], o[3]};
        *reinterpret_cast<float4*>(&Sb[(size_t)t * T + kb + tx * 4]) = o4;
    }
}

// ---------------- segmented scan: FF = cumsum_t(S) ----------------
__global__ __launch_bounds__(256) void colsum_kernel(const float* __restrict__ S,
                                                     float* __restrict__ Psum) {
    int s = blockIdx.x * 256 + threadIdx.x;
    int j = blockIdx.y, b = blockIdx.z;
    const float* Sb = S + (size_t)b * T * T;
    float sum = 0.f;
    for (int r = 0; r < 64; ++r) sum += Sb[(size_t)(j * 64 + r) * T + s];
    Psum[((size_t)b * 32 + j) * T + s] = sum;
}

// prefetch all 32 loads (independent), then scan in registers: 32x latency -> 1x
__global__ __launch_bounds__(256) void scanseg_kernel(float* __restrict__ Psum) {
    int s = blockIdx.x * 256 + threadIdx.x;
    int b = blockIdx.y;
    float v[32];
    #pragma unroll
    for (int j = 0; j < 32; ++j)
        v[j] = Psum[((size_t)(b * 32 + j)) * T + s];
    float run = 0.f;
    #pragma unroll
    for (int j = 0; j < 32; ++j) {
        Psum[((size_t)(b * 32 + j)) * T + s] = run;
        run += v[j];
    }
}

__global__ __launch_bounds__(256) void ffscan_kernel(float* __restrict__ S,
                                                     const float* __restrict__ Psum) {
    int s = blockIdx.x * 256 + threadIdx.x;
    int j = blockIdx.y, b = blockIdx.z;
    float run = Psum[((size_t)b * 32 + j) * T + s];
    float* Sb = S + (size_t)b * T * T;
    for (int r = 0; r < 64; ++r) {
        size_t idx = (size_t)(j * 64 + r) * T + s;
        run += Sb[idx];
        Sb[idx] = run;
    }
}

// ---------------- task table: 40 tasks/(b,h), size-descending ----------------
__device__ const int FTQ[40] = {15,15,15,15,14,14,14,13,13,13,12,12,12,11,11,11,10,10,9,9,8,8,7,7,6,5,4,3,14,10,6,2,13,9,5,1,12,8,4,0};
__device__ const int FK0[40] = {0,8,16,24,0,8,16,0,8,16,0,8,16,0,8,16,0,8,0,8,0,8,0,8,0,0,0,0,24,16,8,0,24,16,8,0,24,16,8,0};
__device__ const int FK1[40] = {8,16,24,32,8,16,24,8,16,24,8,16,24,8,16,24,8,16,8,16,8,16,8,16,8,8,8,8,30,22,14,6,28,20,12,4,26,18,10,2};
__device__ const int FCB[12] = {0,2,4,6,8,11,14,17,20,24,28,32};   // chunk base per Q-4

// ---------------- 32x32 swapped-operand MFMA flash attention ----------------
// Direct rows + merged rows both emit Y as bf16 hi/lo planes (gemm2 input).
__global__ __launch_bounds__(256) void flash_mfma_kernel(
        const unsigned short* __restrict__ Qh, const unsigned short* __restrict__ Ql,
        const unsigned short* __restrict__ Kh, const unsigned short* __restrict__ Kl,
        const unsigned short* __restrict__ Vth, const unsigned short* __restrict__ Vtl,
        const float* __restrict__ FF,
        unsigned short* __restrict__ Yh, unsigned short* __restrict__ Yl,
        float* __restrict__ PART) {
    const int hb = blockIdx.x;
    const int h = hb % NH, b = hb / NH;
    const int u = blockIdx.y;
    const int tq = FTQ[u], kt0 = FK0[u], kt1 = FK1[u];
    const int qb = tq * 128;
    const int tid = threadIdx.x;
    const int lane = tid & 63, w = tid >> 6;
    const int q31 = lane & 31, hi = lane >> 5;
    const int trow = qb + w * 32 + q31;      // this lane's q-row (absolute t)
    __shared__ unsigned short KS[2][64 * FST];   // K [s][d] hi/lo
    __shared__ unsigned short VS[2][64 * FST];   // V^T [d][s] hi/lo

    bf16x8 qfh[4], qfl[4];
    #pragma unroll
    for (int dblk = 0; dblk < 4; ++dblk) {
        size_t qo = ((size_t)hb * T + trow) * 64 + dblk * 16 + hi * 8;
        qfh[dblk] = *reinterpret_cast<const bf16x8*>(&Qh[qo]);
        qfl[dblk] = *reinterpret_cast<const bf16x8*>(&Ql[qo]);
    }

    f32x16 oacc0 = (f32x16)(0.f), oacc1 = (f32x16)(0.f);
    float m = -1e30f, l = 0.f;
    const float* FFb = FF + (size_t)b * T * T;
    const int sr = tid >> 2, sc0 = (tid & 3) * 16;

    for (int kt = kt0; kt < kt1; ++kt) {
        const int kb = kt * 64;
        __syncthreads();
        {
            const unsigned short* ksrc = Kh + ((size_t)hb * T + kb + sr) * 64 + sc0;
            const unsigned short* ksrl = Kl + ((size_t)hb * T + kb + sr) * 64 + sc0;
            const unsigned short* vsrc = Vth + ((size_t)hb * 64 + sr) * T + kb + sc0;
            const unsigned short* vsrl = Vtl + ((size_t)hb * 64 + sr) * T + kb + sc0;
            uint4 k0v = reinterpret_cast<const uint4*>(ksrc)[0];
            uint4 k1v = reinterpret_cast<const uint4*>(ksrc)[1];
            uint4 k2v = reinterpret_cast<const uint4*>(ksrl)[0];
            uint4 k3v = reinterpret_cast<const uint4*>(ksrl)[1];
            uint4 v0v = reinterpret_cast<const uint4*>(vsrc)[0];
            uint4 v1v = reinterpret_cast<const uint4*>(vsrc)[1];
            uint4 v2v = reinterpret_cast<const uint4*>(vsrl)[0];
            uint4 v3v = reinterpret_cast<const uint4*>(vsrl)[1];
            *reinterpret_cast<uint4*>(&KS[0][sr * FST + sc0 + 0]) = k0v;
            *reinterpret_cast<uint4*>(&KS[0][sr * FST + sc0 + 8]) = k1v;
            *reinterpret_cast<uint4*>(&KS[1][sr * FST + sc0 + 0]) = k2v;
            *reinterpret_cast<uint4*>(&KS[1][sr * FST + sc0 + 8]) = k3v;
            *reinterpret_cast<uint4*>(&VS[0][sr * FST + sc0 + 0]) = v0v;
            *reinterpret_cast<uint4*>(&VS[0][sr * FST + sc0 + 8]) = v1v;
            *reinterpret_cast<uint4*>(&VS[1][sr * FST + sc0 + 0]) = v2v;
            *reinterpret_cast<uint4*>(&VS[1][sr * FST + sc0 + 8]) = v3v;
        }
        __syncthreads();
        f32x16 acc[2];
        acc[0] = (f32x16)(0.f); acc[1] = (f32x16)(0.f);
        #pragma unroll
        for (int sb = 0; sb < 2; ++sb) {
            #pragma unroll
            for (int dblk = 0; dblk < 4; ++dblk) {
                bf16x8 kfh = *reinterpret_cast<const bf16x8*>(&KS[0][(sb * 32 + q31) * FST + dblk * 16 + hi * 8]);
                bf16x8 kfl = *reinterpret_cast<const bf16x8*>(&KS[1][(sb * 32 + q31) * FST + dblk * 16 + hi * 8]);
                acc[sb] = __builtin_amdgcn_mfma_f32_32x32x16_bf16(kfh, qfh[dblk], acc[sb], 0, 0, 0);
                acc[sb] = __builtin_amdgcn_mfma_f32_32x32x16_bf16(kfh, qfl[dblk], acc[sb], 0, 0, 0);
                acc[sb] = __builtin_amdgcn_mfma_f32_32x32x16_bf16(kfl, qfh[dblk], acc[sb], 0, 0, 0);
            }
        }
        float pv[2][16];
        #pragma unroll
        for (int sb = 0; sb < 2; ++sb) {
            #pragma unroll
            for (int g = 0; g < 4; ++g) {
                float4 f4 = *reinterpret_cast<const float4*>(
                    &FFb[(size_t)trow * T + kb + sb * 32 + g * 8 + hi * 4]);
                float fv[4] = {f4.x, f4.y, f4.z, f4.w};
                #pragma unroll
                for (int a = 0; a < 4; ++a) {
                    int r = g * 4 + a;
                    int s = kb + sb * 32 + a + g * 8 + hi * 4;
                    float val = acc[sb][r] * 0.125f - fv[a];
                    pv[sb][r] = (s <= trow) ? val : -1e30f;
                }
            }
        }
        float tm = pv[0][0];
        #pragma unroll
        for (int sb = 0; sb < 2; ++sb)
            #pragma unroll
            for (int r = 0; r < 16; ++r) tm = fmaxf(tm, pv[sb][r]);
        tm = fmaxf(tm, __shfl_xor(tm, 32));
        float mn = fmaxf(m, tm);
        float scale = __expf(m - mn);
        float rs = 0.f;
        #pragma unroll
        for (int sb = 0; sb < 2; ++sb)
            #pragma unroll
            for (int r = 0; r < 16; ++r) {
                float pe = __expf(pv[sb][r] - mn);
                pv[sb][r] = pe; rs += pe;
            }
        rs += __shfl_xor(rs, 32);
        l = l * scale + rs;
        m = mn;
        oacc0 *= scale; oacc1 *= scale;
        unsigned wh[2][4][2], wl[2][4][2];
        #pragma unroll
        for (int sb = 0; sb < 2; ++sb)
            #pragma unroll
            for (int bq = 0; bq < 4; ++bq)
                #pragma unroll
                for (int h2 = 0; h2 < 2; ++h2)
                    packP(pv[sb][4 * bq + 2 * h2], pv[sb][4 * bq + 2 * h2 + 1],
                          wh[sb][bq][h2], wl[sb][bq][h2]);
        #pragma unroll
        for (int kk = 0; kk < 4; ++kk) {
            const int sb = kk >> 1;
            const int b0 = 2 * (kk & 1), b1 = b0 + 1;
            unsigned sh_b1_0 = (unsigned)__shfl_xor((int)wh[sb][b1][0], 32);
            unsigned sh_b1_1 = (unsigned)__shfl_xor((int)wh[sb][b1][1], 32);
            unsigned sh_b0_0 = (unsigned)__shfl_xor((int)wh[sb][b0][0], 32);
            unsigned sh_b0_1 = (unsigned)__shfl_xor((int)wh[sb][b0][1], 32);
            unsigned sl_b1_0 = (unsigned)__shfl_xor((int)wl[sb][b1][0], 32);
            unsigned sl_b1_1 = (unsigned)__shfl_xor((int)wl[sb][b1][1], 32);
            unsigned sl_b0_0 = (unsigned)__shfl_xor((int)wl[sb][b0][0], 32);
            unsigned sl_b0_1 = (unsigned)__shfl_xor((int)wl[sb][b0][1], 32);
            u32x4 th, tl;
            th[0] = hi ? sh_b1_0 : wh[sb][b0][0];
            th[1] = hi ? sh_b1_1 : wh[sb][b0][1];
            th[2] = hi ? wh[sb][b1][0] : sh_b0_0;
            th[3] = hi ? wh[sb][b1][1] : sh_b0_1;
            tl[0] = hi ? sl_b1_0 : wl[sb][b0][0];
            tl[1] = hi ? sl_b1_1 : wl[sb][b0][1];
            tl[2] = hi ? wl[sb][b1][0] : sl_b0_0;
            tl[3] = hi ? wl[sb][b1][1] : sl_b0_1;
            bf16x8 pbh = __builtin_bit_cast(bf16x8, th);
            bf16x8 pbl = __builtin_bit_cast(bf16x8, tl);
            {   // db = 0
                bf16x8 vfh = *reinterpret_cast<const bf16x8*>(&VS[0][(q31) * FST + kk * 16 + hi * 8]);
                bf16x8 vfl = *reinterpret_cast<const bf16x8*>(&VS[1][(q31) * FST + kk * 16 + hi * 8]);
                oacc0 = __builtin_amdgcn_mfma_f32_32x32x16_bf16(vfh, pbh, oacc0, 0, 0, 0);
                oacc0 = __builtin_amdgcn_mfma_f32_32x32x16_bf16(vfh, pbl, oacc0, 0, 0, 0);
                oacc0 = __builtin_amdgcn_mfma_f32_32x32x16_bf16(vfl, pbh, oacc0, 0, 0, 0);
            }
            {   // db = 1
                bf16x8 vfh = *reinterpret_cast<const bf16x8*>(&VS[0][(32 + q31) * FST + kk * 16 + hi * 8]);
                bf16x8 vfl = *reinterpret_cast<const bf16x8*>(&VS[1][(32 + q31) * FST + kk * 16 + hi * 8]);
                oacc1 = __builtin_amdgcn_mfma_f32_32x32x16_bf16(vfh, pbh, oacc1, 0, 0, 0);
                oacc1 = __builtin_amdgcn_mfma_f32_32x32x16_bf16(vfh, pbl, oacc1, 0, 0, 0);
                oacc1 = __builtin_amdgcn_mfma_f32_32x32x16_bf16(vfl, pbh, oacc1, 0, 0, 0);
            }
        }
    }
    if (tq < 4) {   // direct: normalized bf16-plane write
        float inv = 1.f / l;
        size_t ybase = ((size_t)(b * T + trow)) * CE + h * 64;
        #pragma unroll
        for (int g = 0; g < 4; ++g) {
            unsigned short h0[4], l0[4], h1[4], l1[4];
            #pragma unroll
            for (int i = 0; i < 4; ++i) {
                bf16split(oacc0[4 * g + i] * inv, h0[i], l0[i]);
                bf16split(oacc1[4 * g + i] * inv, h1[i], l1[i]);
            }
            uint2 ph0 = {(unsigned)h0[0] | ((unsigned)h0[1] << 16), (unsigned)h0[2] | ((unsigned)h0[3] << 16)};
            uint2 pl0 = {(unsigned)l0[0] | ((unsigned)l0[1] << 16), (unsigned)l0[2] | ((unsigned)l0[3] << 16)};
            uint2 ph1 = {(unsigned)h1[0] | ((unsigned)h1[1] << 16), (unsigned)h1[2] | ((unsigned)h1[3] << 16)};
            uint2 pl1 = {(unsigned)l1[0] | ((unsigned)l1[1] << 16), (unsigned)l1[2] | ((unsigned)l1[3] << 16)};
            *reinterpret_cast<uint2*>(&Yh[ybase + g * 8 + hi * 4]) = ph0;
            *reinterpret_cast<uint2*>(&Yl[ybase + g * 8 + hi * 4]) = pl0;
            *reinterpret_cast<uint2*>(&Yh[ybase + 32 + g * 8 + hi * 4]) = ph1;
            *reinterpret_cast<uint2*>(&Yl[ybase + 32 + g * 8 + hi * 4]) = pl1;
        }
    } else {        // partial chunk: unnormalized O + (m,l)
        const int ci = FCB[tq - 4] + (kt0 >> 3);
        float* Ob = PART + (size_t)(hb * 36 + ci) * 8448;
        const int rr = w * 32 + q31;
        #pragma unroll
        for (int g = 0; g < 4; ++g) {
            float4 o0 = {oacc0[4 * g + 0], oacc0[4 * g + 1], oacc0[4 * g + 2], oacc0[4 * g + 3]};
            float4 o1 = {oacc1[4 * g + 0], oacc1[4 * g + 1], oacc1[4 * g + 2], oacc1[4 * g + 3]};
            *reinterpret_cast<float4*>(&Ob[rr * 64 + g * 8 + hi * 4]) = o0;
            *reinterpret_cast<float4*>(&Ob[rr * 64 + 32 + g * 8 + hi * 4]) = o1;
        }
        if (hi == 0) { Ob[8192 + rr] = m; Ob[8192 + 128 + rr] = l; }
    }
}

// ---------------- merge 2..4 chunk partials per 128-row block -> Y planes ----------------
__global__ __launch_bounds__(256) void merge128_kernel(const float* __restrict__ PART,
                                                       unsigned short* __restrict__ Yh,
                                                       unsigned short* __restrict__ Yl) {
    const int hb = blockIdx.x;          // 0..23
    const int tq = 4 + blockIdx.y;      // 4..15
    const int h = hb % NH, b = hb / NH;
    const int nch = (tq >= 12) ? 4 : (tq >= 8) ? 3 : 2;
    const float* base = PART + (size_t)(hb * 36 + FCB[tq - 4]) * 8448;
    const int tid = threadIdx.x;
    const int r = tid >> 1, half = tid & 1;
    float mm[4], la[4];
    float M = -1e30f;
    #pragma unroll
    for (int c = 0; c < 4; ++c) {
        int cc = (c < nch) ? c : 0;
        float mv = base[(size_t)cc * 8448 + 8192 + r];
        float lv = base[(size_t)cc * 8448 + 8192 + 128 + r];
        mm[c] = (c < nch) ? mv : -1e30f;
        la[c] = (c < nch) ? lv : 0.f;
        M = fmaxf(M, mm[c]);
    }
    float a[4], L = 0.f;
    #pragma unroll
    for (int c = 0; c < 4; ++c) {
        a[c] = (c < nch) ? __expf(mm[c] - M) : 0.f;
        L += a[c] * la[c];
    }
    float inv = 1.f / L;
    const int t = tq * 128 + r;
    size_t ybase = ((size_t)(b * T + t)) * CE + h * 64 + half * 32;
    #pragma unroll
    for (int uu = 0; uu < 8; ++uu) {
        float ax = 0.f, ay = 0.f, az = 0.f, aw = 0.f;
        #pragma unroll
        for (int c = 0; c < 4; ++c) {
            int cc = (c < nch) ? c : 0;
            float4 x = *reinterpret_cast<const float4*>(
                &base[(size_t)cc * 8448 + r * 64 + half * 32 + uu * 4]);
            ax += a[c] * x.x; ay += a[c] * x.y; az += a[c] * x.z; aw += a[c] * x.w;
        }
        unsigned short hh[4], ll[4];
        bf16split(ax * inv, hh[0], ll[0]); bf16split(ay * inv, hh[1], ll[1]);
        bf16split(az * inv, hh[2], ll[2]); bf16split(aw * inv, hh[3], ll[3]);
        uint2 ph = {(unsigned)hh[0] | ((unsigned)hh[1] << 16), (unsigned)hh[2] | ((unsigned)hh[3] << 16)};
        uint2 pl = {(unsigned)ll[0] | ((unsigned)ll[1] << 16), (unsigned)ll[2] | ((unsigned)ll[3] << 16)};
        *reinterpret_cast<uint2*>(&Yh[ybase + uu * 4]) = ph;
        *reinterpret_cast<uint2*>(&Yl[ybase + uu * 4]) = pl;
    }
}

// ---------------- fp32 flash fallback (small ws) ----------------
__global__ __launch_bounds__(256) void flash_kernel(const float* __restrict__ qkv,
                                                    const float* __restrict__ FF,
                                                    float* __restrict__ Y,
                                                    float* __restrict__ PO,
                                                    float* __restrict__ PML,
                                                    int split) {
    const int hb = blockIdx.x;
    const int h = hb % NH, b = hb / NH;
    int qt, kt0, kt1, mode;
    if (split) {
        const int u = blockIdx.y;
        if (u < 16)      { qt = 16 + u; kt0 = 0;  kt1 = 16;     mode = 1; }
        else if (u < 32) { qt = 31 - u; kt0 = 0;  kt1 = qt + 1; mode = 0; }
        else             { qt = 63 - u; kt0 = 16; kt1 = qt + 1; mode = 2; }
    } else {
        qt = 31 - blockIdx.y; kt0 = 0; kt1 = qt + 1; mode = 0;
    }
    const int qb = qt * 64;
    const int tid = threadIdx.x, ty = tid >> 4, tx = tid & 15;
    __shared__ float Qt[64][68];
    __shared__ float KtPs[64][68];
    __shared__ float Vs[64][68];
    const int r = tid >> 2, c0 = (tid & 3) * 16;
    {
        const float* qrow = qkv + (size_t)(b * T + qb + r) * C3 + h * 64;
        #pragma unroll
        for (int u = 0; u < 4; ++u) {
            float4 q4 = *reinterpret_cast<const float4*>(&qrow[c0 + u * 4]);
            int d = c0 + u * 4;
            Qt[d + 0][r] = q4.x; Qt[d + 1][r] = q4.y; Qt[d + 2][r] = q4.z; Qt[d + 3][r] = q4.w;
        }
    }
    float m[4], l[4], O[4][4];
    #pragma unroll
    for (int i = 0; i < 4; ++i) {
        m[i] = -1e30f; l[i] = 0.f;
        #pragma unroll
        for (int j = 0; j < 4; ++j) O[i][j] = 0.f;
    }
    const float* FFb = FF + (size_t)b * T * T;
    for (int kt = kt0; kt < kt1; ++kt) {
        const int kb = kt * 64;
        __syncthreads();
        {
            const float* krow = qkv + (size_t)(b * T + kb + r) * C3 + 768 + h * 64;
            const float* vrow = qkv + (size_t)(b * T + kb + r) * C3 + 1536 + h * 64;
            #pragma unroll
            for (int u = 0; u < 4; ++u) {
                float4 k4 = *reinterpret_cast<const float4*>(&krow[c0 + u * 4]);
                int d = c0 + u * 4;
                KtPs[d + 0][r] = k4.x; KtPs[d + 1][r] = k4.y;
                KtPs[d + 2][r] = k4.z; KtPs[d + 3][r] = k4.w;
                *reinterpret_cast<float4*>(&Vs[r][c0 + u * 4]) =
                    *reinterpret_cast<const float4*>(&vrow[c0 + u * 4]);
            }
        }
        __syncthreads();
        float sc[4][4] = {};
        #pragma unroll
        for (int d = 0; d < 64; ++d) {
            float4 qv = *reinterpret_cast<const float4*>(&Qt[d][ty * 4]);
            float4 kv = *reinterpret_cast<const float4*>(&KtPs[d][tx * 4]);
            float qa[4] = {qv.x, qv.y, qv.z, qv.w};
            float ka[4] = {kv.x, kv.y, kv.z, kv.w};
            #pragma unroll
            for (int i = 0; i < 4; ++i)
                #pragma unroll
                for (int j = 0; j < 4; ++j)
                    sc[i][j] = fmaf(qa[i], ka[j], sc[i][j]);
        }
        #pragma unroll
        for (int i = 0; i < 4; ++i) {
            int t = qb + ty * 4 + i;
            float4 f4 = *reinterpret_cast<const float4*>(&FFb[(size_t)t * T + kb + tx * 4]);
            float fv[4] = {f4.x, f4.y, f4.z, f4.w};
            #pragma unroll
            for (int j = 0; j < 4; ++j) {
                int s = kb + tx * 4 + j;
                float v = sc[i][j] * 0.125f - fv[j];
                sc[i][j] = (s <= t) ? v : -1e30f;
            }
        }
        #pragma unroll
        for (int i = 0; i < 4; ++i) {
            float tm = fmaxf(fmaxf(sc[i][0], sc[i][1]), fmaxf(sc[i][2], sc[i][3]));
            tm = fmaxf(tm, __shfl_xor(tm, 1));
            tm = fmaxf(tm, __shfl_xor(tm, 2));
            tm = fmaxf(tm, __shfl_xor(tm, 4));
            tm = fmaxf(tm, __shfl_xor(tm, 8));
            float mn = fmaxf(m[i], tm);
            float scale = __expf(m[i] - mn);
            float rs = 0.f;
            #pragma unroll
            for (int j = 0; j < 4; ++j) {
                float p = __expf(sc[i][j] - mn);
                sc[i][j] = p; rs += p;
            }
            rs += __shfl_xor(rs, 1); rs += __shfl_xor(rs, 2);
            rs += __shfl_xor(rs, 4); rs += __shfl_xor(rs, 8);
            l[i] = l[i] * scale + rs;
            m[i] = mn;
            #pragma unroll
            for (int j = 0; j < 4; ++j) O[i][j] *= scale;
        }
        __syncthreads();
        #pragma unroll
        for (int i = 0; i < 4; ++i) {
            float4 p4 = {sc[i][0], sc[i][1], sc[i][2], sc[i][3]};
            *reinterpret_cast<float4*>(&KtPs[ty * 4 + i][tx * 4]) = p4;
        }
        __syncthreads();
        #pragma unroll
        for (int j4 = 0; j4 < 16; ++j4) {
            float pvv[4][4];
            #pragma unroll
            for (int i = 0; i < 4; ++i) {
                float4 t4 = *reinterpret_cast<const float4*>(&KtPs[ty * 4 + i][j4 * 4]);
                pvv[i][0] = t4.x; pvv[i][1] = t4.y; pvv[i][2] = t4.z; pvv[i][3] = t4.w;
            }
            #pragma unroll
            for (int jj = 0; jj < 4; ++jj) {
                float4 v4 = *reinterpret_cast<const float4*>(&Vs[j4 * 4 + jj][tx * 4]);
                float vv[4] = {v4.x, v4.y, v4.z, v4.w};
                #pragma unroll
                for (int i = 0; i < 4; ++i)
                    #pragma unroll
                    for (int dd = 0; dd < 4; ++dd)
                        O[i][dd] = fmaf(pvv[i][jj], vv[dd], O[i][dd]);
            }
        }
    }
    if (mode == 0) {
        #pragma unroll
        for (int i = 0; i < 4; ++i) {
            int t = qb + ty * 4 + i;
            float inv = 1.f / l[i];
            float4 o4 = {O[i][0] * inv, O[i][1] * inv, O[i][2] * inv, O[i][3] * inv};
            *reinterpret_cast<float4*>(&Y[(size_t)(b * T + t) * CE + h * 64 + tx * 4]) = o4;
        }
    } else {
        const int pidx = (b * NH + h) * 16 + (qt - 16);
        float* Ob  = PO  + (size_t)(mode - 1) * (NB * NH * 16 * 4096) + (size_t)pidx * 4096;
        float* mlb = PML + (size_t)(mode - 1) * (NB * NH * 16 * 128)  + (size_t)pidx * 128;
        #pragma unroll
        for (int i = 0; i < 4; ++i) {
            int rr = ty * 4 + i;
            float4 o4 = {O[i][0], O[i][1], O[i][2], O[i][3]};
            *reinterpret_cast<float4*>(&Ob[rr * 64 + tx * 4]) = o4;
            if (tx == 0) { mlb[rr] = m[i]; mlb[64 + rr] = l[i]; }
        }
    }
}

// ---------------- merge the two split-K partials (fp32 fallback path) ----------------
__global__ __launch_bounds__(256) void merge_kernel(const float* __restrict__ PO,
                                                    const float* __restrict__ PML,
                                                    float* __restrict__ Y) {
    const int p = blockIdx.x;
    const int q16 = p & 15;
    const int hb = p >> 4;
    const int h = hb % NH, b = hb / NH;
    const int qt = 16 + q16;
    const float* O0  = PO  + (size_t)p * 4096;
    const float* O1  = PO  + (size_t)(NB * NH * 16) * 4096 + (size_t)p * 4096;
    const float* ml0 = PML + (size_t)p * 128;
    const float* ml1 = PML + (size_t)(NB * NH * 16) * 128  + (size_t)p * 128;
    const int tid = threadIdx.x;
    const int r = tid >> 2, c0 = (tid & 3) * 16;
    float m0 = ml0[r], l0 = ml0[64 + r];
    float m1 = ml1[r], l1 = ml1[64 + r];
    float M  = fmaxf(m0, m1);
    float a0 = __expf(m0 - M), a1 = __expf(m1 - M);
    float inv = 1.f / (a0 * l0 + a1 * l1);
    const int t = qt * 64 + r;
    float* Yrow = Y + (size_t)(b * T + t) * CE + h * 64;
    #pragma unroll
    for (int u = 0; u < 4; ++u) {
        float4 x0 = *reinterpret_cast<const float4*>(&O0[r * 64 + c0 + u * 4]);
        float4 x1 = *reinterpret_cast<const float4*>(&O1[r * 64 + c0 + u * 4]);
        float4 y;
        y.x = (a0 * x0.x + a1 * x1.x) * inv;
        y.y = (a0 * x0.y + a1 * x1.y) * inv;
        y.z = (a0 * x0.z + a1 * x1.z) * inv;
        y.w = (a0 * x0.w + a1 * x1.w) * inv;
        *reinterpret_cast<float4*>(&Yrow[c0 + u * 4]) = y;
    }
}

extern "C" void kernel_launch(void* const* d_in, const int* in_sizes, int n_in,
                              void* d_out, int out_size, void* d_ws, size_t ws_size,
                              hipStream_t stream) {
    const float* x      = (const float*)d_in[0];
    const float* W_attn = (const float*)d_in[1];
    const float* b_attn = (const float*)d_in[2];
    const float* W_proj = (const float*)d_in[3];
    const float* b_proj = (const float*)d_in[4];
    float* out = (float*)d_out;

    char* ws = (char*)d_ws;
    const size_t QKV_BYTES = (size_t)NB * T * C3 * 4;       // 37,748,736
    const size_t S_BYTES   = (size_t)NB * T * T * 4;        // 33,554,432
    const size_t P_BYTES   = (size_t)NB * 32 * T * 4;       //    524,288
    const size_t Y_BYTES   = (size_t)NB * T * CE * 4;       // 12,582,912
    const size_t PO_BYTES  = (size_t)2 * NB * NH * 16 * 4096 * 4;  // 12,582,912
    const size_t PML_BYTES = (size_t)2 * NB * NH * 16 * 128 * 4;   //    393,216
    const size_t PLANE_X   = (size_t)NB * T * CE * 2;       // 6,291,456
    const size_t PLANE_WA  = (size_t)C3 * CE * 2;           // 3,538,944
    const size_t PLANE_WP  = (size_t)CE * CE * 2;           // 1,179,648
    const size_t PLANE_KV  = (size_t)NB * NH * T * 64 * 2;  // 6,291,456

    const size_t U_OFF  = QKV_BYTES + S_BYTES + P_BYTES + Y_BYTES;
    const size_t U_SIZE = PO_BYTES + PML_BYTES;
    const size_t W_OFF  = U_OFF + U_SIZE;
    const size_t KV_OFF = W_OFF + 2 * PLANE_WA + 2 * PLANE_WP;

    float* qkv  = (float*)ws;                               // fallback paths only
    float* Vtmp = (float*)ws;                               // kv: gemm1 V output (12.6MB)
    float* PART = (float*)ws;                               // kv: flash partials (29.2MB, after Vtmp dead)
    float* S    = (float*)(ws + QKV_BYTES);
    float* Psum = (float*)(ws + QKV_BYTES + S_BYTES);
    float* Yb   = (float*)(ws + QKV_BYTES + S_BYTES + P_BYTES);   // fp32 Y (fallback)
    unsigned short* Qhp = (unsigned short*)(ws + QKV_BYTES + S_BYTES + P_BYTES);  // kv: Q planes in Yb region
    unsigned short* Qlp = (unsigned short*)(ws + QKV_BYTES + S_BYTES + P_BYTES + PLANE_X);
    float* PO   = (float*)(ws + U_OFF);
    float* PML  = (float*)(ws + U_OFF + PO_BYTES);
    unsigned short* Xh  = (unsigned short*)(ws + U_OFF);    // X planes; reused as Y planes after gemm1
    unsigned short* Xl  = (unsigned short*)(ws + U_OFF + PLANE_X);
    unsigned short* Yhp = Xh;
    unsigned short* Ylp = Xl;
    unsigned short* WAh = (unsigned short*)(ws + W_OFF);
    unsigned short* WAl = (unsigned short*)(ws + W_OFF + PLANE_WA);
    unsigned short* WPh = (unsigned short*)(ws + W_OFF + 2 * PLANE_WA);
    unsigned short* WPl = (unsigned short*)(ws + W_OFF + 2 * PLANE_WA + PLANE_WP);
    unsigned short* Khp = (unsigned short*)(ws + KV_OFF);
    unsigned short* Klp = (unsigned short*)(ws + KV_OFF + PLANE_KV);
    unsigned short* VTh = (unsigned short*)(ws + KV_OFF + 2 * PLANE_KV);
    unsigned short* VTl = (unsigned short*)(ws + KV_OFF + 3 * PLANE_KV);

    const size_t NEED_SPLIT = U_OFF + U_SIZE;
    const size_t NEED_MFMA  = KV_OFF;
    const size_t NEED_KV    = KV_OFF + 4 * PLANE_KV;
    const int split = (ws_size >= NEED_SPLIT) ? 1 : 0;
    const int mfma  = (ws_size >= NEED_MFMA) ? 1 : 0;
    const int kv    = (ws_size >= NEED_KV && mfma) ? 1 : 0;

    const int M = NB * T;  // 4096

    if (kv) {
        // weights + x to planes
        cvt_split_T_kernel<<<dim3(C3 / 64, CE / 64), 256, 0, stream>>>(W_attn, WAh, WAl, CE, C3);
        cvt_split_T_kernel<<<dim3(CE / 64, CE / 64), 256, 0, stream>>>(W_proj, WPh, WPl, CE, CE);
        cvt_split_kernel<<<dim3((M * CE / 8) / 256), 256, 0, stream>>>(x, Xh, Xl);
        // gemm1 -> Q/K planes + Vtmp directly (no fp32 qkv)
        gemm_qkv_mfma_kernel<<<dim3(C3 / 128, M / 128), 256, 0, stream>>>(
            Xh, Xl, WAh, WAl, b_attn, Qhp, Qlp, Khp, Klp, Vtmp);
        cvt_kv_vt_kernel<<<dim3(T / 64, NB * NH), 256, 0, stream>>>(Vtmp, VTh, VTl);
        // s0 (+fused colsum -> Psum)
        s0_mfma_kernel<<<dim3(T / 64, T / 64, NB), 256, 0, stream>>>(Qhp, Qlp, Khp, Klp, S, Psum);
        // scan
        scanseg_kernel<<<dim3(T / 256, NB), 256, 0, stream>>>(Psum);
        ffscan_kernel<<<dim3(T / 256, 32, NB), 256, 0, stream>>>(S, Psum);
        // flash -> Y planes (+ PART) ; merge -> Y planes
        flash_mfma_kernel<<<dim3(NB * NH, 40), 256, 0, stream>>>(
            Qhp, Qlp, Khp, Klp, VTh, VTl, S, Yhp, Ylp, PART);
        merge128_kernel<<<dim3(NB * NH, 12), 256, 0, stream>>>(PART, Yhp, Ylp);
        // gemm2 from Y planes
        gemm_mfma_kernel<<<dim3(CE / 128, M / 128), 256, 0, stream>>>(
            Yhp, Ylp, WPh, WPl, b_proj, out, M, CE, CE);
        return;
    }

    // ---------------- fallback paths (small ws) ----------------
    if (mfma) {
        cvt_split_T_kernel<<<dim3(C3 / 64, CE / 64), 256, 0, stream>>>(W_attn, WAh, WAl, CE, C3);
        cvt_split_T_kernel<<<dim3(CE / 64, CE / 64), 256, 0, stream>>>(W_proj, WPh, WPl, CE, CE);
        cvt_split_kernel<<<dim3((M * CE / 8) / 256), 256, 0, stream>>>(x, Xh, Xl);
        gemm_mfma_kernel<<<dim3(C3 / 128, M / 128), 256, 0, stream>>>(Xh, Xl, WAh, WAl, b_attn, qkv, M, C3, CE);
    } else {
        gemm_bias_kernel<<<dim3(C3 / 64, M / 64), 256, 0, stream>>>(x, W_attn, b_attn, qkv, M, C3, CE);
    }
    s0_kernel<<<dim3(T / 64, T / 64, NB), 256, 0, stream>>>(qkv, S);
    colsum_kernel<<<dim3(T / 256, 32, NB), 256, 0, stream>>>(S, Psum);
    scanseg_kernel<<<dim3(T / 256, NB), 256, 0, stream>>>(Psum);
    ffscan_kernel<<<dim3(T / 256, 32, NB), 256, 0, stream>>>(S, Psum);
    if (split) {
        flash_kernel<<<dim3(NB * NH, 48), 256, 0, stream>>>(qkv, S, Yb, PO, PML, 1);
        merge_kernel<<<dim3(NB * NH * 16), 256, 0, stream>>>(PO, PML, Yb);
    } else {
        flash_kernel<<<dim3(NB * NH, 32), 256, 0, stream>>>(qkv, S, Yb, PO, PML, 0);
    }
    if (mfma) {
        cvt_split_kernel<<<dim3((M * CE / 8) / 256), 256, 0, stream>>>(Yb, Xh, Xl);
        gemm_mfma_kernel<<<dim3(CE / 128, M / 128), 256, 0, stream>>>(Xh, Xl, WPh, WPl, b_proj, out, M, CE, CE);
    } else {
        gemm_bias_kernel<<<dim3(CE / 64, M / 64), 256, 0, stream>>>(Yb, W_proj, b_proj, out, M, CE, CE);
    }
}

// Round 9
// 246.367 us; speedup vs baseline: 1.2036x; 1.0166x over previous
//
#include <hip/hip_runtime.h>
#include <math.h>

#define T 2048
#define NH 12
#define HD 64
#define C3 2304   // 3*768
#define CE 768
#define NB 2

typedef __attribute__((ext_vector_type(8))) short bf16x8;
typedef __attribute__((ext_vector_type(4))) float f32x4;
typedef __attribute__((ext_vector_type(16))) float f32x16;
typedef __attribute__((ext_vector_type(4))) unsigned u32x4;

// ---------------- async global->LDS, 16B per lane (wave-uniform LDS base) ----
__device__ __forceinline__ void gload16(const void* g, void* l) {
    __builtin_amdgcn_global_load_lds(
        (const __attribute__((address_space(1))) void*)g,
        (__attribute__((address_space(3))) void*)l, 16, 0, 0);
}

// ---------------- fp32 -> (hi,lo) bf16 split, RNE both halves ----------------
__device__ inline void bf16split(float a, unsigned short& h, unsigned short& l) {
    unsigned int u = __float_as_uint(a);
    unsigned int r = (u + 0x7FFFu + ((u >> 16) & 1u)) >> 16;
    h = (unsigned short)r;
    float hf = __uint_as_float(r << 16);
    float lo = a - hf;                      // exact (Sterbenz)
    unsigned int v = __float_as_uint(lo);
    l = (unsigned short)((v + 0x7FFFu + ((v >> 16) & 1u)) >> 16);
}

__device__ inline void packP(float a, float b, unsigned& wh, unsigned& wl) {
    unsigned short ha, la, hb, lb;
    bf16split(a, ha, la); bf16split(b, hb, lb);
    wh = (unsigned)ha | ((unsigned)hb << 16);
    wl = (unsigned)la | ((unsigned)lb << 16);
}

// A-side converter: fp32 [R][C] -> bf16 planes H,L (same layout). total/8 threads.
__global__ __launch_bounds__(256) void cvt_split_kernel(const float* __restrict__ A,
        unsigned short* __restrict__ H, unsigned short* __restrict__ L) {
    int i = blockIdx.x * 256 + threadIdx.x;         // 8-element group
    float4 a0 = *(reinterpret_cast<const float4*>(A) + (size_t)i * 2);
    float4 a1 = *(reinterpret_cast<const float4*>(A) + (size_t)i * 2 + 1);
    float f[8] = {a0.x, a0.y, a0.z, a0.w, a1.x, a1.y, a1.z, a1.w};
    unsigned short h[8], l[8];
    #pragma unroll
    for (int j = 0; j < 8; ++j) bf16split(f[j], h[j], l[j]);
    uint4 hv, lv;
    hv.x = (unsigned)h[0] | ((unsigned)h[1] << 16); hv.y = (unsigned)h[2] | ((unsigned)h[3] << 16);
    hv.z = (unsigned)h[4] | ((unsigned)h[5] << 16); hv.w = (unsigned)h[6] | ((unsigned)h[7] << 16);
    lv.x = (unsigned)l[0] | ((unsigned)l[1] << 16); lv.y = (unsigned)l[2] | ((unsigned)l[3] << 16);
    lv.z = (unsigned)l[4] | ((unsigned)l[5] << 16); lv.w = (unsigned)l[6] | ((unsigned)l[7] << 16);
    reinterpret_cast<uint4*>(H)[i] = hv;
    reinterpret_cast<uint4*>(L)[i] = lv;
}

// B-side converter with transpose: fp32 W[K][N] -> bf16 planes [N][K].
__global__ __launch_bounds__(256) void cvt_split_T_kernel(const float* __restrict__ W,
        unsigned short* __restrict__ H, unsigned short* __restrict__ L, int K, int N) {
    __shared__ float tile[64][65];
    const int n0 = blockIdx.x * 64, k0 = blockIdx.y * 64;
    const int t = threadIdx.x;
    {
        int r = t >> 2, c4 = (t & 3) * 16;
        #pragma unroll
        for (int u = 0; u < 4; ++u) {
            float4 w = *reinterpret_cast<const float4*>(&W[(size_t)(k0 + r) * N + n0 + c4 + u * 4]);
            tile[r][c4 + u * 4 + 0] = w.x; tile[r][c4 + u * 4 + 1] = w.y;
            tile[r][c4 + u * 4 + 2] = w.z; tile[r][c4 + u * 4 + 3] = w.w;
        }
    }
    __syncthreads();
    {
        int n = t >> 2, kc = (t & 3) * 16;
        unsigned short h[16], l[16];
        #pragma unroll
        for (int j = 0; j < 16; ++j) bf16split(tile[kc + j][n], h[j], l[j]);
        uint4 hv0, hv1, lv0, lv1;
        hv0.x = (unsigned)h[0] | ((unsigned)h[1] << 16);  hv0.y = (unsigned)h[2] | ((unsigned)h[3] << 16);
        hv0.z = (unsigned)h[4] | ((unsigned)h[5] << 16);  hv0.w = (unsigned)h[6] | ((unsigned)h[7] << 16);
        hv1.x = (unsigned)h[8] | ((unsigned)h[9] << 16);  hv1.y = (unsigned)h[10] | ((unsigned)h[11] << 16);
        hv1.z = (unsigned)h[12] | ((unsigned)h[13] << 16); hv1.w = (unsigned)h[14] | ((unsigned)h[15] << 16);
        lv0.x = (unsigned)l[0] | ((unsigned)l[1] << 16);  lv0.y = (unsigned)l[2] | ((unsigned)l[3] << 16);
        lv0.z = (unsigned)l[4] | ((unsigned)l[5] << 16);  lv0.w = (unsigned)l[6] | ((unsigned)l[7] << 16);
        lv1.x = (unsigned)l[8] | ((unsigned)l[9] << 16);  lv1.y = (unsigned)l[10] | ((unsigned)l[11] << 16);
        lv1.z = (unsigned)l[12] | ((unsigned)l[13] << 16); lv1.w = (unsigned)l[14] | ((unsigned)l[15] << 16);
        size_t o = (size_t)(n0 + n) * K + k0 + kc;
        reinterpret_cast<uint4*>(&H[o])[0] = hv0; reinterpret_cast<uint4*>(&H[o])[1] = hv1;
        reinterpret_cast<uint4*>(&L[o])[0] = lv0; reinterpret_cast<uint4*>(&L[o])[1] = lv1;
    }
}

// ---- V converter (transposed): Vtmp [bh][t][64] fp32 -> bf16 planes [bh][d][T] ----
__global__ __launch_bounds__(256) void cvt_kv_vt_kernel(const float* __restrict__ Vtmp,
        unsigned short* __restrict__ Vh, unsigned short* __restrict__ Vl) {
    __shared__ float tile[64][65];
    const int s0 = blockIdx.x * 64;
    const int bh = blockIdx.y;
    const int tid = threadIdx.x;
    {
        int r = tid >> 2, c0 = (tid & 3) * 16;
        const float* src = Vtmp + ((size_t)bh * T + s0 + r) * 64 + c0;
        #pragma unroll
        for (int u = 0; u < 4; ++u) {
            float4 w = *reinterpret_cast<const float4*>(src + u * 4);
            tile[r][c0 + u * 4 + 0] = w.x; tile[r][c0 + u * 4 + 1] = w.y;
            tile[r][c0 + u * 4 + 2] = w.z; tile[r][c0 + u * 4 + 3] = w.w;
        }
    }
    __syncthreads();
    {
        int d = tid >> 2, cs = (tid & 3) * 16;
        unsigned short hh[16], ll[16];
        #pragma unroll
        for (int j = 0; j < 16; ++j) bf16split(tile[cs + j][d], hh[j], ll[j]);
        uint4 hv0, hv1, lv0, lv1;
        hv0.x = (unsigned)hh[0] | ((unsigned)hh[1] << 16);  hv0.y = (unsigned)hh[2] | ((unsigned)hh[3] << 16);
        hv0.z = (unsigned)hh[4] | ((unsigned)hh[5] << 16);  hv0.w = (unsigned)hh[6] | ((unsigned)hh[7] << 16);
        hv1.x = (unsigned)hh[8] | ((unsigned)hh[9] << 16);  hv1.y = (unsigned)hh[10] | ((unsigned)hh[11] << 16);
        hv1.z = (unsigned)hh[12] | ((unsigned)hh[13] << 16); hv1.w = (unsigned)hh[14] | ((unsigned)hh[15] << 16);
        lv0.x = (unsigned)ll[0] | ((unsigned)ll[1] << 16);  lv0.y = (unsigned)ll[2] | ((unsigned)ll[3] << 16);
        lv0.z = (unsigned)ll[4] | ((unsigned)ll[5] << 16);  lv0.w = (unsigned)ll[6] | ((unsigned)ll[7] << 16);
        lv1.x = (unsigned)ll[8] | ((unsigned)ll[9] << 16);  lv1.y = (unsigned)ll[10] | ((unsigned)ll[11] << 16);
        lv1.z = (unsigned)ll[12] | ((unsigned)ll[13] << 16); lv1.w = (unsigned)ll[14] | ((unsigned)ll[15] << 16);
        size_t o = ((size_t)bh * 64 + d) * T + s0 + cs;
        reinterpret_cast<uint4*>(&Vh[o])[0] = hv0; reinterpret_cast<uint4*>(&Vh[o])[1] = hv1;
        reinterpret_cast<uint4*>(&Vl[o])[0] = lv0; reinterpret_cast<uint4*>(&Vl[o])[1] = lv1;
    }
}

// ---------------- split-bf16 MFMA GEMM (generic): C = A*B + bias ----------------
// global_load_lds staging (unpadded LD32 rows, XOR-chunk swizzle), XCD block
// swizzle, swapped-operand MFMA -> float4 epilogue stores.
#define LD32 32
__global__ __launch_bounds__(256) void gemm_mfma_kernel(
        const unsigned short* __restrict__ Ah, const unsigned short* __restrict__ Al,
        const unsigned short* __restrict__ Bh, const unsigned short* __restrict__ Bl,
        const float* __restrict__ bias, float* __restrict__ Cm,
        int M, int N, int K) {
    __shared__ unsigned short lA[2][128 * LD32];
    __shared__ unsigned short lB[2][128 * LD32];
    const int tid = threadIdx.x;
    // XCD-aware block swizzle (all launches have nwg % 8 == 0)
    const int nwg = gridDim.x * gridDim.y;
    int bid = blockIdx.y * gridDim.x + blockIdx.x;
    bid = (bid & 7) * (nwg >> 3) + (bid >> 3);
    const int bm = (bid / gridDim.x) * 128, bn = (bid % gridDim.x) * 128;
    const int lane = tid & 63, wid = tid >> 6;
    const int wr = wid >> 1, wc = wid & 1;
    f32x4 acc[4][4];
    #pragma unroll
    for (int i = 0; i < 4; ++i)
        #pragma unroll
        for (int j = 0; j < 4; ++j) acc[i][j] = (f32x4){0.f, 0.f, 0.f, 0.f};
    const int srow0 = wid * 32 + (lane >> 2);       // staging row (+h*16)
    const int scn   = lane & 3;                     // staging chunk
    const int arb = wr * 64 + (lane & 15);
    const int brb = wc * 64 + (lane & 15);
    const int kc  = lane >> 4;                      // fragment k-chunk
    for (int k0 = 0; k0 < K; k0 += 32) {
        __syncthreads();
        #pragma unroll
        for (int h = 0; h < 2; ++h) {
            int row = srow0 + h * 16;
            int cs = scn ^ ((row >> 1) & 3);        // pre-swizzled source chunk
            size_t ao = (size_t)(bm + row) * K + k0 + cs * 8;
            size_t bo = (size_t)(bn + row) * K + k0 + cs * 8;
            unsigned short* d0 = &lA[0][(wid * 32 + h * 16) * LD32];
            unsigned short* d1 = &lA[1][(wid * 32 + h * 16) * LD32];
            unsigned short* d2 = &lB[0][(wid * 32 + h * 16) * LD32];
            unsigned short* d3 = &lB[1][(wid * 32 + h * 16) * LD32];
            gload16(&Ah[ao], d0);
            gload16(&Al[ao], d1);
            gload16(&Bh[bo], d2);
            gload16(&Bl[bo], d3);
        }
        __syncthreads();
        bf16x8 fa[2][4], fb[2][4];
        #pragma unroll
        for (int fi = 0; fi < 4; ++fi) {
            int ra = arb + fi * 16, rb = brb + fi * 16;
            int ca = (kc ^ ((ra >> 1) & 3)) * 8;    // swizzled read chunk
            int cb = (kc ^ ((rb >> 1) & 3)) * 8;
            fa[0][fi] = *reinterpret_cast<const bf16x8*>(&lA[0][ra * LD32 + ca]);
            fa[1][fi] = *reinterpret_cast<const bf16x8*>(&lA[1][ra * LD32 + ca]);
            fb[0][fi] = *reinterpret_cast<const bf16x8*>(&lB[0][rb * LD32 + cb]);
            fb[1][fi] = *reinterpret_cast<const bf16x8*>(&lB[1][rb * LD32 + cb]);
        }
        #pragma unroll
        for (int fi = 0; fi < 4; ++fi)
            #pragma unroll
            for (int fj = 0; fj < 4; ++fj) {
                acc[fi][fj] = __builtin_amdgcn_mfma_f32_16x16x32_bf16(fb[0][fj], fa[0][fi], acc[fi][fj], 0, 0, 0);
                acc[fi][fj] = __builtin_amdgcn_mfma_f32_16x16x32_bf16(fb[0][fj], fa[1][fi], acc[fi][fj], 0, 0, 0);
                acc[fi][fj] = __builtin_amdgcn_mfma_f32_16x16x32_bf16(fb[1][fj], fa[0][fi], acc[fi][fj], 0, 0, 0);
            }
    }
    const int mloc = lane & 15, ng = (lane >> 4) * 4;
    #pragma unroll
    for (int fi = 0; fi < 4; ++fi) {
        int row = bm + wr * 64 + fi * 16 + mloc;
        #pragma unroll
        for (int fj = 0; fj < 4; ++fj) {
            int n0 = bn + wc * 64 + fj * 16 + ng;
            float4 bv = *reinterpret_cast<const float4*>(&bias[n0]);
            float4 o4 = {acc[fi][fj][0] + bv.x, acc[fi][fj][1] + bv.y,
                         acc[fi][fj][2] + bv.z, acc[fi][fj][3] + bv.w};
            *reinterpret_cast<float4*>(&Cm[(size_t)row * N + n0]) = o4;
        }
    }
}

// ---------------- gemm1 specialized: qkv = x@W_attn + b, writing planes directly ----
__global__ __launch_bounds__(256) void gemm_qkv_mfma_kernel(
        const unsigned short* __restrict__ Ah, const unsigned short* __restrict__ Al,
        const unsigned short* __restrict__ Bh, const unsigned short* __restrict__ Bl,
        const float* __restrict__ bias,
        unsigned short* __restrict__ Qh, unsigned short* __restrict__ Ql,
        unsigned short* __restrict__ Kh, unsigned short* __restrict__ Kl,
        float* __restrict__ Vtmp) {
    const int K = CE;
    __shared__ unsigned short lA[2][128 * LD32];
    __shared__ unsigned short lB[2][128 * LD32];
    const int tid = threadIdx.x;
    const int nwg = gridDim.x * gridDim.y;
    int bid = blockIdx.y * gridDim.x + blockIdx.x;
    bid = (bid & 7) * (nwg >> 3) + (bid >> 3);
    const int bm = (bid / gridDim.x) * 128, bn = (bid % gridDim.x) * 128;
    const int lane = tid & 63, wid = tid >> 6;
    const int wr = wid >> 1, wc = wid & 1;
    f32x4 acc[4][4];
    #pragma unroll
    for (int i = 0; i < 4; ++i)
        #pragma unroll
        for (int j = 0; j < 4; ++j) acc[i][j] = (f32x4){0.f, 0.f, 0.f, 0.f};
    const int srow0 = wid * 32 + (lane >> 2);
    const int scn   = lane & 3;
    const int arb = wr * 64 + (lane & 15);
    const int brb = wc * 64 + (lane & 15);
    const int kc  = lane >> 4;
    for (int k0 = 0; k0 < K; k0 += 32) {
        __syncthreads();
        #pragma unroll
        for (int h = 0; h < 2; ++h) {
            int row = srow0 + h * 16;
            int cs = scn ^ ((row >> 1) & 3);
            size_t ao = (size_t)(bm + row) * K + k0 + cs * 8;
            size_t bo = (size_t)(bn + row) * K + k0 + cs * 8;
            unsigned short* d0 = &lA[0][(wid * 32 + h * 16) * LD32];
            unsigned short* d1 = &lA[1][(wid * 32 + h * 16) * LD32];
            unsigned short* d2 = &lB[0][(wid * 32 + h * 16) * LD32];
            unsigned short* d3 = &lB[1][(wid * 32 + h * 16) * LD32];
            gload16(&Ah[ao], d0);
            gload16(&Al[ao], d1);
            gload16(&Bh[bo], d2);
            gload16(&Bl[bo], d3);
        }
        __syncthreads();
        bf16x8 fa[2][4], fb[2][4];
        #pragma unroll
        for (int fi = 0; fi < 4; ++fi) {
            int ra = arb + fi * 16, rb = brb + fi * 16;
            int ca = (kc ^ ((ra >> 1) & 3)) * 8;
            int cb = (kc ^ ((rb >> 1) & 3)) * 8;
            fa[0][fi] = *reinterpret_cast<const bf16x8*>(&lA[0][ra * LD32 + ca]);
            fa[1][fi] = *reinterpret_cast<const bf16x8*>(&lA[1][ra * LD32 + ca]);
            fb[0][fi] = *reinterpret_cast<const bf16x8*>(&lB[0][rb * LD32 + cb]);
            fb[1][fi] = *reinterpret_cast<const bf16x8*>(&lB[1][rb * LD32 + cb]);
        }
        #pragma unroll
        for (int fi = 0; fi < 4; ++fi)
            #pragma unroll
            for (int fj = 0; fj < 4; ++fj) {
                acc[fi][fj] = __builtin_amdgcn_mfma_f32_16x16x32_bf16(fb[0][fj], fa[0][fi], acc[fi][fj], 0, 0, 0);
                acc[fi][fj] = __builtin_amdgcn_mfma_f32_16x16x32_bf16(fb[0][fj], fa[1][fi], acc[fi][fj], 0, 0, 0);
                acc[fi][fj] = __builtin_amdgcn_mfma_f32_16x16x32_bf16(fb[1][fj], fa[0][fi], acc[fi][fj], 0, 0, 0);
            }
    }
    // epilogue: wave's 64 cols = one head of one region; lane holds one t,
    // p walks d -> vectorized plane stores
    const int colbase = bn + wc * 64;
    const int region = colbase / 768;           // 0=Q, 1=K, 2=V
    const int h = (colbase % 768) >> 6;
    const int mloc = lane & 15, ng = (lane >> 4) * 4;
    #pragma unroll
    for (int fi = 0; fi < 4; ++fi) {
        int tg = bm + wr * 64 + fi * 16 + mloc;
        int bb = tg >> 11, t = tg & (T - 1);
        #pragma unroll
        for (int fj = 0; fj < 4; ++fj) {
            int dbase = fj * 16 + ng;
            float4 bv = *reinterpret_cast<const float4*>(&bias[colbase + dbase]);
            float v0 = acc[fi][fj][0] + bv.x, v1 = acc[fi][fj][1] + bv.y;
            float v2 = acc[fi][fj][2] + bv.z, v3 = acc[fi][fj][3] + bv.w;
            size_t o = ((size_t)(bb * NH + h) * T + t) * 64 + dbase;
            if (region == 2) {
                float4 o4 = {v0, v1, v2, v3};
                *reinterpret_cast<float4*>(&Vtmp[o]) = o4;
            } else {
                unsigned short hh[4], ll[4];
                bf16split(v0, hh[0], ll[0]); bf16split(v1, hh[1], ll[1]);
                bf16split(v2, hh[2], ll[2]); bf16split(v3, hh[3], ll[3]);
                uint2 ph = {(unsigned)hh[0] | ((unsigned)hh[1] << 16),
                            (unsigned)hh[2] | ((unsigned)hh[3] << 16)};
                uint2 pl = {(unsigned)ll[0] | ((unsigned)ll[1] << 16),
                            (unsigned)ll[2] | ((unsigned)ll[3] << 16)};
                if (region == 0) {
                    *reinterpret_cast<uint2*>(&Qh[o]) = ph;
                    *reinterpret_cast<uint2*>(&Ql[o]) = pl;
                } else {
                    *reinterpret_cast<uint2*>(&Kh[o]) = ph;
                    *reinterpret_cast<uint2*>(&Kl[o]) = pl;
                }
            }
        }
    }
}

// ---------------- fp32 GEMM fallback (small ws) ----------------
__global__ __launch_bounds__(256) void gemm_bias_kernel(
        const float* __restrict__ A, const float* __restrict__ B,
        const float* __restrict__ bias, float* __restrict__ Cm,
        int M, int N, int K) {
    __shared__ float As[16][64];
    __shared__ float Bs[16][68];
    const int tid = threadIdx.x;
    const int ty = tid >> 4, tx = tid & 15;
    const int bm = blockIdx.y * 64, bn = blockIdx.x * 64;
    float acc[4][4] = {};
    for (int k0 = 0; k0 < K; k0 += 16) {
        {
            int r = tid >> 2;
            int kk = (tid & 3) * 4;
            float4 a = *reinterpret_cast<const float4*>(&A[(size_t)(bm + r) * K + k0 + kk]);
            As[kk + 0][r] = a.x; As[kk + 1][r] = a.y; As[kk + 2][r] = a.z; As[kk + 3][r] = a.w;
        }
        {
            int kk = tid >> 4;
            int c = (tid & 15) * 4;
            *reinterpret_cast<float4*>(&Bs[kk][c]) =
                *reinterpret_cast<const float4*>(&B[(size_t)(k0 + kk) * N + bn + c]);
        }
        __syncthreads();
        #pragma unroll
        for (int kk = 0; kk < 16; ++kk) {
            float4 a4 = *reinterpret_cast<const float4*>(&As[kk][ty * 4]);
            float4 b4 = *reinterpret_cast<const float4*>(&Bs[kk][tx * 4]);
            float av[4] = {a4.x, a4.y, a4.z, a4.w};
            float bv[4] = {b4.x, b4.y, b4.z, b4.w};
            #pragma unroll
            for (int i = 0; i < 4; ++i)
                #pragma unroll
                for (int j = 0; j < 4; ++j)
                    acc[i][j] = fmaf(av[i], bv[j], acc[i][j]);
        }
        __syncthreads();
    }
    #pragma unroll
    for (int i = 0; i < 4; ++i) {
        int row = bm + ty * 4 + i;
        #pragma unroll
        for (int j = 0; j < 4; ++j) {
            int col = bn + tx * 4 + j;
            Cm[(size_t)row * N + col] = acc[i][j] + bias[col];
        }
    }
}

#define FST 72   // LDS row stride (bf16), 144 B = 16B-aligned rows

// ---------------- s0 via MFMA + fused column sums: S, Psum ----------------
__global__ __launch_bounds__(256) void s0_mfma_kernel(
        const unsigned short* __restrict__ Qh, const unsigned short* __restrict__ Ql,
        const unsigned short* __restrict__ Kh, const unsigned short* __restrict__ Kl,
        float* __restrict__ S, float* __restrict__ Psum) {
    const int kb = blockIdx.x * 64, qb = blockIdx.y * 64, b = blockIdx.z;
    const int tid = threadIdx.x;
    float* Sb = S + (size_t)b * T * T;
    if (kb > qb) {  // entire tile masked -> zero S tile + zero Psum entries
        const int ty = tid >> 4, tx = tid & 15;
        #pragma unroll
        for (int i = 0; i < 4; ++i) {
            float4 z = {0.f, 0.f, 0.f, 0.f};
            *reinterpret_cast<float4*>(&Sb[(size_t)(qb + ty * 4 + i) * T + kb + tx * 4]) = z;
        }
        if (tid < 64) Psum[((size_t)(b * 32 + (qb >> 6)) * T) + kb + tid] = 0.f;
        return;
    }
    const int lane = tid & 63, w = tid >> 6;
    const int fr = lane & 15, fg = lane >> 4;
    __shared__ unsigned short Ks[2][64 * FST];
    __shared__ float csum[4][64];
    const int hb0 = b * NH;   // head 0
    {
        const int sr = tid >> 2, sc0 = (tid & 3) * 16;
        const unsigned short* kh = Kh + ((size_t)hb0 * T + kb + sr) * 64 + sc0;
        const unsigned short* kl = Kl + ((size_t)hb0 * T + kb + sr) * 64 + sc0;
        uint4 a0 = reinterpret_cast<const uint4*>(kh)[0];
        uint4 a1 = reinterpret_cast<const uint4*>(kh)[1];
        uint4 b0 = reinterpret_cast<const uint4*>(kl)[0];
        uint4 b1 = reinterpret_cast<const uint4*>(kl)[1];
        *reinterpret_cast<uint4*>(&Ks[0][sr * FST + sc0 + 0]) = a0;
        *reinterpret_cast<uint4*>(&Ks[0][sr * FST + sc0 + 8]) = a1;
        *reinterpret_cast<uint4*>(&Ks[1][sr * FST + sc0 + 0]) = b0;
        *reinterpret_cast<uint4*>(&Ks[1][sr * FST + sc0 + 8]) = b1;
    }
    bf16x8 qh[2], ql[2];
    #pragma unroll
    for (int ks = 0; ks < 2; ++ks) {
        size_t qo = ((size_t)hb0 * T + qb + w * 16 + fr) * 64 + ks * 32 + fg * 8;
        qh[ks] = *reinterpret_cast<const bf16x8*>(&Qh[qo]);
        ql[ks] = *reinterpret_cast<const bf16x8*>(&Ql[qo]);
    }
    __syncthreads();
    f32x4 qk[4];
    #pragma unroll
    for (int fj = 0; fj < 4; ++fj) qk[fj] = (f32x4){0.f, 0.f, 0.f, 0.f};
    #pragma unroll
    for (int ks = 0; ks < 2; ++ks) {
        bf16x8 kbh[4], kbl[4];
        #pragma unroll
        for (int fj = 0; fj < 4; ++fj) {
            kbh[fj] = *reinterpret_cast<const bf16x8*>(&Ks[0][(fj * 16 + fr) * FST + ks * 32 + fg * 8]);
            kbl[fj] = *reinterpret_cast<const bf16x8*>(&Ks[1][(fj * 16 + fr) * FST + ks * 32 + fg * 8]);
        }
        #pragma unroll
        for (int fj = 0; fj < 4; ++fj) {
            qk[fj] = __builtin_amdgcn_mfma_f32_16x16x32_bf16(qh[ks], kbh[fj], qk[fj], 0, 0, 0);
            qk[fj] = __builtin_amdgcn_mfma_f32_16x16x32_bf16(qh[ks], kbl[fj], qk[fj], 0, 0, 0);
            qk[fj] = __builtin_amdgcn_mfma_f32_16x16x32_bf16(ql[ks], kbh[fj], qk[fj], 0, 0, 0);
        }
    }
    float colsum[4] = {0.f, 0.f, 0.f, 0.f};
    #pragma unroll
    for (int p = 0; p < 4; ++p) {
        int t = qb + w * 16 + fg * 4 + p;
        #pragma unroll
        for (int fj = 0; fj < 4; ++fj) {
            int s = kb + fj * 16 + fr;
            float v = qk[fj][p] * 0.125f;
            float o = (s >= 1 && s < t) ? fmaxf(v, 0.0f) : 0.0f;
            Sb[(size_t)t * T + s] = o;
            colsum[fj] += o;
        }
    }
    // fused colsum: reduce over fg (xor16, xor32) then across waves via LDS
    #pragma unroll
    for (int fj = 0; fj < 4; ++fj) {
        colsum[fj] += __shfl_xor(colsum[fj], 16);
        colsum[fj] += __shfl_xor(colsum[fj], 32);
    }
    if (lane < 16) {
        #pragma unroll
        for (int fj = 0; fj < 4; ++fj) csum[w][fj * 16 + lane] = colsum[fj];
    }
    __syncthreads();
    if (tid < 64) {
        float v = csum[0][tid] + csum[1][tid] + csum[2][tid] + csum[3][tid];
        Psum[((size_t)(b * 32 + (qb >> 6)) * T) + kb + tid] = v;
    }
}

// ---------------- fp32 s0 fallback ----------------
__global__ __launch_bounds__(256) void s0_kernel(const float* __restrict__ qkv,
                                                 float* __restrict__ S) {
    const int kb = blockIdx.x * 64, qb = blockIdx.y * 64, b = blockIdx.z;
    const int tid = threadIdx.x, ty = tid >> 4, tx = tid & 15;
    float* Sb = S + (size_t)b * T * T;
    if (kb > qb) {
        #pragma unroll
        for (int i = 0; i < 4; ++i) {
            int row = qb + ty * 4 + i;
            float4 z = {0.f, 0.f, 0.f, 0.f};
            *reinterpret_cast<float4*>(&Sb[(size_t)row * T + kb + tx * 4]) = z;
        }
        return;
    }
    __shared__ float Qt[64][68];
    __shared__ float Kt[64][68];
    {
        int r = tid >> 2;
        int c0 = (tid & 3) * 16;
        const float* qrow = qkv + (size_t)(b * T + qb + r) * C3 + 0;
        const float* krow = qkv + (size_t)(b * T + kb + r) * C3 + 768;
        #pragma unroll
        for (int u = 0; u < 4; ++u) {
            float4 q4 = *reinterpret_cast<const float4*>(&qrow[c0 + u * 4]);
            float4 k4 = *reinterpret_cast<const float4*>(&krow[c0 + u * 4]);
            int d = c0 + u * 4;
            Qt[d + 0][r] = q4.x; Qt[d + 1][r] = q4.y; Qt[d + 2][r] = q4.z; Qt[d + 3][r] = q4.w;
            Kt[d + 0][r] = k4.x; Kt[d + 1][r] = k4.y; Kt[d + 2][r] = k4.z; Kt[d + 3][r] = k4.w;
        }
    }
    __syncthreads();
    float acc[4][4] = {};
    #pragma unroll
    for (int d = 0; d < 64; ++d) {
        float4 qv = *reinterpret_cast<const float4*>(&Qt[d][ty * 4]);
        float4 kv = *reinterpret_cast<const float4*>(&Kt[d][tx * 4]);
        float qa[4] = {qv.x, qv.y, qv.z, qv.w};
        float ka[4] = {kv.x, kv.y, kv.z, kv.w};
        #pragma unroll
        for (int i = 0; i < 4; ++i)
            #pragma unroll
            for (int j = 0; j < 4; ++j)
                acc[i][j] = fmaf(qa[i], ka[j], acc[i][j]);
    }
    #pragma unroll
    for (int i = 0; i < 4; ++i) {
        int t = qb + ty * 4 + i;
        float o[4];
        #pragma unroll
        for (int j = 0; j < 4; ++j) {
            int s = kb + tx * 4 + j;
            float v = acc[i][j] * 0.125f;
            o[j] = (s >= 1 && s < t) ? fmaxf(v, 0.0f) : 0.0f;
        }
        float4 o4 = {o[0], o[1], o[2], o[3]};
        *reinterpret_cast<float4*>(&Sb[(size_t)t * T + kb + tx * 4]) = o4;
    }
}

// ---------------- segmented scan: FF = cumsum_t(S) ----------------
__global__ __launch_bounds__(256) void colsum_kernel(const float* __restrict__ S,
                                                     float* __restrict__ Psum) {
    int s = blockIdx.x * 256 + threadIdx.x;
    int j = blockIdx.y, b = blockIdx.z;
    const float* Sb = S + (size_t)b * T * T;
    float sum = 0.f;
    for (int r = 0; r < 64; ++r) sum += Sb[(size_t)(j * 64 + r) * T + s];
    Psum[((size_t)b * 32 + j) * T + s] = sum;
}

// prefetch all 32 loads (independent), then scan in registers: 32x latency -> 1x
__global__ __launch_bounds__(256) void scanseg_kernel(float* __restrict__ Psum) {
    int s = blockIdx.x * 256 + threadIdx.x;
    int b = blockIdx.y;
    float v[32];
    #pragma unroll
    for (int j = 0; j < 32; ++j)
        v[j] = Psum[((size_t)(b * 32 + j)) * T + s];
    float run = 0.f;
    #pragma unroll
    for (int j = 0; j < 32; ++j) {
        Psum[((size_t)(b * 32 + j)) * T + s] = run;
        run += v[j];
    }
}

__global__ __launch_bounds__(256) void ffscan_kernel(float* __restrict__ S,
                                                     const float* __restrict__ Psum) {
    int s = blockIdx.x * 256 + threadIdx.x;
    int j = blockIdx.y, b = blockIdx.z;
    float run = Psum[((size_t)b * 32 + j) * T + s];
    float* Sb = S + (size_t)b * T * T;
    for (int r = 0; r < 64; ++r) {
        size_t idx = (size_t)(j * 64 + r) * T + s;
        run += Sb[idx];
        Sb[idx] = run;
    }
}

// ---------------- task table: 40 tasks/(b,h), size-descending ----------------
__device__ const int FTQ[40] = {15,15,15,15,14,14,14,13,13,13,12,12,12,11,11,11,10,10,9,9,8,8,7,7,6,5,4,3,14,10,6,2,13,9,5,1,12,8,4,0};
__device__ const int FK0[40] = {0,8,16,24,0,8,16,0,8,16,0,8,16,0,8,16,0,8,0,8,0,8,0,8,0,0,0,0,24,16,8,0,24,16,8,0,24,16,8,0};
__device__ const int FK1[40] = {8,16,24,32,8,16,24,8,16,24,8,16,24,8,16,24,8,16,8,16,8,16,8,16,8,8,8,8,30,22,14,6,28,20,12,4,26,18,10,2};
__device__ const int FCB[12] = {0,2,4,6,8,11,14,17,20,24,28,32};   // chunk base per Q-4

// ---------------- 32x32 swapped-operand MFMA flash attention ----------------
__global__ __launch_bounds__(256) void flash_mfma_kernel(
        const unsigned short* __restrict__ Qh, const unsigned short* __restrict__ Ql,
        const unsigned short* __restrict__ Kh, const unsigned short* __restrict__ Kl,
        const unsigned short* __restrict__ Vth, const unsigned short* __restrict__ Vtl,
        const float* __restrict__ FF,
        unsigned short* __restrict__ Yh, unsigned short* __restrict__ Yl,
        float* __restrict__ PART) {
    const int hb = blockIdx.x;
    const int h = hb % NH, b = hb / NH;
    const int u = blockIdx.y;
    const int tq = FTQ[u], kt0 = FK0[u], kt1 = FK1[u];
    const int qb = tq * 128;
    const int tid = threadIdx.x;
    const int lane = tid & 63, w = tid >> 6;
    const int q31 = lane & 31, hi = lane >> 5;
    const int trow = qb + w * 32 + q31;      // this lane's q-row (absolute t)
    __shared__ unsigned short KS[2][64 * FST];   // K [s][d] hi/lo
    __shared__ unsigned short VS[2][64 * FST];   // V^T [d][s] hi/lo

    bf16x8 qfh[4], qfl[4];
    #pragma unroll
    for (int dblk = 0; dblk < 4; ++dblk) {
        size_t qo = ((size_t)hb * T + trow) * 64 + dblk * 16 + hi * 8;
        qfh[dblk] = *reinterpret_cast<const bf16x8*>(&Qh[qo]);
        qfl[dblk] = *reinterpret_cast<const bf16x8*>(&Ql[qo]);
    }

    f32x16 oacc0 = (f32x16)(0.f), oacc1 = (f32x16)(0.f);
    float m = -1e30f, l = 0.f;
    const float* FFb = FF + (size_t)b * T * T;
    const int sr = tid >> 2, sc0 = (tid & 3) * 16;

    for (int kt = kt0; kt < kt1; ++kt) {
        const int kb = kt * 64;
        __syncthreads();
        {
            const unsigned short* ksrc = Kh + ((size_t)hb * T + kb + sr) * 64 + sc0;
            const unsigned short* ksrl = Kl + ((size_t)hb * T + kb + sr) * 64 + sc0;
            const unsigned short* vsrc = Vth + ((size_t)hb * 64 + sr) * T + kb + sc0;
            const unsigned short* vsrl = Vtl + ((size_t)hb * 64 + sr) * T + kb + sc0;
            uint4 k0v = reinterpret_cast<const uint4*>(ksrc)[0];
            uint4 k1v = reinterpret_cast<const uint4*>(ksrc)[1];
            uint4 k2v = reinterpret_cast<const uint4*>(ksrl)[0];
            uint4 k3v = reinterpret_cast<const uint4*>(ksrl)[1];
            uint4 v0v = reinterpret_cast<const uint4*>(vsrc)[0];
            uint4 v1v = reinterpret_cast<const uint4*>(vsrc)[1];
            uint4 v2v = reinterpret_cast<const uint4*>(vsrl)[0];
            uint4 v3v = reinterpret_cast<const uint4*>(vsrl)[1];
            *reinterpret_cast<uint4*>(&KS[0][sr * FST + sc0 + 0]) = k0v;
            *reinterpret_cast<uint4*>(&KS[0][sr * FST + sc0 + 8]) = k1v;
            *reinterpret_cast<uint4*>(&KS[1][sr * FST + sc0 + 0]) = k2v;
            *reinterpret_cast<uint4*>(&KS[1][sr * FST + sc0 + 8]) = k3v;
            *reinterpret_cast<uint4*>(&VS[0][sr * FST + sc0 + 0]) = v0v;
            *reinterpret_cast<uint4*>(&VS[0][sr * FST + sc0 + 8]) = v1v;
            *reinterpret_cast<uint4*>(&VS[1][sr * FST + sc0 + 0]) = v2v;
            *reinterpret_cast<uint4*>(&VS[1][sr * FST + sc0 + 8]) = v3v;
        }
        __syncthreads();
        f32x16 acc[2];
        acc[0] = (f32x16)(0.f); acc[1] = (f32x16)(0.f);
        #pragma unroll
        for (int sb = 0; sb < 2; ++sb) {
            #pragma unroll
            for (int dblk = 0; dblk < 4; ++dblk) {
                bf16x8 kfh = *reinterpret_cast<const bf16x8*>(&KS[0][(sb * 32 + q31) * FST + dblk * 16 + hi * 8]);
                bf16x8 kfl = *reinterpret_cast<const bf16x8*>(&KS[1][(sb * 32 + q31) * FST + dblk * 16 + hi * 8]);
                acc[sb] = __builtin_amdgcn_mfma_f32_32x32x16_bf16(kfh, qfh[dblk], acc[sb], 0, 0, 0);
                acc[sb] = __builtin_amdgcn_mfma_f32_32x32x16_bf16(kfh, qfl[dblk], acc[sb], 0, 0, 0);
                acc[sb] = __builtin_amdgcn_mfma_f32_32x32x16_bf16(kfl, qfh[dblk], acc[sb], 0, 0, 0);
            }
        }
        float pv[2][16];
        #pragma unroll
        for (int sb = 0; sb < 2; ++sb) {
            #pragma unroll
            for (int g = 0; g < 4; ++g) {
                float4 f4 = *reinterpret_cast<const float4*>(
                    &FFb[(size_t)trow * T + kb + sb * 32 + g * 8 + hi * 4]);
                float fv[4] = {f4.x, f4.y, f4.z, f4.w};
                #pragma unroll
                for (int a = 0; a < 4; ++a) {
                    int r = g * 4 + a;
                    int s = kb + sb * 32 + a + g * 8 + hi * 4;
                    float val = acc[sb][r] * 0.125f - fv[a];
                    pv[sb][r] = (s <= trow) ? val : -1e30f;
                }
            }
        }
        float tm = pv[0][0];
        #pragma unroll
        for (int sb = 0; sb < 2; ++sb)
            #pragma unroll
            for (int r = 0; r < 16; ++r) tm = fmaxf(tm, pv[sb][r]);
        tm = fmaxf(tm, __shfl_xor(tm, 32));
        float mn = fmaxf(m, tm);
        float scale = __expf(m - mn);
        float rs = 0.f;
        #pragma unroll
        for (int sb = 0; sb < 2; ++sb)
            #pragma unroll
            for (int r = 0; r < 16; ++r) {
                float pe = __expf(pv[sb][r] - mn);
                pv[sb][r] = pe; rs += pe;
            }
        rs += __shfl_xor(rs, 32);
        l = l * scale + rs;
        m = mn;
        oacc0 *= scale; oacc1 *= scale;
        unsigned wh[2][4][2], wl[2][4][2];
        #pragma unroll
        for (int sb = 0; sb < 2; ++sb)
            #pragma unroll
            for (int bq = 0; bq < 4; ++bq)
                #pragma unroll
                for (int h2 = 0; h2 < 2; ++h2)
                    packP(pv[sb][4 * bq + 2 * h2], pv[sb][4 * bq + 2 * h2 + 1],
                          wh[sb][bq][h2], wl[sb][bq][h2]);
        #pragma unroll
        for (int kk = 0; kk < 4; ++kk) {
            const int sb = kk >> 1;
            const int b0 = 2 * (kk & 1), b1 = b0 + 1;
            unsigned sh_b1_0 = (unsigned)__shfl_xor((int)wh[sb][b1][0], 32);
            unsigned sh_b1_1 = (unsigned)__shfl_xor((int)wh[sb][b1][1], 32);
            unsigned sh_b0_0 = (unsigned)__shfl_xor((int)wh[sb][b0][0], 32);
            unsigned sh_b0_1 = (unsigned)__shfl_xor((int)wh[sb][b0][1], 32);
            unsigned sl_b1_0 = (unsigned)__shfl_xor((int)wl[sb][b1][0], 32);
            unsigned sl_b1_1 = (unsigned)__shfl_xor((int)wl[sb][b1][1], 32);
            unsigned sl_b0_0 = (unsigned)__shfl_xor((int)wl[sb][b0][0], 32);
            unsigned sl_b0_1 = (unsigned)__shfl_xor((int)wl[sb][b0][1], 32);
            u32x4 th, tl;
            th[0] = hi ? sh_b1_0 : wh[sb][b0][0];
            th[1] = hi ? sh_b1_1 : wh[sb][b0][1];
            th[2] = hi ? wh[sb][b1][0] : sh_b0_0;
            th[3] = hi ? wh[sb][b1][1] : sh_b0_1;
            tl[0] = hi ? sl_b1_0 : wl[sb][b0][0];
            tl[1] = hi ? sl_b1_1 : wl[sb][b0][1];
            tl[2] = hi ? wl[sb][b1][0] : sl_b0_0;
            tl[3] = hi ? wl[sb][b1][1] : sl_b0_1;
            bf16x8 pbh = __builtin_bit_cast(bf16x8, th);
            bf16x8 pbl = __builtin_bit_cast(bf16x8, tl);
            {   // db = 0
                bf16x8 vfh = *reinterpret_cast<const bf16x8*>(&VS[0][(q31) * FST + kk * 16 + hi * 8]);
                bf16x8 vfl = *reinterpret_cast<const bf16x8*>(&VS[1][(q31) * FST + kk * 16 + hi * 8]);
                oacc0 = __builtin_amdgcn_mfma_f32_32x32x16_bf16(vfh, pbh, oacc0, 0, 0, 0);
                oacc0 = __builtin_amdgcn_mfma_f32_32x32x16_bf16(vfh, pbl, oacc0, 0, 0, 0);
                oacc0 = __builtin_amdgcn_mfma_f32_32x32x16_bf16(vfl, pbh, oacc0, 0, 0, 0);
            }
            {   // db = 1
                bf16x8 vfh = *reinterpret_cast<const bf16x8*>(&VS[0][(32 + q31) * FST + kk * 16 + hi * 8]);
                bf16x8 vfl = *reinterpret_cast<const bf16x8*>(&VS[1][(32 + q31) * FST + kk * 16 + hi * 8]);
                oacc1 = __builtin_amdgcn_mfma_f32_32x32x16_bf16(vfh, pbh, oacc1, 0, 0, 0);
                oacc1 = __builtin_amdgcn_mfma_f32_32x32x16_bf16(vfh, pbl, oacc1, 0, 0, 0);
                oacc1 = __builtin_amdgcn_mfma_f32_32x32x16_bf16(vfl, pbh, oacc1, 0, 0, 0);
            }
        }
    }
    if (tq < 4) {   // direct: normalized bf16-plane write
        float inv = 1.f / l;
        size_t ybase = ((size_t)(b * T + trow)) * CE + h * 64;
        #pragma unroll
        for (int g = 0; g < 4; ++g) {
            unsigned short h0[4], l0[4], h1[4], l1[4];
            #pragma unroll
            for (int i = 0; i < 4; ++i) {
                bf16split(oacc0[4 * g + i] * inv, h0[i], l0[i]);
                bf16split(oacc1[4 * g + i] * inv, h1[i], l1[i]);
            }
            uint2 ph0 = {(unsigned)h0[0] | ((unsigned)h0[1] << 16), (unsigned)h0[2] | ((unsigned)h0[3] << 16)};
            uint2 pl0 = {(unsigned)l0[0] | ((unsigned)l0[1] << 16), (unsigned)l0[2] | ((unsigned)l0[3] << 16)};
            uint2 ph1 = {(unsigned)h1[0] | ((unsigned)h1[1] << 16), (unsigned)h1[2] | ((unsigned)h1[3] << 16)};
            uint2 pl1 = {(unsigned)l1[0] | ((unsigned)l1[1] << 16), (unsigned)l1[2] | ((unsigned)l1[3] << 16)};
            *reinterpret_cast<uint2*>(&Yh[ybase + g * 8 + hi * 4]) = ph0;
            *reinterpret_cast<uint2*>(&Yl[ybase + g * 8 + hi * 4]) = pl0;
            *reinterpret_cast<uint2*>(&Yh[ybase + 32 + g * 8 + hi * 4]) = ph1;
            *reinterpret_cast<uint2*>(&Yl[ybase + 32 + g * 8 + hi * 4]) = pl1;
        }
    } else {        // partial chunk: unnormalized O + (m,l)
        const int ci = FCB[tq - 4] + (kt0 >> 3);
        float* Ob = PART + (size_t)(hb * 36 + ci) * 8448;
        const int rr = w * 32 + q31;
        #pragma unroll
        for (int g = 0; g < 4; ++g) {
            float4 o0 = {oacc0[4 * g + 0], oacc0[4 * g + 1], oacc0[4 * g + 2], oacc0[4 * g + 3]};
            float4 o1 = {oacc1[4 * g + 0], oacc1[4 * g + 1], oacc1[4 * g + 2], oacc1[4 * g + 3]};
            *reinterpret_cast<float4*>(&Ob[rr * 64 + g * 8 + hi * 4]) = o0;
            *reinterpret_cast<float4*>(&Ob[rr * 64 + 32 + g * 8 + hi * 4]) = o1;
        }
        if (hi == 0) { Ob[8192 + rr] = m; Ob[8192 + 128 + rr] = l; }
    }
}

// ---------------- merge 2..4 chunk partials per 128-row block -> Y planes ----------------
__global__ __launch_bounds__(256) void merge128_kernel(const float* __restrict__ PART,
                                                       unsigned short* __restrict__ Yh,
                                                       unsigned short* __restrict__ Yl) {
    const int hb = blockIdx.x;          // 0..23
    const int tq = 4 + blockIdx.y;      // 4..15
    const int h = hb % NH, b = hb / NH;
    const int nch = (tq >= 12) ? 4 : (tq >= 8) ? 3 : 2;
    const float* base = PART + (size_t)(hb * 36 + FCB[tq - 4]) * 8448;
    const int tid = threadIdx.x;
    const int r = tid >> 1, half = tid & 1;
    float mm[4], la[4];
    float M = -1e30f;
    #pragma unroll
    for (int c = 0; c < 4; ++c) {
        int cc = (c < nch) ? c : 0;
        float mv = base[(size_t)cc * 8448 + 8192 + r];
        float lv = base[(size_t)cc * 8448 + 8192 + 128 + r];
        mm[c] = (c < nch) ? mv : -1e30f;
        la[c] = (c < nch) ? lv : 0.f;
        M = fmaxf(M, mm[c]);
    }
    float a[4], L = 0.f;
    #pragma unroll
    for (int c = 0; c < 4; ++c) {
        a[c] = (c < nch) ? __expf(mm[c] - M) : 0.f;
        L += a[c] * la[c];
    }
    float inv = 1.f / L;
    const int t = tq * 128 + r;
    size_t ybase = ((size_t)(b * T + t)) * CE + h * 64 + half * 32;
    #pragma unroll
    for (int uu = 0; uu < 8; ++uu) {
        float ax = 0.f, ay = 0.f, az = 0.f, aw = 0.f;
        #pragma unroll
        for (int c = 0; c < 4; ++c) {
            int cc = (c < nch) ? c : 0;
            float4 x = *reinterpret_cast<const float4*>(
                &base[(size_t)cc * 8448 + r * 64 + half * 32 + uu * 4]);
            ax += a[c] * x.x; ay += a[c] * x.y; az += a[c] * x.z; aw += a[c] * x.w;
        }
        unsigned short hh[4], ll[4];
        bf16split(ax * inv, hh[0], ll[0]); bf16split(ay * inv, hh[1], ll[1]);
        bf16split(az * inv, hh[2], ll[2]); bf16split(aw * inv, hh[3], ll[3]);
        uint2 ph = {(unsigned)hh[0] | ((unsigned)hh[1] << 16), (unsigned)hh[2] | ((unsigned)hh[3] << 16)};
        uint2 pl = {(unsigned)ll[0] | ((unsigned)ll[1] << 16), (unsigned)ll[2] | ((unsigned)ll[3] << 16)};
        *reinterpret_cast<uint2*>(&Yh[ybase + uu * 4]) = ph;
        *reinterpret_cast<uint2*>(&Yl[ybase + uu * 4]) = pl;
    }
}

// ---------------- fp32 flash fallback (small ws) ----------------
__global__ __launch_bounds__(256) void flash_kernel(const float* __restrict__ qkv,
                                                    const float* __restrict__ FF,
                                                    float* __restrict__ Y,
                                                    float* __restrict__ PO,
                                                    float* __restrict__ PML,
                                                    int split) {
    const int hb = blockIdx.x;
    const int h = hb % NH, b = hb / NH;
    int qt, kt0, kt1, mode;
    if (split) {
        const int u = blockIdx.y;
        if (u < 16)      { qt = 16 + u; kt0 = 0;  kt1 = 16;     mode = 1; }
        else if (u < 32) { qt = 31 - u; kt0 = 0;  kt1 = qt + 1; mode = 0; }
        else             { qt = 63 - u; kt0 = 16; kt1 = qt + 1; mode = 2; }
    } else {
        qt = 31 - blockIdx.y; kt0 = 0; kt1 = qt + 1; mode = 0;
    }
    const int qb = qt * 64;
    const int tid = threadIdx.x, ty = tid >> 4, tx = tid & 15;
    __shared__ float Qt[64][68];
    __shared__ float KtPs[64][68];
    __shared__ float Vs[64][68];
    const int r = tid >> 2, c0 = (tid & 3) * 16;
    {
        const float* qrow = qkv + (size_t)(b * T + qb + r) * C3 + h * 64;
        #pragma unroll
        for (int u = 0; u < 4; ++u) {
            float4 q4 = *reinterpret_cast<const float4*>(&qrow[c0 + u * 4]);
            int d = c0 + u * 4;
            Qt[d + 0][r] = q4.x; Qt[d + 1][r] = q4.y; Qt[d + 2][r] = q4.z; Qt[d + 3][r] = q4.w;
        }
    }
    float m[4], l[4], O[4][4];
    #pragma unroll
    for (int i = 0; i < 4; ++i) {
        m[i] = -1e30f; l[i] = 0.f;
        #pragma unroll
        for (int j = 0; j < 4; ++j) O[i][j] = 0.f;
    }
    const float* FFb = FF + (size_t)b * T * T;
    for (int kt = kt0; kt < kt1; ++kt) {
        const int kb = kt * 64;
        __syncthreads();
        {
            const float* krow = qkv + (size_t)(b * T + kb + r) * C3 + 768 + h * 64;
            const float* vrow = qkv + (size_t)(b * T + kb + r) * C3 + 1536 + h * 64;
            #pragma unroll
            for (int u = 0; u < 4; ++u) {
                float4 k4 = *reinterpret_cast<const float4*>(&krow[c0 + u * 4]);
                int d = c0 + u * 4;
                KtPs[d + 0][r] = k4.x; KtPs[d + 1][r] = k4.y;
                KtPs[d + 2][r] = k4.z; KtPs[d + 3][r] = k4.w;
                *reinterpret_cast<float4*>(&Vs[r][c0 + u * 4]) =
                    *reinterpret_cast<const float4*>(&vrow[c0 + u * 4]);
            }
        }
        __syncthreads();
        float sc[4][4] = {};
        #pragma unroll
        for (int d = 0; d < 64; ++d) {
            float4 qv = *reinterpret_cast<const float4*>(&Qt[d][ty * 4]);
            float4 kv = *reinterpret_cast<const float4*>(&KtPs[d][tx * 4]);
            float qa[4] = {qv.x, qv.y, qv.z, qv.w};
            float ka[4] = {kv.x, kv.y, kv.z, kv.w};
            #pragma unroll
            for (int i = 0; i < 4; ++i)
                #pragma unroll
                for (int j = 0; j < 4; ++j)
                    sc[i][j] = fmaf(qa[i], ka[j], sc[i][j]);
        }
        #pragma unroll
        for (int i = 0; i < 4; ++i) {
            int t = qb + ty * 4 + i;
            float4 f4 = *reinterpret_cast<const float4*>(&FFb[(size_t)t * T + kb + tx * 4]);
            float fv[4] = {f4.x, f4.y, f4.z, f4.w};
            #pragma unroll
            for (int j = 0; j < 4; ++j) {
                int s = kb + tx * 4 + j;
                float v = sc[i][j] * 0.125f - fv[j];
                sc[i][j] = (s <= t) ? v : -1e30f;
            }
        }
        #pragma unroll
        for (int i = 0; i < 4; ++i) {
            float tm = fmaxf(fmaxf(sc[i][0], sc[i][1]), fmaxf(sc[i][2], sc[i][3]));
            tm = fmaxf(tm, __shfl_xor(tm, 1));
            tm = fmaxf(tm, __shfl_xor(tm, 2));
            tm = fmaxf(tm, __shfl_xor(tm, 4));
            tm = fmaxf(tm, __shfl_xor(tm, 8));
            float mn = fmaxf(m[i], tm);
            float scale = __expf(m[i] - mn);
            float rs = 0.f;
            #pragma unroll
            for (int j = 0; j < 4; ++j) {
                float p = __expf(sc[i][j] - mn);
                sc[i][j] = p; rs += p;
            }
            rs += __shfl_xor(rs, 1); rs += __shfl_xor(rs, 2);
            rs += __shfl_xor(rs, 4); rs += __shfl_xor(rs, 8);
            l[i] = l[i] * scale + rs;
            m[i] = mn;
            #pragma unroll
            for (int j = 0; j < 4; ++j) O[i][j] *= scale;
        }
        __syncthreads();
        #pragma unroll
        for (int i = 0; i < 4; ++i) {
            float4 p4 = {sc[i][0], sc[i][1], sc[i][2], sc[i][3]};
            *reinterpret_cast<float4*>(&KtPs[ty * 4 + i][tx * 4]) = p4;
        }
        __syncthreads();
        #pragma unroll
        for (int j4 = 0; j4 < 16; ++j4) {
            float pvv[4][4];
            #pragma unroll
            for (int i = 0; i < 4; ++i) {
                float4 t4 = *reinterpret_cast<const float4*>(&KtPs[ty * 4 + i][j4 * 4]);
                pvv[i][0] = t4.x; pvv[i][1] = t4.y; pvv[i][2] = t4.z; pvv[i][3] = t4.w;
            }
            #pragma unroll
            for (int jj = 0; jj < 4; ++jj) {
                float4 v4 = *reinterpret_cast<const float4*>(&Vs[j4 * 4 + jj][tx * 4]);
                float vv[4] = {v4.x, v4.y, v4.z, v4.w};
                #pragma unroll
                for (int i = 0; i < 4; ++i)
                    #pragma unroll
                    for (int dd = 0; dd < 4; ++dd)
                        O[i][dd] = fmaf(pvv[i][jj], vv[dd], O[i][dd]);
            }
        }
    }
    if (mode == 0) {
        #pragma unroll
        for (int i = 0; i < 4; ++i) {
            int t = qb + ty * 4 + i;
            float inv = 1.f / l[i];
            float4 o4 = {O[i][0] * inv, O[i][1] * inv, O[i][2] * inv, O[i][3] * inv};
            *reinterpret_cast<float4*>(&Y[(size_t)(b * T + t) * CE + h * 64 + tx * 4]) = o4;
        }
    } else {
        const int pidx = (b * NH + h) * 16 + (qt - 16);
        float* Ob  = PO  + (size_t)(mode - 1) * (NB * NH * 16 * 4096) + (size_t)pidx * 4096;
        float* mlb = PML + (size_t)(mode - 1) * (NB * NH * 16 * 128)  + (size_t)pidx * 128;
        #pragma unroll
        for (int i = 0; i < 4; ++i) {
            int rr = ty * 4 + i;
            float4 o4 = {O[i][0], O[i][1], O[i][2], O[i][3]};
            *reinterpret_cast<float4*>(&Ob[rr * 64 + tx * 4]) = o4;
            if (tx == 0) { mlb[rr] = m[i]; mlb[64 + rr] = l[i]; }
        }
    }
}

// ---------------- merge the two split-K partials (fp32 fallback path) ----------------
__global__ __launch_bounds__(256) void merge_kernel(const float* __restrict__ PO,
                                                    const float* __restrict__ PML,
                                                    float* __restrict__ Y) {
    const int p = blockIdx.x;
    const int q16 = p & 15;
    const int hb = p >> 4;
    const int h = hb % NH, b = hb / NH;
    const int qt = 16 + q16;
    const float* O0  = PO  + (size_t)p * 4096;
    const float* O1  = PO  + (size_t)(NB * NH * 16) * 4096 + (size_t)p * 4096;
    const float* ml0 = PML + (size_t)p * 128;
    const float* ml1 = PML + (size_t)(NB * NH * 16) * 128  + (size_t)p * 128;
    const int tid = threadIdx.x;
    const int r = tid >> 2, c0 = (tid & 3) * 16;
    float m0 = ml0[r], l0 = ml0[64 + r];
    float m1 = ml1[r], l1 = ml1[64 + r];
    float M  = fmaxf(m0, m1);
    float a0 = __expf(m0 - M), a1 = __expf(m1 - M);
    float inv = 1.f / (a0 * l0 + a1 * l1);
    const int t = qt * 64 + r;
    float* Yrow = Y + (size_t)(b * T + t) * CE + h * 64;
    #pragma unroll
    for (int u = 0; u < 4; ++u) {
        float4 x0 = *reinterpret_cast<const float4*>(&O0[r * 64 + c0 + u * 4]);
        float4 x1 = *reinterpret_cast<const float4*>(&O1[r * 64 + c0 + u * 4]);
        float4 y;
        y.x = (a0 * x0.x + a1 * x1.x) * inv;
        y.y = (a0 * x0.y + a1 * x1.y) * inv;
        y.z = (a0 * x0.z + a1 * x1.z) * inv;
        y.w = (a0 * x0.w + a1 * x1.w) * inv;
        *reinterpret_cast<float4*>(&Yrow[c0 + u * 4]) = y;
    }
}

extern "C" void kernel_launch(void* const* d_in, const int* in_sizes, int n_in,
                              void* d_out, int out_size, void* d_ws, size_t ws_size,
                              hipStream_t stream) {
    const float* x      = (const float*)d_in[0];
    const float* W_attn = (const float*)d_in[1];
    const float* b_attn = (const float*)d_in[2];
    const float* W_proj = (const float*)d_in[3];
    const float* b_proj = (const float*)d_in[4];
    float* out = (float*)d_out;

    char* ws = (char*)d_ws;
    const size_t QKV_BYTES = (size_t)NB * T * C3 * 4;       // 37,748,736
    const size_t S_BYTES   = (size_t)NB * T * T * 4;        // 33,554,432
    const size_t P_BYTES   = (size_t)NB * 32 * T * 4;       //    524,288
    const size_t Y_BYTES   = (size_t)NB * T * CE * 4;       // 12,582,912
    const size_t PO_BYTES  = (size_t)2 * NB * NH * 16 * 4096 * 4;  // 12,582,912
    const size_t PML_BYTES = (size_t)2 * NB * NH * 16 * 128 * 4;   //    393,216
    const size_t PLANE_X   = (size_t)NB * T * CE * 2;       // 6,291,456
    const size_t PLANE_WA  = (size_t)C3 * CE * 2;           // 3,538,944
    const size_t PLANE_WP  = (size_t)CE * CE * 2;           // 1,179,648
    const size_t PLANE_KV  = (size_t)NB * NH * T * 64 * 2;  // 6,291,456

    const size_t U_OFF  = QKV_BYTES + S_BYTES + P_BYTES + Y_BYTES;
    const size_t U_SIZE = PO_BYTES + PML_BYTES;
    const size_t W_OFF  = U_OFF + U_SIZE;
    const size_t KV_OFF = W_OFF + 2 * PLANE_WA + 2 * PLANE_WP;

    float* qkv  = (float*)ws;                               // fallback paths only
    float* Vtmp = (float*)ws;                               // kv: gemm1 V output (12.6MB)
    float* PART = (float*)ws;                               // kv: flash partials (29.2MB, after Vtmp dead)
    float* S    = (float*)(ws + QKV_BYTES);
    float* Psum = (float*)(ws + QKV_BYTES + S_BYTES);
    float* Yb   = (float*)(ws + QKV_BYTES + S_BYTES + P_BYTES);   // fp32 Y (fallback)
    unsigned short* Qhp = (unsigned short*)(ws + QKV_BYTES + S_BYTES + P_BYTES);  // kv: Q planes in Yb region
    unsigned short* Qlp = (unsigned short*)(ws + QKV_BYTES + S_BYTES + P_BYTES + PLANE_X);
    float* PO   = (float*)(ws + U_OFF);
    float* PML  = (float*)(ws + U_OFF + PO_BYTES);
    unsigned short* Xh  = (unsigned short*)(ws + U_OFF);    // X planes; reused as Y planes after gemm1
    unsigned short* Xl  = (unsigned short*)(ws + U_OFF + PLANE_X);
    unsigned short* Yhp = Xh;
    unsigned short* Ylp = Xl;
    unsigned short* WAh = (unsigned short*)(ws + W_OFF);
    unsigned short* WAl = (unsigned short*)(ws + W_OFF + PLANE_WA);
    unsigned short* WPh = (unsigned short*)(ws + W_OFF + 2 * PLANE_WA);
    unsigned short* WPl = (unsigned short*)(ws + W_OFF + 2 * PLANE_WA + PLANE_WP);
    unsigned short* Khp = (unsigned short*)(ws + KV_OFF);
    unsigned short* Klp = (unsigned short*)(ws + KV_OFF + PLANE_KV);
    unsigned short* VTh = (unsigned short*)(ws + KV_OFF + 2 * PLANE_KV);
    unsigned short* VTl = (unsigned short*)(ws + KV_OFF + 3 * PLANE_KV);

    const size_t NEED_SPLIT = U_OFF + U_SIZE;
    const size_t NEED_MFMA  = KV_OFF;
    const size_t NEED_KV    = KV_OFF + 4 * PLANE_KV;
    const int split = (ws_size >= NEED_SPLIT) ? 1 : 0;
    const int mfma  = (ws_size >= NEED_MFMA) ? 1 : 0;
    const int kv    = (ws_size >= NEED_KV && mfma) ? 1 : 0;

    const int M = NB * T;  // 4096

    if (kv) {
        // weights + x to planes
        cvt_split_T_kernel<<<dim3(C3 / 64, CE / 64), 256, 0, stream>>>(W_attn, WAh, WAl, CE, C3);
        cvt_split_T_kernel<<<dim3(CE / 64, CE / 64), 256, 0, stream>>>(W_proj, WPh, WPl, CE, CE);
        cvt_split_kernel<<<dim3((M * CE / 8) / 256), 256, 0, stream>>>(x, Xh, Xl);
        // gemm1 -> Q/K planes + Vtmp directly (no fp32 qkv)
        gemm_qkv_mfma_kernel<<<dim3(C3 / 128, M / 128), 256, 0, stream>>>(
            Xh, Xl, WAh, WAl, b_attn, Qhp, Qlp, Khp, Klp, Vtmp);
        cvt_kv_vt_kernel<<<dim3(T / 64, NB * NH), 256, 0, stream>>>(Vtmp, VTh, VTl);
        // s0 (+fused colsum -> Psum)
        s0_mfma_kernel<<<dim3(T / 64, T / 64, NB), 256, 0, stream>>>(Qhp, Qlp, Khp, Klp, S, Psum);
        // scan
        scanseg_kernel<<<dim3(T / 256, NB), 256, 0, stream>>>(Psum);
        ffscan_kernel<<<dim3(T / 256, 32, NB), 256, 0, stream>>>(S, Psum);
        // flash -> Y planes (+ PART) ; merge -> Y planes
        flash_mfma_kernel<<<dim3(NB * NH, 40), 256, 0, stream>>>(
            Qhp, Qlp, Khp, Klp, VTh, VTl, S, Yhp, Ylp, PART);
        merge128_kernel<<<dim3(NB * NH, 12), 256, 0, stream>>>(PART, Yhp, Ylp);
        // gemm2 from Y planes
        gemm_mfma_kernel<<<dim3(CE / 128, M / 128), 256, 0, stream>>>(
            Yhp, Ylp, WPh, WPl, b_proj, out, M, CE, CE);
        return;
    }

    // ---------------- fallback paths (small ws) ----------------
    if (mfma) {
        cvt_split_T_kernel<<<dim3(C3 / 64, CE / 64), 256, 0, stream>>>(W_attn, WAh, WAl, CE, C3);
        cvt_split_T_kernel<<<dim3(CE / 64, CE / 64), 256, 0, stream>>>(W_proj, WPh, WPl, CE, CE);
        cvt_split_kernel<<<dim3((M * CE / 8) / 256), 256, 0, stream>>>(x, Xh, Xl);
        gemm_mfma_kernel<<<dim3(C3 / 128, M / 128), 256, 0, stream>>>(Xh, Xl, WAh, WAl, b_attn, qkv, M, C3, CE);
    } else {
        gemm_bias_kernel<<<dim3(C3 / 64, M / 64), 256, 0, stream>>>(x, W_attn, b_attn, qkv, M, C3, CE);
    }
    s0_kernel<<<dim3(T / 64, T / 64, NB), 256, 0, stream>>>(qkv, S);
    colsum_kernel<<<dim3(T / 256, 32, NB), 256, 0, stream>>>(S, Psum);
    scanseg_kernel<<<dim3(T / 256, NB), 256, 0, stream>>>(Psum);
    ffscan_kernel<<<dim3(T / 256, 32, NB), 256, 0, stream>>>(S, Psum);
    if (split) {
        flash_kernel<<<dim3(NB * NH, 48), 256, 0, stream>>>(qkv, S, Yb, PO, PML, 1);
        merge_kernel<<<dim3(NB * NH * 16), 256, 0, stream>>>(PO, PML, Yb);
    } else {
        flash_kernel<<<dim3(NB * NH, 32), 256, 0, stream>>>(qkv, S, Yb, PO, PML, 0);
    }
    if (mfma) {
        cvt_split_kernel<<<dim3((M * CE / 8) / 256), 256, 0, stream>>>(Yb, Xh, Xl);
        gemm_mfma_kernel<<<dim3(CE / 128, M / 128), 256, 0, stream>>>(Xh, Xl, WPh, WPl, b_proj, out, M, CE, CE);
    } else {
        gemm_bias_kernel<<<dim3(CE / 64, M / 64), 256, 0, stream>>>(Yb, W_proj, b_proj, out, M, CE, CE);
    }
}